// Round 5
// baseline (1263.897 us; speedup 1.0000x reference)
//
#include <hip/hip_runtime.h>
#include <float.h>
#include <math.h>

#define N_ 8192
#define C_ 512
#define H_ 128

typedef __attribute__((ext_vector_type(8))) short bfrag;
typedef __attribute__((ext_vector_type(4))) float f4;

__device__ __forceinline__ ushort f2bf(float f) {
  unsigned u = __float_as_uint(f);
  unsigned r = (u + 0x7fffu + ((u >> 16) & 1u)) >> 16;
  return (ushort)r;
}

// ---------------- helpers ----------------
__device__ __forceinline__ float bred_sum128(float v, float* buf) {
  int t = threadIdx.x;
  buf[t] = v; __syncthreads();
  for (int s = 64; s > 0; s >>= 1) {
    if (t < s) buf[t] += buf[t + s];
    __syncthreads();
  }
  float r = buf[0]; __syncthreads();
  return r;
}

__device__ __forceinline__ void top3_ins(float (&tv)[3], int (&ti)[3], float v, int j) {
  bool b2 = (v > tv[2]) || (v == tv[2] && j < ti[2]);
  if (!b2) return;
  bool b1 = (v > tv[1]) || (v == tv[1] && j < ti[1]);
  if (b1) {
    tv[2] = tv[1]; ti[2] = ti[1];
    bool b0 = (v > tv[0]) || (v == tv[0] && j < ti[0]);
    if (b0) { tv[1] = tv[0]; ti[1] = ti[0]; tv[0] = v; ti[0] = j; }
    else    { tv[1] = v;     ti[1] = j; }
  } else { tv[2] = v; ti[2] = j; }
}

// ---------------- stage 1: concept aggregation ----------------
__global__ __launch_bounds__(256) void k_colsum1(const int* __restrict__ cm,
      const float* __restrict__ mv, float* __restrict__ colsum1) {
  int t = threadIdx.x;
  int c = blockIdx.x * 256 + t;
  int r0 = blockIdx.y * 256;
  float acc = 0.f;
  for (int r = 0; r < 256; ++r) {
    int i = r0 + r;
    acc += (float)cm[(size_t)i * C_ + c] * mv[i];
  }
  atomicAdd(&colsum1[c], acc);
}

template<int MODE>
__global__ __launch_bounds__(256) void k_agg(const float* __restrict__ x,
      const int* __restrict__ cm, const float* __restrict__ mv,
      const float* __restrict__ S, const float* __restrict__ colmax,
      float* __restrict__ outCH) {
  __shared__ float ws[8][32];
  int t = threadIdx.x;
  int cbase = blockIdx.x * 32;
  int h = t & 127, half = t >> 7;
  float acc[16];
#pragma unroll
  for (int k = 0; k < 16; ++k) acc[k] = 0.f;
  int sr = t >> 5, sc = t & 31;
  for (int sub = 0; sub < 128; ++sub) {
    int ibase = blockIdx.y * 1024 + sub * 8;
    {
      int i = ibase + sr, c = cbase + sc;
      float w;
      if (MODE == 0) w = cm[(size_t)i * C_ + c] ? mv[i] : 0.f;
      else           w = __expf(S[(size_t)i * C_ + c] - colmax[c]);
      ws[sr][sc] = w;
    }
    __syncthreads();
#pragma unroll
    for (int r = 0; r < 8; ++r) {
      float xv = x[(size_t)(ibase + r) * H_ + h];
      const float* wr = &ws[r][half * 16];
#pragma unroll
      for (int k = 0; k < 16; ++k) acc[k] += wr[k] * xv;
    }
    __syncthreads();
  }
#pragma unroll
  for (int k = 0; k < 16; ++k)
    atomicAdd(&outCH[(size_t)(cbase + half * 16 + k) * H_ + h], acc[k]);
}

__global__ __launch_bounds__(128) void k_fin_hidden1(float* __restrict__ h1,
      const float* __restrict__ colsum1, int* __restrict__ keep1) {
  __shared__ float buf[128];
  int c = blockIdx.x, t = threadIdx.x;
  float v = h1[(size_t)c * H_ + t] / (colsum1[c] + 1.f);
  h1[(size_t)c * H_ + t] = v;
  float sm = bred_sum128(v, buf);
  if (t == 0) keep1[c] = (sm != 0.f) ? 1 : 0;
}

__global__ __launch_bounds__(128) void k_fin_hidden2(float* __restrict__ h2,
      const float* __restrict__ colsumexp, float* __restrict__ rny) {
  __shared__ float buf[128];
  int c = blockIdx.x, t = threadIdx.x;
  float v = h2[(size_t)c * H_ + t] / colsumexp[c];
  h2[(size_t)c * H_ + t] = v;
  float ss = bred_sum128(v * v, buf);
  if (t == 0) rny[c] = (ss > 0.f) ? 1.f / sqrtf(ss) : 0.f;
}

__global__ __launch_bounds__(128) void k_rowstats(const float* __restrict__ A,
      float* __restrict__ rinv, float* __restrict__ diag, int* __restrict__ keep) {
  __shared__ float buf[128];
  int i = blockIdx.x, t = threadIdx.x;
  float v = A[(size_t)i * H_ + t];
  float ss = bred_sum128(v * v, buf);
  float sm = bred_sum128(v, buf);
  if (t == 0) {
    float nr = sqrtf(ss);
    if (rinv) rinv[i] = (ss > 0.f) ? 1.f / nr : 0.f;
    if (diag) diag[i] = (ss > 0.f) ? ss / (nr * nr) : 0.f;
    if (keep) keep[i] = (sm != 0.f) ? 1 : 0;
  }
}

// ---------------- generic fp32 tiled GEMM ----------------
template<int TRANSB, int ACT>
__global__ __launch_bounds__(256) void k_gemm(const float* __restrict__ A, int lda,
      const float* __restrict__ B, int ldb, float* __restrict__ Cc, int ldc,
      int M, int Nn, int Kk, const float* __restrict__ bias,
      const float* __restrict__ rowscale, const float* __restrict__ colscale) {
  __shared__ float As[16][68];
  __shared__ float Bs[16][68];
  int t = threadIdx.x;
  int n0 = blockIdx.x * 64, m0 = blockIdx.y * 64;
  int ty = t >> 4, tx = t & 15;
  float acc[4][4] = {};
  for (int k0 = 0; k0 < Kk; k0 += 16) {
#pragma unroll
    for (int li = t; li < 1024; li += 256) {
      int r = li >> 4, c = li & 15;
      As[c][r] = A[(size_t)(m0 + r) * lda + k0 + c];
    }
    if (TRANSB) {
#pragma unroll
      for (int li = t; li < 1024; li += 256) {
        int r = li >> 4, c = li & 15;
        Bs[c][r] = B[(size_t)(n0 + r) * ldb + k0 + c];
      }
    } else {
#pragma unroll
      for (int li = t; li < 1024; li += 256) {
        int nn = li & 63, c = li >> 6;
        Bs[c][nn] = B[(size_t)(k0 + c) * ldb + n0 + nn];
      }
    }
    __syncthreads();
#pragma unroll
    for (int kk = 0; kk < 16; ++kk) {
      float4 av = *(const float4*)&As[kk][ty * 4];
      float4 bv = *(const float4*)&Bs[kk][tx * 4];
      float a0 = av.x, a1 = av.y, a2 = av.z, a3 = av.w;
      float b0 = bv.x, b1 = bv.y, b2 = bv.z, b3 = bv.w;
      acc[0][0] += a0 * b0; acc[0][1] += a0 * b1; acc[0][2] += a0 * b2; acc[0][3] += a0 * b3;
      acc[1][0] += a1 * b0; acc[1][1] += a1 * b1; acc[1][2] += a1 * b2; acc[1][3] += a1 * b3;
      acc[2][0] += a2 * b0; acc[2][1] += a2 * b1; acc[2][2] += a2 * b2; acc[2][3] += a2 * b3;
      acc[3][0] += a3 * b0; acc[3][1] += a3 * b1; acc[3][2] += a3 * b2; acc[3][3] += a3 * b3;
    }
    __syncthreads();
  }
#pragma unroll
  for (int ii = 0; ii < 4; ++ii) {
    int row = m0 + ty * 4 + ii;
    float rs = rowscale ? rowscale[row] : 1.f;
#pragma unroll
    for (int jj = 0; jj < 4; ++jj) {
      int col = n0 + tx * 4 + jj;
      float v = acc[ii][jj] * rs;
      if (colscale) v *= colscale[col];
      if (bias) v += bias[col];
      if (ACT) v = (v > 0.f) ? v : 0.01f * v;
      Cc[(size_t)row * ldc + col] = v;
    }
  }
}

// ---------------- column softmax over S[N,C] ----------------
__global__ __launch_bounds__(256) void k_colmax_part(const float* __restrict__ S,
      float* __restrict__ part) {
  int t = threadIdx.x, b = blockIdx.x;
  int r0 = b * 256;
  float m0 = -FLT_MAX, m1 = -FLT_MAX;
  for (int r = 0; r < 256; ++r) {
    const float* row = S + (size_t)(r0 + r) * C_;
    m0 = fmaxf(m0, row[t]);
    m1 = fmaxf(m1, row[t + 256]);
  }
  part[(size_t)b * C_ + t] = m0;
  part[(size_t)b * C_ + t + 256] = m1;
}

__global__ __launch_bounds__(256) void k_colsum_part(const float* __restrict__ S,
      const float* __restrict__ colmax, float* __restrict__ part) {
  int t = threadIdx.x, b = blockIdx.x;
  int r0 = b * 256;
  float cm0 = colmax[t], cm1 = colmax[t + 256];
  float s0 = 0.f, s1 = 0.f;
  for (int r = 0; r < 256; ++r) {
    const float* row = S + (size_t)(r0 + r) * C_;
    s0 += __expf(row[t] - cm0);
    s1 += __expf(row[t + 256] - cm1);
  }
  part[(size_t)b * C_ + t] = s0;
  part[(size_t)b * C_ + t + 256] = s1;
}

__global__ __launch_bounds__(512) void k_colfin_max(const float* __restrict__ part,
      float* __restrict__ outv) {
  int c = threadIdx.x;
  float m = -FLT_MAX;
  for (int b = 0; b < 32; ++b) m = fmaxf(m, part[(size_t)b * C_ + c]);
  outv[c] = m;
}

__global__ __launch_bounds__(512) void k_colfin_sum(const float* __restrict__ part,
      float* __restrict__ outv) {
  int c = threadIdx.x;
  float s = 0.f;
  for (int b = 0; b < 32; ++b) s += part[(size_t)b * C_ + c];
  outv[c] = s;
}

// ---------------- row softmax (512 cols) with keep mask ----------------
__global__ __launch_bounds__(256) void k_rowsoftmax(float* __restrict__ Sm,
      const int* __restrict__ keep1) {
  __shared__ float buf[256];
  int i = blockIdx.x, t = threadIdx.x;
  float* row = Sm + (size_t)i * C_;
  int k0 = keep1[t], k1 = keep1[t + 256];
  float v0 = k0 ? row[t] : -FLT_MAX;
  float v1 = k1 ? row[t + 256] : -FLT_MAX;
  buf[t] = fmaxf(v0, v1); __syncthreads();
  for (int s = 128; s > 0; s >>= 1) {
    if (t < s) buf[t] = fmaxf(buf[t], buf[t + s]);
    __syncthreads();
  }
  float m = buf[0]; __syncthreads();
  float e0 = k0 ? expf(v0 - m) : 0.f;
  float e1 = k1 ? expf(v1 - m) : 0.f;
  buf[t] = e0 + e1; __syncthreads();
  for (int s = 128; s > 0; s >>= 1) {
    if (t < s) buf[t] += buf[t + s];
    __syncthreads();
  }
  float inv = 1.f / buf[0];
  row[t] = e0 * inv;
  row[t + 256] = e1 * inv;
}

// ---------------- gram prep: normalized rows split into bf16 hi + lo ----------------
__global__ __launch_bounds__(256) void k_prep_gram(const float* __restrict__ hs,
      const float* __restrict__ rn, ushort* __restrict__ Ghi, ushort* __restrict__ Glo) {
  int t = threadIdx.x;
  int row = blockIdx.x * 8 + (t >> 5);
  int c = (t & 31) * 4;
  float r = rn[row];
  float4 v = *(const float4*)&hs[(size_t)row * H_ + c];
  float q[4] = {v.x * r, v.y * r, v.z * r, v.w * r};
  ushort hi[4], lo[4];
#pragma unroll
  for (int k = 0; k < 4; ++k) {
    hi[k] = f2bf(q[k]);
    float hf = __uint_as_float(((unsigned)hi[k]) << 16);
    lo[k] = f2bf(q[k] - hf);
  }
  *(ushort4*)&Ghi[(size_t)row * H_ + c] = *(ushort4*)hi;
  *(ushort4*)&Glo[(size_t)row * H_ + c] = *(ushort4*)lo;
}

// ---------------- N x N Gram via compensated-bf16 MFMA + fused top-3 candidates ------
// 1 wave/block, 16 q-rows, grid (N/16, GSPLIT). Scores = hi*hi + hi*lo + lo*hi
// computed as 3 INDEPENDENT 4-chains (ILP); emits per-split top-3 candidate indices.
#define GSPLIT 8
__global__ __launch_bounds__(64) void k_gram_mfma(const ushort* __restrict__ Ghi,
      const ushort* __restrict__ Glo, int* __restrict__ Gip) {
  __shared__ float sv[64][12];
  __shared__ int   si[64][12];
  int l = threadIdx.x;
  int lo16 = l & 15, quad = l >> 4;
  int i0 = blockIdx.x * 16;
  int sp = blockIdx.y;
  const int jspan = N_ / GSPLIT;   // 1024

  bfrag ahi[4], alo[4];
#pragma unroll
  for (int kc = 0; kc < 4; ++kc) {
    size_t base = (size_t)(i0 + lo16) * H_ + kc * 32 + quad * 8;
    ahi[kc] = *(const bfrag*)&Ghi[base];
    alo[kc] = *(const bfrag*)&Glo[base];
  }

  float tv[4][3]; int ti[4][3];
#pragma unroll
  for (int r = 0; r < 4; ++r)
#pragma unroll
    for (int s = 0; s < 3; ++s) { tv[r][s] = -FLT_MAX; ti[r][s] = 0x7fffffff; }

  for (int jt = 0; jt < jspan / 64; ++jt) {
    int j0 = sp * jspan + jt * 64;
#pragma unroll
    for (int js = 0; js < 4; ++js) {
      int j = j0 + js * 16 + lo16;
      bfrag bhi[4], blo[4];
#pragma unroll
      for (int kc = 0; kc < 4; ++kc) {
        size_t base = (size_t)j * H_ + kc * 32 + quad * 8;
        bhi[kc] = *(const bfrag*)&Ghi[base];
        blo[kc] = *(const bfrag*)&Glo[base];
      }
      f4 ahh = (f4){0.f, 0.f, 0.f, 0.f};
      f4 ahl = (f4){0.f, 0.f, 0.f, 0.f};
      f4 alh = (f4){0.f, 0.f, 0.f, 0.f};
#pragma unroll
      for (int kc = 0; kc < 4; ++kc) {
        ahh = __builtin_amdgcn_mfma_f32_16x16x32_bf16(ahi[kc], bhi[kc], ahh, 0, 0, 0);
        ahl = __builtin_amdgcn_mfma_f32_16x16x32_bf16(ahi[kc], blo[kc], ahl, 0, 0, 0);
        alh = __builtin_amdgcn_mfma_f32_16x16x32_bf16(alo[kc], bhi[kc], alh, 0, 0, 0);
      }
#pragma unroll
      for (int r = 0; r < 4; ++r) {
        int gi = i0 + quad * 4 + r;
        float v = (j == gi) ? 0.f : (ahh[r] + ahl[r] + alh[r]);
        top3_ins(tv[r], ti[r], v, j);
      }
    }
  }
#pragma unroll
  for (int r = 0; r < 4; ++r)
#pragma unroll
    for (int s = 0; s < 3; ++s) {
      sv[l][r * 3 + s] = tv[r][s];
      si[l][r * 3 + s] = ti[r][s];
    }
  __syncthreads();
  if (l < 16) {
    int q = l >> 2, r = l & 3;     // row = q*4 + r = l
    float bv[3] = {-FLT_MAX, -FLT_MAX, -FLT_MAX};
    int bi[3] = {0x7fffffff, 0x7fffffff, 0x7fffffff};
    for (int u = 0; u < 16; ++u) {
      int src = q * 16 + u;
#pragma unroll
      for (int s = 0; s < 3; ++s)
        top3_ins(bv, bi, sv[src][r * 3 + s], si[src][r * 3 + s]);
    }
#pragma unroll
    for (int s = 0; s < 3; ++s)
      Gip[((size_t)sp * N_ + i0 + l) * 3 + s] = bi[s];
  }
}

// ---------------- exact fp32 rescore of 24 candidates/row -> final top-3 -------------
__global__ __launch_bounds__(256) void k_gram_rescore(const float* __restrict__ hs,
      const float* __restrict__ rn, const int* __restrict__ Gip,
      float* __restrict__ gvals, int* __restrict__ gidx) {
  int row = blockIdx.x * 4 + (threadIdx.x >> 6);
  int lane = threadIdx.x & 63;
  const float* qr = &hs[(size_t)row * H_];
  float q0 = qr[lane], q1 = qr[lane + 64];
  float rni = rn[row];
  float bv[3] = {-FLT_MAX, -FLT_MAX, -FLT_MAX};
  int bi[3] = {0x7fffffff, 0x7fffffff, 0x7fffffff};
  for (int s = 0; s < GSPLIT; ++s)
#pragma unroll
    for (int k = 0; k < 3; ++k) {
      int j = Gip[((size_t)s * N_ + row) * 3 + k];
      const float* jr = &hs[(size_t)j * H_];
      float d = q0 * jr[lane] + q1 * jr[lane + 64];
#pragma unroll
      for (int x = 1; x < 64; x <<= 1) d += __shfl_xor(d, x, 64);
      float v = (j == row) ? 0.f : d * rni * rn[j];
      top3_ins(bv, bi, v, j);
    }
  if (lane == 0) {
#pragma unroll
    for (int s = 0; s < 3; ++s) {
      gvals[(size_t)row * 3 + s] = bv[s];
      gidx[(size_t)row * 3 + s] = bi[s];
    }
  }
}

// ---------------- sparse scatter: hidden3 = hs2c^T @ h_shared ----------------
__global__ __launch_bounds__(128) void k_scatter(const float* __restrict__ hs,
      const float* __restrict__ gvals, const int* __restrict__ gidx,
      float* __restrict__ hidden3, float* __restrict__ colsum3) {
  int i = blockIdx.x, t = threadIdx.x;
  float xs = hs[(size_t)i * H_ + t];
#pragma unroll
  for (int k = 0; k < 3; ++k) {
    int j = gidx[i * 3 + k];
    float v = gvals[i * 3 + k];
    atomicAdd(&hidden3[(size_t)j * H_ + t], v * xs);
  }
  if (t == 0) {
#pragma unroll
    for (int k = 0; k < 3; ++k) atomicAdd(&colsum3[gidx[i * 3 + k]], gvals[i * 3 + k]);
  }
}

__global__ __launch_bounds__(128) void k_h3fin(float* __restrict__ hidden3,
      const float* __restrict__ hs, const float* __restrict__ colsum3,
      const float* __restrict__ diagv, float* __restrict__ rn3, int* __restrict__ keep2) {
  __shared__ float buf[128];
  int j = blockIdx.x, t = threadIdx.x;
  float v = hidden3[(size_t)j * H_ + t];
  if (colsum3[j] != 0.f) v += diagv[j] * hs[(size_t)j * H_ + t];
  hidden3[(size_t)j * H_ + t] = v;
  float ss = bred_sum128(v * v, buf);
  float sm = bred_sum128(v, buf);
  if (t == 0) {
    rn3[j] = (ss > 0.f) ? 1.f / sqrtf(ss) : 0.f;
    keep2[j] = (sm != 0.f) ? 1 : 0;
  }
}

// ---------------- attention prep: bf16 Qn/Kn, transposed V, keep as float ----------
__global__ __launch_bounds__(256) void k_prep_attn(const float* __restrict__ hs,
      const float* __restrict__ h3, const float* __restrict__ rqh,
      const float* __restrict__ rn3, const int* __restrict__ keep2,
      ushort* __restrict__ Qn, ushort* __restrict__ Kn, ushort* __restrict__ Vt,
      float* __restrict__ keepf) {
  __shared__ ushort T[H_][68];
  int t = threadIdx.x;
  int i0 = blockIdx.x * 64;
  int r = i0 + (t >> 2);
  int c0 = (t & 3) * 32;
  float rq = rqh[r], r3 = rn3[r];
  for (int c = c0; c < c0 + 32; c += 4) {
    float4 hv = *(const float4*)&hs[(size_t)r * H_ + c];
    float4 h3v = *(const float4*)&h3[(size_t)r * H_ + c];
    ushort q4[4] = {f2bf(hv.x * rq), f2bf(hv.y * rq), f2bf(hv.z * rq), f2bf(hv.w * rq)};
    ushort k4[4] = {f2bf(h3v.x * r3), f2bf(h3v.y * r3), f2bf(h3v.z * r3), f2bf(h3v.w * r3)};
    *(ushort4*)&Qn[(size_t)r * H_ + c] = *(ushort4*)q4;
    *(ushort4*)&Kn[(size_t)r * H_ + c] = *(ushort4*)k4;
    T[c + 0][r - i0] = f2bf(h3v.x);
    T[c + 1][r - i0] = f2bf(h3v.y);
    T[c + 2][r - i0] = f2bf(h3v.z);
    T[c + 3][r - i0] = f2bf(h3v.w);
  }
  if (t < 64) keepf[i0 + t] = (float)keep2[i0 + t];
  __syncthreads();
  int h = t >> 1, off = (t & 1) * 32;
  for (int u = 0; u < 32; u += 4) {
    ushort4 vv;
    vv.x = T[h][off + u]; vv.y = T[h][off + u + 1];
    vv.z = T[h][off + u + 2]; vv.w = T[h][off + u + 3];
    *(ushort4*)&Vt[(size_t)h * N_ + i0 + off + u] = vv;
  }
}

// ---------------- MFMA flash attention, FIXED-MAX softmax (scores are cos-sims <= ~1)
// p = keep * exp(s - 1); no running max, no alpha rescale. 1 wave/block, 16 q-rows.
#define JSPLIT 8
__global__ __launch_bounds__(64) void k_attn_mfma(const ushort* __restrict__ Qn,
      const ushort* __restrict__ Kn, const ushort* __restrict__ Vt,
      const float* __restrict__ keepf, float* __restrict__ Opart,
      float* __restrict__ Lpart) {
  __shared__ ushort Ps[16][72];
  int l = threadIdx.x;
  int lo16 = l & 15, quad = l >> 4;
  int i0 = blockIdx.x * 16;
  int sp = blockIdx.y;
  const int jspan = N_ / JSPLIT;

  bfrag aq[4];
#pragma unroll
  for (int kc = 0; kc < 4; ++kc)
    aq[kc] = *(const bfrag*)&Qn[(size_t)(i0 + lo16) * H_ + kc * 32 + quad * 8];

  f4 O[8];
#pragma unroll
  for (int ns = 0; ns < 8; ++ns) O[ns] = (f4){0.f, 0.f, 0.f, 0.f};
  f4 lsum = (f4){0.f, 0.f, 0.f, 0.f};   // per-lane partial row sums

  for (int jt = 0; jt < jspan / 64; ++jt) {
    int j0 = sp * jspan + jt * 64;
    float kp[4];
#pragma unroll
    for (int js = 0; js < 4; ++js) kp[js] = keepf[j0 + js * 16 + lo16];

    f4 S[4];
#pragma unroll
    for (int js = 0; js < 4; ++js) {
      f4 acc = (f4){0.f, 0.f, 0.f, 0.f};
#pragma unroll
      for (int kc = 0; kc < 4; ++kc) {
        bfrag b = *(const bfrag*)&Kn[(size_t)(j0 + js * 16 + lo16) * H_ + kc * 32 + quad * 8];
        acc = __builtin_amdgcn_mfma_f32_16x16x32_bf16(aq[kc], b, acc, 0, 0, 0);
      }
      S[js] = acc;
    }
#pragma unroll
    for (int js = 0; js < 4; ++js)
#pragma unroll
      for (int r = 0; r < 4; ++r) {
        float p = kp[js] * __expf(S[js][r] - 1.f);   // s in [-1.03,1.03]: safe
        lsum[r] += p;
        Ps[quad * 4 + r][js * 16 + lo16] = f2bf(p);
      }
    __syncthreads();
#pragma unroll
    for (int kc = 0; kc < 2; ++kc) {
      bfrag ap = *(const bfrag*)&Ps[lo16][kc * 32 + quad * 8];
#pragma unroll
      for (int ns = 0; ns < 8; ++ns) {
        bfrag bv = *(const bfrag*)&Vt[(size_t)(ns * 16 + lo16) * N_ + j0 + kc * 32 + quad * 8];
        O[ns] = __builtin_amdgcn_mfma_f32_16x16x32_bf16(ap, bv, O[ns], 0, 0, 0);
      }
    }
    __syncthreads();
  }
  // write partial O (unnormalized)
#pragma unroll
  for (int ns = 0; ns < 8; ++ns)
#pragma unroll
    for (int r = 0; r < 4; ++r) {
      int row = i0 + quad * 4 + r;
      Opart[((size_t)sp * N_ + row) * H_ + ns * 16 + lo16] = O[ns][r];
    }
  // reduce row sums across the 16 lanes of each quad-group, once
#pragma unroll
  for (int x = 1; x <= 8; x <<= 1)
#pragma unroll
    for (int r = 0; r < 4; ++r) lsum[r] += __shfl_xor(lsum[r], x, 16);
  if (lo16 == 0) {
#pragma unroll
    for (int r = 0; r < 4; ++r)
      Lpart[(size_t)sp * N_ + i0 + quad * 4 + r] = lsum[r];
  }
}

__global__ __launch_bounds__(128) void k_attn_merge(const float* __restrict__ Opart,
      const float* __restrict__ Lpart, float* __restrict__ outp) {
  int i = blockIdx.x, t = threadIdx.x;
  float lg = 0.f;
#pragma unroll
  for (int s = 0; s < JSPLIT; ++s) lg += Lpart[(size_t)s * N_ + i];
  float inv = (lg > 0.f) ? 1.f / lg : 0.f;
  float acc = 0.f;
#pragma unroll
  for (int s = 0; s < JSPLIT; ++s)
    acc += Opart[((size_t)s * N_ + i) * H_ + t];
  outp[(size_t)i * H_ + t] = acc * inv;
}

// ---------------- elementwise ----------------
__global__ __launch_bounds__(256) void k_sub2(const float4* __restrict__ a,
      const float4* __restrict__ b, float4* __restrict__ o) {
  int i = blockIdx.x * 256 + threadIdx.x;
  float4 x = a[i], y = b[i], r;
  r.x = x.x - y.x; r.y = x.y - y.y; r.z = x.z - y.z; r.w = x.w - y.w;
  o[i] = r;
}

__global__ __launch_bounds__(256) void k_sub3(const float4* __restrict__ a,
      const float4* __restrict__ b, const float4* __restrict__ c, float4* __restrict__ o) {
  int i = blockIdx.x * 256 + threadIdx.x;
  float4 x = a[i], y = b[i], z = c[i], r;
  r.x = x.x - y.x - z.x; r.y = x.y - y.y - z.y; r.z = x.z - y.z - z.z; r.w = x.w - y.w - z.w;
  o[i] = r;
}

__global__ __launch_bounds__(128) void k_pred(const float* __restrict__ a,
      const float* __restrict__ b, const float* __restrict__ c,
      const float* __restrict__ wout, const float* __restrict__ bout,
      float* __restrict__ outp) {
  __shared__ float buf[128];
  int i = blockIdx.x, t = threadIdx.x;
  size_t idx = (size_t)i * H_ + t;
  float v = (a[idx] + b[idx] + c[idx]) * wout[t];
  float s = bred_sum128(v, buf);
  if (t == 0) outp[i] = s + bout[0];
}

// ---------------- host ----------------
extern "C" void kernel_launch(void* const* d_in, const int* in_sizes, int n_in,
                              void* d_out, int out_size, void* d_ws, size_t ws_size,
                              hipStream_t stream) {
  const float* x          = (const float*)d_in[0];
  const float* mv         = (const float*)d_in[1];
  const int*   cm         = (const int*)d_in[2];
  const float* W_ps       = (const float*)d_in[3];
  const float* b_ps       = (const float*)d_in[4];
  const float* W_hs       = (const float*)d_in[5];
  const float* b_hs       = (const float*)d_in[6];
  const float* W_ps_fore  = (const float*)d_in[7];
  const float* b_ps_fore  = (const float*)d_in[8];
  const float* W_hs_fore  = (const float*)d_in[9];
  const float* b_hs_fore  = (const float*)d_in[10];
  const float* W_ps_back  = (const float*)d_in[11];
  const float* b_ps_back  = (const float*)d_in[12];
  const float* W_hs_back  = (const float*)d_in[13];
  const float* b_hs_back  = (const float*)d_in[14];
  const float* W_indi     = (const float*)d_in[15];
  const float* b_indi     = (const float*)d_in[16];
  const float* W_out      = (const float*)d_in[23];
  const float* b_out      = (const float*)d_in[24];
  float* outp = (float*)d_out;

  float* W = (float*)d_ws;
  const size_t NC = (size_t)N_ * C_;   // NC = 4*NH
  const size_t NH = (size_t)N_ * H_;
  const size_t CH = (size_t)C_ * H_;
  float* Sbuf = W;
  float* pback   = Sbuf;
  float* outps   = Sbuf + NH;
  float* hback   = Sbuf + 2 * NH;
  float* outindi = Sbuf + 3 * NH;
  size_t off = NC;
  float* T1       = W + off; off += NH;
  float* p_shared = W + off; off += NH;
  float* h_shared = W + off; off += NH;
  float* hidden3  = W + off; off += NH;
  float* h_info   = W + off; off += NH;
  float* out_hs   = W + off; off += NH;
  float* hidden1  = W + off; off += CH;
  float* hidden2  = W + off; off += CH;
  float* colsum1   = W + off; off += C_;
  float* colmax    = W + off; off += C_;
  float* colsumexp = W + off; off += C_;
  float* rny2      = W + off; off += C_;
  float* partb     = W + off; off += 32 * C_;
  float* rnx     = W + off; off += N_;
  float* rqh     = W + off; off += N_;
  float* diagv   = W + off; off += N_;
  float* colsum3 = W + off; off += N_;
  float* rn3     = W + off; off += N_;
  float* gvals   = W + off; off += 3 * N_;
  float* Lpart   = W + off; off += (size_t)JSPLIT * N_;
  float* keepf   = W + off; off += N_;
  int* keep1 = (int*)(W + off); off += C_;
  int* keep2 = (int*)(W + off); off += N_;
  int* gidx  = (int*)(W + off); off += 3 * N_;
  ushort* Qn = (ushort*)(W + off); off += NH / 2;
  ushort* Kn = (ushort*)(W + off); off += NH / 2;
  ushort* Vt = (ushort*)(W + off); off += NH / 2;
  float* Opart = W + off; off += (size_t)JSPLIT * NH;   // stage-5 only
  // Gram scratch ALIASES Opart (stage-4 only; disjoint in time from attention):
  ushort* Ghi = (ushort*)Opart;
  ushort* Glo = Ghi + NH;
  int*    Gip = (int*)(Opart + NH);

  hipMemsetAsync(colsum1, 0, C_ * sizeof(float), stream);
  hipMemsetAsync(hidden1, 0, CH * sizeof(float), stream);
  hipMemsetAsync(hidden2, 0, CH * sizeof(float), stream);
  hipMemsetAsync(hidden3, 0, NH * sizeof(float), stream);
  hipMemsetAsync(colsum3, 0, N_ * sizeof(float), stream);

  // stage 1: market-value aggregation
  k_colsum1<<<dim3(2, 32), 256, 0, stream>>>(cm, mv, colsum1);
  k_agg<0><<<dim3(16, 8), 256, 0, stream>>>(x, cm, mv, nullptr, nullptr, hidden1);
  k_fin_hidden1<<<C_, 128, 0, stream>>>(hidden1, colsum1, keep1);
  k_rowstats<<<N_, 128, 0, stream>>>(x, rnx, nullptr, nullptr);

  // stage 2: softmax over stocks, hidden2
  k_gemm<1, 0><<<dim3(C_ / 64, N_ / 64), 256, 0, stream>>>(
      x, H_, hidden1, H_, Sbuf, C_, N_, C_, H_, nullptr, nullptr, nullptr);
  k_colmax_part<<<32, 256, 0, stream>>>(Sbuf, partb);
  k_colfin_max<<<1, 512, 0, stream>>>(partb, colmax);
  k_colsum_part<<<32, 256, 0, stream>>>(Sbuf, colmax, partb);
  k_colfin_sum<<<1, 512, 0, stream>>>(partb, colsumexp);
  k_agg<1><<<dim3(16, 8), 256, 0, stream>>>(x, nullptr, nullptr, Sbuf, colmax, hidden2);
  k_fin_hidden2<<<C_, 128, 0, stream>>>(hidden2, colsumexp, rny2);

  // stage 3: c2s softmax + p branch
  k_gemm<1, 0><<<dim3(C_ / 64, N_ / 64), 256, 0, stream>>>(
      x, H_, hidden2, H_, Sbuf, C_, N_, C_, H_, nullptr, rnx, rny2);
  k_rowsoftmax<<<N_, 256, 0, stream>>>(Sbuf, keep1);
  k_gemm<0, 0><<<dim3(H_ / 64, N_ / 64), 256, 0, stream>>>(
      Sbuf, C_, hidden2, H_, T1, H_, N_, H_, C_, nullptr, nullptr, nullptr);
  k_gemm<0, 0><<<dim3(2, 128), 256, 0, stream>>>(
      T1, H_, W_ps, H_, p_shared, H_, N_, H_, H_, b_ps, nullptr, nullptr);
  k_gemm<0, 0><<<dim3(2, 128), 256, 0, stream>>>(
      p_shared, H_, W_ps_back, H_, pback, H_, N_, H_, H_, b_ps_back, nullptr, nullptr);
  k_gemm<0, 1><<<dim3(2, 128), 256, 0, stream>>>(
      p_shared, H_, W_ps_fore, H_, outps, H_, N_, H_, H_, b_ps_fore, nullptr, nullptr);

  // stage 4: h_shared, N x N top-3 graph (MFMA candidates + exact rescore)
  k_sub2<<<NH / 4 / 256, 256, 0, stream>>>((const float4*)x, (const float4*)pback,
                                           (float4*)h_shared);
  k_rowstats<<<N_, 128, 0, stream>>>(h_shared, rqh, diagv, nullptr);
  k_prep_gram<<<N_ / 8, 256, 0, stream>>>(h_shared, rqh, Ghi, Glo);
  k_gram_mfma<<<dim3(N_ / 16, GSPLIT), 64, 0, stream>>>(Ghi, Glo, Gip);
  k_gram_rescore<<<N_ / 4, 256, 0, stream>>>(h_shared, rqh, Gip, gvals, gidx);
  k_scatter<<<N_, 128, 0, stream>>>(h_shared, gvals, gidx, hidden3, colsum3);
  k_h3fin<<<N_, 128, 0, stream>>>(hidden3, h_shared, colsum3, diagv, rn3, keep2);

  // stage 5: MFMA flash attention (fixed-max), h branch
  k_prep_attn<<<N_ / 64, 256, 0, stream>>>(h_shared, hidden3, rqh, rn3, keep2,
                                           Qn, Kn, Vt, keepf);
  k_attn_mfma<<<dim3(N_ / 16, JSPLIT), 64, 0, stream>>>(Qn, Kn, Vt, keepf,
                                                        Opart, Lpart);
  k_attn_merge<<<N_, 128, 0, stream>>>(Opart, Lpart, T1);
  k_gemm<0, 0><<<dim3(2, 128), 256, 0, stream>>>(
      T1, H_, W_hs, H_, h_info, H_, N_, H_, H_, b_hs, nullptr, nullptr);
  k_gemm<0, 0><<<dim3(2, 128), 256, 0, stream>>>(
      h_info, H_, W_hs_back, H_, hback, H_, N_, H_, H_, b_hs_back, nullptr, nullptr);
  k_gemm<0, 1><<<dim3(2, 128), 256, 0, stream>>>(
      h_info, H_, W_hs_fore, H_, out_hs, H_, N_, H_, H_, b_hs_fore, nullptr, nullptr);

  // stage 6: individual branch + final projection
  k_sub3<<<NH / 4 / 256, 256, 0, stream>>>((const float4*)x, (const float4*)pback,
                                           (const float4*)hback, (float4*)h_shared);
  k_gemm<0, 1><<<dim3(2, 128), 256, 0, stream>>>(
      h_shared, H_, W_indi, H_, outindi, H_, N_, H_, H_, b_indi, nullptr, nullptr);
  k_pred<<<N_, 128, 0, stream>>>(outps, out_hs, outindi, W_out, b_out, outp);
}

// Round 6
// 981.950 us; speedup vs baseline: 1.2871x; 1.2871x over previous
//
#include <hip/hip_runtime.h>
#include <float.h>
#include <math.h>

#define N_ 8192
#define C_ 512
#define H_ 128

typedef __attribute__((ext_vector_type(8))) short bfrag;
typedef __attribute__((ext_vector_type(4))) float f4;

__device__ __forceinline__ ushort f2bf(float f) {
  unsigned u = __float_as_uint(f);
  unsigned r = (u + 0x7fffu + ((u >> 16) & 1u)) >> 16;
  return (ushort)r;
}

// ---------------- helpers ----------------
__device__ __forceinline__ float bred_sum128(float v, float* buf) {
  int t = threadIdx.x;
  buf[t] = v; __syncthreads();
  for (int s = 64; s > 0; s >>= 1) {
    if (t < s) buf[t] += buf[t + s];
    __syncthreads();
  }
  float r = buf[0]; __syncthreads();
  return r;
}

__device__ __forceinline__ void top3_ins(float (&tv)[3], int (&ti)[3], float v, int j) {
  bool b2 = (v > tv[2]) || (v == tv[2] && j < ti[2]);
  if (!b2) return;
  bool b1 = (v > tv[1]) || (v == tv[1] && j < ti[1]);
  if (b1) {
    tv[2] = tv[1]; ti[2] = ti[1];
    bool b0 = (v > tv[0]) || (v == tv[0] && j < ti[0]);
    if (b0) { tv[1] = tv[0]; ti[1] = ti[0]; tv[0] = v; ti[0] = j; }
    else    { tv[1] = v;     ti[1] = j; }
  } else { tv[2] = v; ti[2] = j; }
}

// ---------------- stage 1: concept aggregation ----------------
__global__ __launch_bounds__(256) void k_colsum1(const int* __restrict__ cm,
      const float* __restrict__ mv, float* __restrict__ colsum1) {
  int t = threadIdx.x;
  int c = blockIdx.x * 256 + t;
  int r0 = blockIdx.y * 256;
  float acc = 0.f;
  for (int r = 0; r < 256; ++r) {
    int i = r0 + r;
    acc += (float)cm[(size_t)i * C_ + c] * mv[i];
  }
  atomicAdd(&colsum1[c], acc);
}

template<int MODE>
__global__ __launch_bounds__(256) void k_agg(const float* __restrict__ x,
      const int* __restrict__ cm, const float* __restrict__ mv,
      const float* __restrict__ S, const float* __restrict__ colmax,
      float* __restrict__ outCH) {
  __shared__ float ws[8][32];
  int t = threadIdx.x;
  int cbase = blockIdx.x * 32;
  int h = t & 127, half = t >> 7;
  float acc[16];
#pragma unroll
  for (int k = 0; k < 16; ++k) acc[k] = 0.f;
  int sr = t >> 5, sc = t & 31;
  for (int sub = 0; sub < 128; ++sub) {
    int ibase = blockIdx.y * 1024 + sub * 8;
    {
      int i = ibase + sr, c = cbase + sc;
      float w;
      if (MODE == 0) w = cm[(size_t)i * C_ + c] ? mv[i] : 0.f;
      else           w = __expf(S[(size_t)i * C_ + c] - colmax[c]);
      ws[sr][sc] = w;
    }
    __syncthreads();
#pragma unroll
    for (int r = 0; r < 8; ++r) {
      float xv = x[(size_t)(ibase + r) * H_ + h];
      const float* wr = &ws[r][half * 16];
#pragma unroll
      for (int k = 0; k < 16; ++k) acc[k] += wr[k] * xv;
    }
    __syncthreads();
  }
#pragma unroll
  for (int k = 0; k < 16; ++k)
    atomicAdd(&outCH[(size_t)(cbase + half * 16 + k) * H_ + h], acc[k]);
}

__global__ __launch_bounds__(128) void k_fin_hidden1(float* __restrict__ h1,
      const float* __restrict__ colsum1, int* __restrict__ keep1) {
  __shared__ float buf[128];
  int c = blockIdx.x, t = threadIdx.x;
  float v = h1[(size_t)c * H_ + t] / (colsum1[c] + 1.f);
  h1[(size_t)c * H_ + t] = v;
  float sm = bred_sum128(v, buf);
  if (t == 0) keep1[c] = (sm != 0.f) ? 1 : 0;
}

__global__ __launch_bounds__(128) void k_fin_hidden2(float* __restrict__ h2,
      const float* __restrict__ colsumexp, float* __restrict__ rny) {
  __shared__ float buf[128];
  int c = blockIdx.x, t = threadIdx.x;
  float v = h2[(size_t)c * H_ + t] / colsumexp[c];
  h2[(size_t)c * H_ + t] = v;
  float ss = bred_sum128(v * v, buf);
  if (t == 0) rny[c] = (ss > 0.f) ? 1.f / sqrtf(ss) : 0.f;
}

__global__ __launch_bounds__(128) void k_rowstats(const float* __restrict__ A,
      float* __restrict__ rinv, float* __restrict__ diag, int* __restrict__ keep) {
  __shared__ float buf[128];
  int i = blockIdx.x, t = threadIdx.x;
  float v = A[(size_t)i * H_ + t];
  float ss = bred_sum128(v * v, buf);
  float sm = bred_sum128(v, buf);
  if (t == 0) {
    float nr = sqrtf(ss);
    if (rinv) rinv[i] = (ss > 0.f) ? 1.f / nr : 0.f;
    if (diag) diag[i] = (ss > 0.f) ? ss / (nr * nr) : 0.f;
    if (keep) keep[i] = (sm != 0.f) ? 1 : 0;
  }
}

// ---------------- generic fp32 tiled GEMM ----------------
template<int TRANSB, int ACT>
__global__ __launch_bounds__(256) void k_gemm(const float* __restrict__ A, int lda,
      const float* __restrict__ B, int ldb, float* __restrict__ Cc, int ldc,
      int M, int Nn, int Kk, const float* __restrict__ bias,
      const float* __restrict__ rowscale, const float* __restrict__ colscale) {
  __shared__ float As[16][68];
  __shared__ float Bs[16][68];
  int t = threadIdx.x;
  int n0 = blockIdx.x * 64, m0 = blockIdx.y * 64;
  int ty = t >> 4, tx = t & 15;
  float acc[4][4] = {};
  for (int k0 = 0; k0 < Kk; k0 += 16) {
#pragma unroll
    for (int li = t; li < 1024; li += 256) {
      int r = li >> 4, c = li & 15;
      As[c][r] = A[(size_t)(m0 + r) * lda + k0 + c];
    }
    if (TRANSB) {
#pragma unroll
      for (int li = t; li < 1024; li += 256) {
        int r = li >> 4, c = li & 15;
        Bs[c][r] = B[(size_t)(n0 + r) * ldb + k0 + c];
      }
    } else {
#pragma unroll
      for (int li = t; li < 1024; li += 256) {
        int nn = li & 63, c = li >> 6;
        Bs[c][nn] = B[(size_t)(k0 + c) * ldb + n0 + nn];
      }
    }
    __syncthreads();
#pragma unroll
    for (int kk = 0; kk < 16; ++kk) {
      float4 av = *(const float4*)&As[kk][ty * 4];
      float4 bv = *(const float4*)&Bs[kk][tx * 4];
      float a0 = av.x, a1 = av.y, a2 = av.z, a3 = av.w;
      float b0 = bv.x, b1 = bv.y, b2 = bv.z, b3 = bv.w;
      acc[0][0] += a0 * b0; acc[0][1] += a0 * b1; acc[0][2] += a0 * b2; acc[0][3] += a0 * b3;
      acc[1][0] += a1 * b0; acc[1][1] += a1 * b1; acc[1][2] += a1 * b2; acc[1][3] += a1 * b3;
      acc[2][0] += a2 * b0; acc[2][1] += a2 * b1; acc[2][2] += a2 * b2; acc[2][3] += a2 * b3;
      acc[3][0] += a3 * b0; acc[3][1] += a3 * b1; acc[3][2] += a3 * b2; acc[3][3] += a3 * b3;
    }
    __syncthreads();
  }
#pragma unroll
  for (int ii = 0; ii < 4; ++ii) {
    int row = m0 + ty * 4 + ii;
    float rs = rowscale ? rowscale[row] : 1.f;
#pragma unroll
    for (int jj = 0; jj < 4; ++jj) {
      int col = n0 + tx * 4 + jj;
      float v = acc[ii][jj] * rs;
      if (colscale) v *= colscale[col];
      if (bias) v += bias[col];
      if (ACT) v = (v > 0.f) ? v : 0.01f * v;
      Cc[(size_t)row * ldc + col] = v;
    }
  }
}

// ---------------- column softmax over S[N,C] ----------------
__global__ __launch_bounds__(256) void k_colmax_part(const float* __restrict__ S,
      float* __restrict__ part) {
  int t = threadIdx.x, b = blockIdx.x;
  int r0 = b * 256;
  float m0 = -FLT_MAX, m1 = -FLT_MAX;
  for (int r = 0; r < 256; ++r) {
    const float* row = S + (size_t)(r0 + r) * C_;
    m0 = fmaxf(m0, row[t]);
    m1 = fmaxf(m1, row[t + 256]);
  }
  part[(size_t)b * C_ + t] = m0;
  part[(size_t)b * C_ + t + 256] = m1;
}

__global__ __launch_bounds__(256) void k_colsum_part(const float* __restrict__ S,
      const float* __restrict__ colmax, float* __restrict__ part) {
  int t = threadIdx.x, b = blockIdx.x;
  int r0 = b * 256;
  float cm0 = colmax[t], cm1 = colmax[t + 256];
  float s0 = 0.f, s1 = 0.f;
  for (int r = 0; r < 256; ++r) {
    const float* row = S + (size_t)(r0 + r) * C_;
    s0 += __expf(row[t] - cm0);
    s1 += __expf(row[t + 256] - cm1);
  }
  part[(size_t)b * C_ + t] = s0;
  part[(size_t)b * C_ + t + 256] = s1;
}

__global__ __launch_bounds__(512) void k_colfin_max(const float* __restrict__ part,
      float* __restrict__ outv) {
  int c = threadIdx.x;
  float m = -FLT_MAX;
  for (int b = 0; b < 32; ++b) m = fmaxf(m, part[(size_t)b * C_ + c]);
  outv[c] = m;
}

__global__ __launch_bounds__(512) void k_colfin_sum(const float* __restrict__ part,
      float* __restrict__ outv) {
  int c = threadIdx.x;
  float s = 0.f;
  for (int b = 0; b < 32; ++b) s += part[(size_t)b * C_ + c];
  outv[c] = s;
}

// ---------------- row softmax (512 cols) with keep mask ----------------
__global__ __launch_bounds__(256) void k_rowsoftmax(float* __restrict__ Sm,
      const int* __restrict__ keep1) {
  __shared__ float buf[256];
  int i = blockIdx.x, t = threadIdx.x;
  float* row = Sm + (size_t)i * C_;
  int k0 = keep1[t], k1 = keep1[t + 256];
  float v0 = k0 ? row[t] : -FLT_MAX;
  float v1 = k1 ? row[t + 256] : -FLT_MAX;
  buf[t] = fmaxf(v0, v1); __syncthreads();
  for (int s = 128; s > 0; s >>= 1) {
    if (t < s) buf[t] = fmaxf(buf[t], buf[t + s]);
    __syncthreads();
  }
  float m = buf[0]; __syncthreads();
  float e0 = k0 ? expf(v0 - m) : 0.f;
  float e1 = k1 ? expf(v1 - m) : 0.f;
  buf[t] = e0 + e1; __syncthreads();
  for (int s = 128; s > 0; s >>= 1) {
    if (t < s) buf[t] += buf[t + s];
    __syncthreads();
  }
  float inv = 1.f / buf[0];
  row[t] = e0 * inv;
  row[t + 256] = e1 * inv;
}

// ---------------- gram prep: normalized rows split into bf16 hi + lo ----------------
__global__ __launch_bounds__(256) void k_prep_gram(const float* __restrict__ hs,
      const float* __restrict__ rn, ushort* __restrict__ Ghi, ushort* __restrict__ Glo) {
  int t = threadIdx.x;
  int row = blockIdx.x * 8 + (t >> 5);
  int c = (t & 31) * 4;
  float r = rn[row];
  float4 v = *(const float4*)&hs[(size_t)row * H_ + c];
  float q[4] = {v.x * r, v.y * r, v.z * r, v.w * r};
  ushort hi[4], lo[4];
#pragma unroll
  for (int k = 0; k < 4; ++k) {
    hi[k] = f2bf(q[k]);
    float hf = __uint_as_float(((unsigned)hi[k]) << 16);
    lo[k] = f2bf(q[k] - hf);
  }
  *(ushort4*)&Ghi[(size_t)row * H_ + c] = *(ushort4*)hi;
  *(ushort4*)&Glo[(size_t)row * H_ + c] = *(ushort4*)lo;
}

// ---------------- N x N Gram: 4-wave blocks, LDS-staged j-tiles, top-3 candidates ----
// 256 thr, 64 q-rows/block (16/wave), grid (N/64, GSPLIT). j-tile (64 rows hi+lo)
// staged in LDS once per block, consumed by all 4 waves -> 4x less L2/L3 traffic.
#define GSPLIT 8
__global__ __launch_bounds__(256) void k_gram_mfma(const ushort* __restrict__ Ghi,
      const ushort* __restrict__ Glo, int* __restrict__ Gip) {
  __shared__ ushort JH[64 * 136];   // stride 136 shorts = 68 dwords === 4 mod 32: 2-way max
  __shared__ ushort JL[64 * 136];
  int t = threadIdx.x;
  int l = t & 63, w = t >> 6;
  int lo16 = l & 15, quad = l >> 4;
  int i0 = blockIdx.x * 64;
  int sp = blockIdx.y;
  const int jspan = N_ / GSPLIT;   // 1024

  bfrag ahi[4], alo[4];
#pragma unroll
  for (int kc = 0; kc < 4; ++kc) {
    size_t base = (size_t)(i0 + w * 16 + lo16) * H_ + kc * 32 + quad * 8;
    ahi[kc] = *(const bfrag*)&Ghi[base];
    alo[kc] = *(const bfrag*)&Glo[base];
  }

  float tv[4][3]; int ti[4][3];
#pragma unroll
  for (int r = 0; r < 4; ++r)
#pragma unroll
    for (int s = 0; s < 3; ++s) { tv[r][s] = -FLT_MAX; ti[r][s] = 0x7fffffff; }

  int srow = t >> 2, scol = (t & 3) * 32;
  for (int jt = 0; jt < jspan / 64; ++jt) {
    int j0 = sp * jspan + jt * 64;
    __syncthreads();
    {
      const ushort* gh = &Ghi[(size_t)(j0 + srow) * H_ + scol];
      const ushort* gl = &Glo[(size_t)(j0 + srow) * H_ + scol];
      ushort* dh = &JH[srow * 136 + scol];
      ushort* dl = &JL[srow * 136 + scol];
#pragma unroll
      for (int u = 0; u < 32; u += 4) {
        *(ushort4*)&dh[u] = *(const ushort4*)&gh[u];
        *(ushort4*)&dl[u] = *(const ushort4*)&gl[u];
      }
    }
    __syncthreads();
#pragma unroll
    for (int js = 0; js < 4; ++js) {
      int jl_ = js * 16 + lo16;
      int j = j0 + jl_;
      bfrag bhi[4], blo[4];
#pragma unroll
      for (int kc = 0; kc < 4; ++kc) {
        int base = jl_ * 136 + kc * 32 + quad * 8;
        bhi[kc] = *(const bfrag*)&JH[base];
        blo[kc] = *(const bfrag*)&JL[base];
      }
      f4 ahh = (f4){0.f, 0.f, 0.f, 0.f};
      f4 ahl = (f4){0.f, 0.f, 0.f, 0.f};
      f4 alh = (f4){0.f, 0.f, 0.f, 0.f};
#pragma unroll
      for (int kc = 0; kc < 4; ++kc) {
        ahh = __builtin_amdgcn_mfma_f32_16x16x32_bf16(ahi[kc], bhi[kc], ahh, 0, 0, 0);
        ahl = __builtin_amdgcn_mfma_f32_16x16x32_bf16(ahi[kc], blo[kc], ahl, 0, 0, 0);
        alh = __builtin_amdgcn_mfma_f32_16x16x32_bf16(alo[kc], bhi[kc], alh, 0, 0, 0);
      }
#pragma unroll
      for (int r = 0; r < 4; ++r) {
        int gi = i0 + w * 16 + quad * 4 + r;
        float v = (j == gi) ? 0.f : (ahh[r] + ahl[r] + alh[r]);
        top3_ins(tv[r], ti[r], v, j);
      }
    }
  }
  // block-wide top-3 reduce; reuse staging LDS as scratch (256 x 12 floats/ints)
  __syncthreads();
  float* svf = (float*)JH;
  int*   sif = (int*)JL;
#pragma unroll
  for (int r = 0; r < 4; ++r)
#pragma unroll
    for (int s = 0; s < 3; ++s) {
      svf[t * 12 + r * 3 + s] = tv[r][s];
      sif[t * 12 + r * 3 + s] = ti[r][s];
    }
  __syncthreads();
  if (t < 64) {
    int ww = t >> 4, qr = t & 15;
    int r2 = qr & 3, quad2 = qr >> 2;
    float bv[3] = {-FLT_MAX, -FLT_MAX, -FLT_MAX};
    int bi[3] = {0x7fffffff, 0x7fffffff, 0x7fffffff};
    for (int u = 0; u < 16; ++u) {
      int src = ww * 64 + quad2 * 16 + u;
#pragma unroll
      for (int s = 0; s < 3; ++s)
        top3_ins(bv, bi, svf[src * 12 + r2 * 3 + s], sif[src * 12 + r2 * 3 + s]);
    }
#pragma unroll
    for (int s = 0; s < 3; ++s)
      Gip[((size_t)sp * N_ + i0 + t) * 3 + s] = bi[s];
  }
}

// ---------------- exact fp32 rescore of 24 candidates/row -> final top-3 -------------
__global__ __launch_bounds__(256) void k_gram_rescore(const float* __restrict__ hs,
      const float* __restrict__ rn, const int* __restrict__ Gip,
      float* __restrict__ gvals, int* __restrict__ gidx) {
  int row = blockIdx.x * 4 + (threadIdx.x >> 6);
  int lane = threadIdx.x & 63;
  const float* qr = &hs[(size_t)row * H_];
  float q0 = qr[lane], q1 = qr[lane + 64];
  float rni = rn[row];
  float bv[3] = {-FLT_MAX, -FLT_MAX, -FLT_MAX};
  int bi[3] = {0x7fffffff, 0x7fffffff, 0x7fffffff};
  for (int s = 0; s < GSPLIT; ++s)
#pragma unroll
    for (int k = 0; k < 3; ++k) {
      int j = Gip[((size_t)s * N_ + row) * 3 + k];
      const float* jr = &hs[(size_t)j * H_];
      float d = q0 * jr[lane] + q1 * jr[lane + 64];
#pragma unroll
      for (int x = 1; x < 64; x <<= 1) d += __shfl_xor(d, x, 64);
      float v = (j == row) ? 0.f : d * rni * rn[j];
      top3_ins(bv, bi, v, j);
    }
  if (lane == 0) {
#pragma unroll
    for (int s = 0; s < 3; ++s) {
      gvals[(size_t)row * 3 + s] = bv[s];
      gidx[(size_t)row * 3 + s] = bi[s];
    }
  }
}

// ---------------- sparse scatter: hidden3 = hs2c^T @ h_shared ----------------
__global__ __launch_bounds__(128) void k_scatter(const float* __restrict__ hs,
      const float* __restrict__ gvals, const int* __restrict__ gidx,
      float* __restrict__ hidden3, float* __restrict__ colsum3) {
  int i = blockIdx.x, t = threadIdx.x;
  float xs = hs[(size_t)i * H_ + t];
#pragma unroll
  for (int k = 0; k < 3; ++k) {
    int j = gidx[i * 3 + k];
    float v = gvals[i * 3 + k];
    atomicAdd(&hidden3[(size_t)j * H_ + t], v * xs);
  }
  if (t == 0) {
#pragma unroll
    for (int k = 0; k < 3; ++k) atomicAdd(&colsum3[gidx[i * 3 + k]], gvals[i * 3 + k]);
  }
}

__global__ __launch_bounds__(128) void k_h3fin(float* __restrict__ hidden3,
      const float* __restrict__ hs, const float* __restrict__ colsum3,
      const float* __restrict__ diagv, float* __restrict__ rn3, int* __restrict__ keep2) {
  __shared__ float buf[128];
  int j = blockIdx.x, t = threadIdx.x;
  float v = hidden3[(size_t)j * H_ + t];
  if (colsum3[j] != 0.f) v += diagv[j] * hs[(size_t)j * H_ + t];
  hidden3[(size_t)j * H_ + t] = v;
  float ss = bred_sum128(v * v, buf);
  float sm = bred_sum128(v, buf);
  if (t == 0) {
    rn3[j] = (ss > 0.f) ? 1.f / sqrtf(ss) : 0.f;
    keep2[j] = (sm != 0.f) ? 1 : 0;
  }
}

// ---------------- attention prep: bf16 Qn/Kn, transposed V, keep as float ----------
__global__ __launch_bounds__(256) void k_prep_attn(const float* __restrict__ hs,
      const float* __restrict__ h3, const float* __restrict__ rqh,
      const float* __restrict__ rn3, const int* __restrict__ keep2,
      ushort* __restrict__ Qn, ushort* __restrict__ Kn, ushort* __restrict__ Vt,
      float* __restrict__ keepf) {
  __shared__ ushort T[H_][68];
  int t = threadIdx.x;
  int i0 = blockIdx.x * 64;
  int r = i0 + (t >> 2);
  int c0 = (t & 3) * 32;
  float rq = rqh[r], r3 = rn3[r];
  for (int c = c0; c < c0 + 32; c += 4) {
    float4 hv = *(const float4*)&hs[(size_t)r * H_ + c];
    float4 h3v = *(const float4*)&h3[(size_t)r * H_ + c];
    ushort q4[4] = {f2bf(hv.x * rq), f2bf(hv.y * rq), f2bf(hv.z * rq), f2bf(hv.w * rq)};
    ushort k4[4] = {f2bf(h3v.x * r3), f2bf(h3v.y * r3), f2bf(h3v.z * r3), f2bf(h3v.w * r3)};
    *(ushort4*)&Qn[(size_t)r * H_ + c] = *(ushort4*)q4;
    *(ushort4*)&Kn[(size_t)r * H_ + c] = *(ushort4*)k4;
    T[c + 0][r - i0] = f2bf(h3v.x);
    T[c + 1][r - i0] = f2bf(h3v.y);
    T[c + 2][r - i0] = f2bf(h3v.z);
    T[c + 3][r - i0] = f2bf(h3v.w);
  }
  if (t < 64) keepf[i0 + t] = (float)keep2[i0 + t];
  __syncthreads();
  int h = t >> 1, off = (t & 1) * 32;
  for (int u = 0; u < 32; u += 4) {
    ushort4 vv;
    vv.x = T[h][off + u]; vv.y = T[h][off + u + 1];
    vv.z = T[h][off + u + 2]; vv.w = T[h][off + u + 3];
    *(ushort4*)&Vt[(size_t)h * N_ + i0 + off + u] = vv;
  }
}

// ---------------- MFMA flash attention: 4-wave blocks, LDS-staged K/V, fixed-max ----
// p = keep * exp(s - 1) (cos-sim scores bounded). 256 thr, 64 q-rows/block.
#define JSPLIT 8
__global__ __launch_bounds__(256) void k_attn_mfma(const ushort* __restrict__ Qn,
      const ushort* __restrict__ Kn, const ushort* __restrict__ Vt,
      const float* __restrict__ keepf, float* __restrict__ Opart,
      float* __restrict__ Lpart) {
  __shared__ ushort Ks[64 * 136];      // [j][k] stride 136
  __shared__ ushort Vs[128 * 72];      // [h][j] stride 72
  __shared__ ushort Ps[4][16 * 72];    // per-wave P tile
  int t = threadIdx.x;
  int l = t & 63, w = t >> 6;
  int lo16 = l & 15, quad = l >> 4;
  int i0 = blockIdx.x * 64;
  int sp = blockIdx.y;
  const int jspan = N_ / JSPLIT;   // 1024

  bfrag aq[4];
#pragma unroll
  for (int kc = 0; kc < 4; ++kc)
    aq[kc] = *(const bfrag*)&Qn[(size_t)(i0 + w * 16 + lo16) * H_ + kc * 32 + quad * 8];

  f4 O[8];
#pragma unroll
  for (int ns = 0; ns < 8; ++ns) O[ns] = (f4){0.f, 0.f, 0.f, 0.f};
  f4 lsum = (f4){0.f, 0.f, 0.f, 0.f};

  int krow = t >> 2, kcol = (t & 3) * 32;
  int vrow = t >> 1, vcol = (t & 1) * 32;
  for (int jt = 0; jt < jspan / 64; ++jt) {
    int j0 = sp * jspan + jt * 64;
    __syncthreads();
    {
      const ushort* gk = &Kn[(size_t)(j0 + krow) * H_ + kcol];
      ushort* dk = &Ks[krow * 136 + kcol];
#pragma unroll
      for (int u = 0; u < 32; u += 4)
        *(ushort4*)&dk[u] = *(const ushort4*)&gk[u];
      const ushort* gv = &Vt[(size_t)vrow * N_ + j0 + vcol];
      ushort* dv = &Vs[vrow * 72 + vcol];
#pragma unroll
      for (int u = 0; u < 32; u += 4)
        *(ushort4*)&dv[u] = *(const ushort4*)&gv[u];
    }
    __syncthreads();
    float kp[4];
#pragma unroll
    for (int js = 0; js < 4; ++js) kp[js] = keepf[j0 + js * 16 + lo16];
    f4 S[4];
#pragma unroll
    for (int js = 0; js < 4; ++js) {
      f4 acc = (f4){0.f, 0.f, 0.f, 0.f};
#pragma unroll
      for (int kc = 0; kc < 4; ++kc) {
        bfrag b = *(const bfrag*)&Ks[(js * 16 + lo16) * 136 + kc * 32 + quad * 8];
        acc = __builtin_amdgcn_mfma_f32_16x16x32_bf16(aq[kc], b, acc, 0, 0, 0);
      }
      S[js] = acc;
    }
#pragma unroll
    for (int js = 0; js < 4; ++js)
#pragma unroll
      for (int r = 0; r < 4; ++r) {
        float p = kp[js] * __expf(S[js][r] - 1.f);
        lsum[r] += p;
        Ps[w][(quad * 4 + r) * 72 + js * 16 + lo16] = f2bf(p);
      }
    __syncthreads();
#pragma unroll
    for (int kc = 0; kc < 2; ++kc) {
      bfrag ap = *(const bfrag*)&Ps[w][lo16 * 72 + kc * 32 + quad * 8];
#pragma unroll
      for (int ns = 0; ns < 8; ++ns) {
        bfrag bv = *(const bfrag*)&Vs[(ns * 16 + lo16) * 72 + kc * 32 + quad * 8];
        O[ns] = __builtin_amdgcn_mfma_f32_16x16x32_bf16(ap, bv, O[ns], 0, 0, 0);
      }
    }
  }
  // write partial O (unnormalized)
#pragma unroll
  for (int ns = 0; ns < 8; ++ns)
#pragma unroll
    for (int r = 0; r < 4; ++r) {
      int row = i0 + w * 16 + quad * 4 + r;
      Opart[((size_t)sp * N_ + row) * H_ + ns * 16 + lo16] = O[ns][r];
    }
#pragma unroll
  for (int x = 1; x <= 8; x <<= 1)
#pragma unroll
    for (int r = 0; r < 4; ++r) lsum[r] += __shfl_xor(lsum[r], x, 16);
  if (lo16 == 0) {
#pragma unroll
    for (int r = 0; r < 4; ++r)
      Lpart[(size_t)sp * N_ + i0 + w * 16 + quad * 4 + r] = lsum[r];
  }
}

__global__ __launch_bounds__(128) void k_attn_merge(const float* __restrict__ Opart,
      const float* __restrict__ Lpart, float* __restrict__ outp) {
  int i = blockIdx.x, t = threadIdx.x;
  float lg = 0.f;
#pragma unroll
  for (int s = 0; s < JSPLIT; ++s) lg += Lpart[(size_t)s * N_ + i];
  float inv = (lg > 0.f) ? 1.f / lg : 0.f;
  float acc = 0.f;
#pragma unroll
  for (int s = 0; s < JSPLIT; ++s)
    acc += Opart[((size_t)s * N_ + i) * H_ + t];
  outp[(size_t)i * H_ + t] = acc * inv;
}

// ---------------- elementwise ----------------
__global__ __launch_bounds__(256) void k_sub2(const float4* __restrict__ a,
      const float4* __restrict__ b, float4* __restrict__ o) {
  int i = blockIdx.x * 256 + threadIdx.x;
  float4 x = a[i], y = b[i], r;
  r.x = x.x - y.x; r.y = x.y - y.y; r.z = x.z - y.z; r.w = x.w - y.w;
  o[i] = r;
}

__global__ __launch_bounds__(256) void k_sub3(const float4* __restrict__ a,
      const float4* __restrict__ b, const float4* __restrict__ c, float4* __restrict__ o) {
  int i = blockIdx.x * 256 + threadIdx.x;
  float4 x = a[i], y = b[i], z = c[i], r;
  r.x = x.x - y.x - z.x; r.y = x.y - y.y - z.y; r.z = x.z - y.z - z.z; r.w = x.w - y.w - z.w;
  o[i] = r;
}

__global__ __launch_bounds__(128) void k_pred(const float* __restrict__ a,
      const float* __restrict__ b, const float* __restrict__ c,
      const float* __restrict__ wout, const float* __restrict__ bout,
      float* __restrict__ outp) {
  __shared__ float buf[128];
  int i = blockIdx.x, t = threadIdx.x;
  size_t idx = (size_t)i * H_ + t;
  float v = (a[idx] + b[idx] + c[idx]) * wout[t];
  float s = bred_sum128(v, buf);
  if (t == 0) outp[i] = s + bout[0];
}

// ---------------- host ----------------
extern "C" void kernel_launch(void* const* d_in, const int* in_sizes, int n_in,
                              void* d_out, int out_size, void* d_ws, size_t ws_size,
                              hipStream_t stream) {
  const float* x          = (const float*)d_in[0];
  const float* mv         = (const float*)d_in[1];
  const int*   cm         = (const int*)d_in[2];
  const float* W_ps       = (const float*)d_in[3];
  const float* b_ps       = (const float*)d_in[4];
  const float* W_hs       = (const float*)d_in[5];
  const float* b_hs       = (const float*)d_in[6];
  const float* W_ps_fore  = (const float*)d_in[7];
  const float* b_ps_fore  = (const float*)d_in[8];
  const float* W_hs_fore  = (const float*)d_in[9];
  const float* b_hs_fore  = (const float*)d_in[10];
  const float* W_ps_back  = (const float*)d_in[11];
  const float* b_ps_back  = (const float*)d_in[12];
  const float* W_hs_back  = (const float*)d_in[13];
  const float* b_hs_back  = (const float*)d_in[14];
  const float* W_indi     = (const float*)d_in[15];
  const float* b_indi     = (const float*)d_in[16];
  const float* W_out      = (const float*)d_in[23];
  const float* b_out      = (const float*)d_in[24];
  float* outp = (float*)d_out;

  float* W = (float*)d_ws;
  const size_t NC = (size_t)N_ * C_;   // NC = 4*NH
  const size_t NH = (size_t)N_ * H_;
  const size_t CH = (size_t)C_ * H_;
  float* Sbuf = W;
  float* pback   = Sbuf;
  float* outps   = Sbuf + NH;
  float* hback   = Sbuf + 2 * NH;
  float* outindi = Sbuf + 3 * NH;
  size_t off = NC;
  float* T1       = W + off; off += NH;
  float* p_shared = W + off; off += NH;
  float* h_shared = W + off; off += NH;
  float* hidden3  = W + off; off += NH;
  float* h_info   = W + off; off += NH;
  float* out_hs   = W + off; off += NH;
  float* hidden1  = W + off; off += CH;
  float* hidden2  = W + off; off += CH;
  float* colsum1   = W + off; off += C_;
  float* colmax    = W + off; off += C_;
  float* colsumexp = W + off; off += C_;
  float* rny2      = W + off; off += C_;
  float* partb     = W + off; off += 32 * C_;
  float* rnx     = W + off; off += N_;
  float* rqh     = W + off; off += N_;
  float* diagv   = W + off; off += N_;
  float* colsum3 = W + off; off += N_;
  float* rn3     = W + off; off += N_;
  float* gvals   = W + off; off += 3 * N_;
  float* Lpart   = W + off; off += (size_t)JSPLIT * N_;
  float* keepf   = W + off; off += N_;
  int* keep1 = (int*)(W + off); off += C_;
  int* keep2 = (int*)(W + off); off += N_;
  int* gidx  = (int*)(W + off); off += 3 * N_;
  ushort* Qn = (ushort*)(W + off); off += NH / 2;
  ushort* Kn = (ushort*)(W + off); off += NH / 2;
  ushort* Vt = (ushort*)(W + off); off += NH / 2;
  float* Opart = W + off; off += (size_t)JSPLIT * NH;   // stage-5 only
  // Gram scratch ALIASES Opart (stage-4 only; disjoint in time from attention):
  ushort* Ghi = (ushort*)Opart;
  ushort* Glo = Ghi + NH;
  int*    Gip = (int*)(Opart + NH);

  hipMemsetAsync(colsum1, 0, C_ * sizeof(float), stream);
  hipMemsetAsync(hidden1, 0, CH * sizeof(float), stream);
  hipMemsetAsync(hidden2, 0, CH * sizeof(float), stream);
  hipMemsetAsync(hidden3, 0, NH * sizeof(float), stream);
  hipMemsetAsync(colsum3, 0, N_ * sizeof(float), stream);

  // stage 1: market-value aggregation
  k_colsum1<<<dim3(2, 32), 256, 0, stream>>>(cm, mv, colsum1);
  k_agg<0><<<dim3(16, 8), 256, 0, stream>>>(x, cm, mv, nullptr, nullptr, hidden1);
  k_fin_hidden1<<<C_, 128, 0, stream>>>(hidden1, colsum1, keep1);
  k_rowstats<<<N_, 128, 0, stream>>>(x, rnx, nullptr, nullptr);

  // stage 2: softmax over stocks, hidden2
  k_gemm<1, 0><<<dim3(C_ / 64, N_ / 64), 256, 0, stream>>>(
      x, H_, hidden1, H_, Sbuf, C_, N_, C_, H_, nullptr, nullptr, nullptr);
  k_colmax_part<<<32, 256, 0, stream>>>(Sbuf, partb);
  k_colfin_max<<<1, 512, 0, stream>>>(partb, colmax);
  k_colsum_part<<<32, 256, 0, stream>>>(Sbuf, colmax, partb);
  k_colfin_sum<<<1, 512, 0, stream>>>(partb, colsumexp);
  k_agg<1><<<dim3(16, 8), 256, 0, stream>>>(x, nullptr, nullptr, Sbuf, colmax, hidden2);
  k_fin_hidden2<<<C_, 128, 0, stream>>>(hidden2, colsumexp, rny2);

  // stage 3: c2s softmax + p branch
  k_gemm<1, 0><<<dim3(C_ / 64, N_ / 64), 256, 0, stream>>>(
      x, H_, hidden2, H_, Sbuf, C_, N_, C_, H_, nullptr, rnx, rny2);
  k_rowsoftmax<<<N_, 256, 0, stream>>>(Sbuf, keep1);
  k_gemm<0, 0><<<dim3(H_ / 64, N_ / 64), 256, 0, stream>>>(
      Sbuf, C_, hidden2, H_, T1, H_, N_, H_, C_, nullptr, nullptr, nullptr);
  k_gemm<0, 0><<<dim3(2, 128), 256, 0, stream>>>(
      T1, H_, W_ps, H_, p_shared, H_, N_, H_, H_, b_ps, nullptr, nullptr);
  k_gemm<0, 0><<<dim3(2, 128), 256, 0, stream>>>(
      p_shared, H_, W_ps_back, H_, pback, H_, N_, H_, H_, b_ps_back, nullptr, nullptr);
  k_gemm<0, 1><<<dim3(2, 128), 256, 0, stream>>>(
      p_shared, H_, W_ps_fore, H_, outps, H_, N_, H_, H_, b_ps_fore, nullptr, nullptr);

  // stage 4: h_shared, N x N top-3 graph (MFMA candidates + exact rescore)
  k_sub2<<<NH / 4 / 256, 256, 0, stream>>>((const float4*)x, (const float4*)pback,
                                           (float4*)h_shared);
  k_rowstats<<<N_, 128, 0, stream>>>(h_shared, rqh, diagv, nullptr);
  k_prep_gram<<<N_ / 8, 256, 0, stream>>>(h_shared, rqh, Ghi, Glo);
  k_gram_mfma<<<dim3(N_ / 64, GSPLIT), 256, 0, stream>>>(Ghi, Glo, Gip);
  k_gram_rescore<<<N_ / 4, 256, 0, stream>>>(h_shared, rqh, Gip, gvals, gidx);
  k_scatter<<<N_, 128, 0, stream>>>(h_shared, gvals, gidx, hidden3, colsum3);
  k_h3fin<<<N_, 128, 0, stream>>>(hidden3, h_shared, colsum3, diagv, rn3, keep2);

  // stage 5: MFMA flash attention (fixed-max, LDS-staged K/V), h branch
  k_prep_attn<<<N_ / 64, 256, 0, stream>>>(h_shared, hidden3, rqh, rn3, keep2,
                                           Qn, Kn, Vt, keepf);
  k_attn_mfma<<<dim3(N_ / 64, JSPLIT), 256, 0, stream>>>(Qn, Kn, Vt, keepf,
                                                         Opart, Lpart);
  k_attn_merge<<<N_, 128, 0, stream>>>(Opart, Lpart, T1);
  k_gemm<0, 0><<<dim3(2, 128), 256, 0, stream>>>(
      T1, H_, W_hs, H_, h_info, H_, N_, H_, H_, b_hs, nullptr, nullptr);
  k_gemm<0, 0><<<dim3(2, 128), 256, 0, stream>>>(
      h_info, H_, W_hs_back, H_, hback, H_, N_, H_, H_, b_hs_back, nullptr, nullptr);
  k_gemm<0, 1><<<dim3(2, 128), 256, 0, stream>>>(
      h_info, H_, W_hs_fore, H_, out_hs, H_, N_, H_, H_, b_hs_fore, nullptr, nullptr);

  // stage 6: individual branch + final projection
  k_sub3<<<NH / 4 / 256, 256, 0, stream>>>((const float4*)x, (const float4*)pback,
                                           (const float4*)hback, (float4*)h_shared);
  k_gemm<0, 1><<<dim3(2, 128), 256, 0, stream>>>(
      h_shared, H_, W_indi, H_, outindi, H_, N_, H_, H_, b_indi, nullptr, nullptr);
  k_pred<<<N_, 128, 0, stream>>>(outps, out_hs, outindi, W_out, b_out, outp);
}

// Round 7
// 774.590 us; speedup vs baseline: 1.6317x; 1.2677x over previous
//
#include <hip/hip_runtime.h>
#include <float.h>
#include <math.h>

#define N_ 8192
#define C_ 512
#define H_ 128

typedef __attribute__((ext_vector_type(8))) short bfrag;
typedef __attribute__((ext_vector_type(4))) float f4;

__device__ __forceinline__ ushort f2bf(float f) {
  unsigned u = __float_as_uint(f);
  unsigned r = (u + 0x7fffu + ((u >> 16) & 1u)) >> 16;
  return (ushort)r;
}

// ---------------- helpers ----------------
__device__ __forceinline__ float bred_sum128(float v, float* buf) {
  int t = threadIdx.x;
  buf[t] = v; __syncthreads();
  for (int s = 64; s > 0; s >>= 1) {
    if (t < s) buf[t] += buf[t + s];
    __syncthreads();
  }
  float r = buf[0]; __syncthreads();
  return r;
}

__device__ __forceinline__ void top3_ins(float (&tv)[3], int (&ti)[3], float v, int j) {
  bool b2 = (v > tv[2]) || (v == tv[2] && j < ti[2]);
  if (!b2) return;
  bool b1 = (v > tv[1]) || (v == tv[1] && j < ti[1]);
  if (b1) {
    tv[2] = tv[1]; ti[2] = ti[1];
    bool b0 = (v > tv[0]) || (v == tv[0] && j < ti[0]);
    if (b0) { tv[1] = tv[0]; ti[1] = ti[0]; tv[0] = v; ti[0] = j; }
    else    { tv[1] = v;     ti[1] = j; }
  } else { tv[2] = v; ti[2] = j; }
}

// ---------------- stage 1: concept aggregation ----------------
__global__ __launch_bounds__(256) void k_colsum1(const int* __restrict__ cm,
      const float* __restrict__ mv, float* __restrict__ colsum1) {
  int t = threadIdx.x;
  int c = blockIdx.x * 256 + t;
  int r0 = blockIdx.y * 64;
  float acc = 0.f;
  for (int r = 0; r < 64; ++r) {
    int i = r0 + r;
    acc += (float)cm[(size_t)i * C_ + c] * mv[i];
  }
  atomicAdd(&colsum1[c], acc);
}

// grid (C/32, N/128): 1024 blocks -> 4 blocks/CU (was 128 blocks: half the GPU idle)
template<int MODE>
__global__ __launch_bounds__(256) void k_agg(const float* __restrict__ x,
      const int* __restrict__ cm, const float* __restrict__ mv,
      const float* __restrict__ S, const float* __restrict__ colmax,
      float* __restrict__ outCH) {
  __shared__ float ws[8][32];
  int t = threadIdx.x;
  int cbase = blockIdx.x * 32;
  int h = t & 127, half = t >> 7;
  float acc[16];
#pragma unroll
  for (int k = 0; k < 16; ++k) acc[k] = 0.f;
  int sr = t >> 5, sc = t & 31;
  for (int sub = 0; sub < 16; ++sub) {
    int ibase = blockIdx.y * 128 + sub * 8;
    {
      int i = ibase + sr, c = cbase + sc;
      float w;
      if (MODE == 0) w = cm[(size_t)i * C_ + c] ? mv[i] : 0.f;
      else           w = __expf(S[(size_t)i * C_ + c] - colmax[c]);
      ws[sr][sc] = w;
    }
    __syncthreads();
#pragma unroll
    for (int r = 0; r < 8; ++r) {
      float xv = x[(size_t)(ibase + r) * H_ + h];
      const float* wr = &ws[r][half * 16];
#pragma unroll
      for (int k = 0; k < 16; ++k) acc[k] += wr[k] * xv;
    }
    __syncthreads();
  }
#pragma unroll
  for (int k = 0; k < 16; ++k)
    atomicAdd(&outCH[(size_t)(cbase + half * 16 + k) * H_ + h], acc[k]);
}

__global__ __launch_bounds__(128) void k_fin_hidden1(float* __restrict__ h1,
      const float* __restrict__ colsum1, int* __restrict__ keep1) {
  __shared__ float buf[128];
  int c = blockIdx.x, t = threadIdx.x;
  float v = h1[(size_t)c * H_ + t] / (colsum1[c] + 1.f);
  h1[(size_t)c * H_ + t] = v;
  float sm = bred_sum128(v, buf);
  if (t == 0) keep1[c] = (sm != 0.f) ? 1 : 0;
}

__global__ __launch_bounds__(128) void k_fin_hidden2(float* __restrict__ h2,
      const float* __restrict__ colsumexp, float* __restrict__ rny) {
  __shared__ float buf[128];
  int c = blockIdx.x, t = threadIdx.x;
  float v = h2[(size_t)c * H_ + t] / colsumexp[c];
  h2[(size_t)c * H_ + t] = v;
  float ss = bred_sum128(v * v, buf);
  if (t == 0) rny[c] = (ss > 0.f) ? 1.f / sqrtf(ss) : 0.f;
}

__global__ __launch_bounds__(128) void k_rowstats(const float* __restrict__ A,
      float* __restrict__ rinv, float* __restrict__ diag, int* __restrict__ keep) {
  __shared__ float buf[128];
  int i = blockIdx.x, t = threadIdx.x;
  float v = A[(size_t)i * H_ + t];
  float ss = bred_sum128(v * v, buf);
  float sm = bred_sum128(v, buf);
  if (t == 0) {
    float nr = sqrtf(ss);
    if (rinv) rinv[i] = (ss > 0.f) ? 1.f / nr : 0.f;
    if (diag) diag[i] = (ss > 0.f) ? ss / (nr * nr) : 0.f;
    if (keep) keep[i] = (sm != 0.f) ? 1 : 0;
  }
}

// ---------------- generic fp32 tiled GEMM ----------------
template<int TRANSB, int ACT>
__global__ __launch_bounds__(256) void k_gemm(const float* __restrict__ A, int lda,
      const float* __restrict__ B, int ldb, float* __restrict__ Cc, int ldc,
      int M, int Nn, int Kk, const float* __restrict__ bias,
      const float* __restrict__ rowscale, const float* __restrict__ colscale) {
  __shared__ float As[16][68];
  __shared__ float Bs[16][68];
  int t = threadIdx.x;
  int n0 = blockIdx.x * 64, m0 = blockIdx.y * 64;
  int ty = t >> 4, tx = t & 15;
  float acc[4][4] = {};
  for (int k0 = 0; k0 < Kk; k0 += 16) {
#pragma unroll
    for (int li = t; li < 1024; li += 256) {
      int r = li >> 4, c = li & 15;
      As[c][r] = A[(size_t)(m0 + r) * lda + k0 + c];
    }
    if (TRANSB) {
#pragma unroll
      for (int li = t; li < 1024; li += 256) {
        int r = li >> 4, c = li & 15;
        Bs[c][r] = B[(size_t)(n0 + r) * ldb + k0 + c];
      }
    } else {
#pragma unroll
      for (int li = t; li < 1024; li += 256) {
        int nn = li & 63, c = li >> 6;
        Bs[c][nn] = B[(size_t)(k0 + c) * ldb + n0 + nn];
      }
    }
    __syncthreads();
#pragma unroll
    for (int kk = 0; kk < 16; ++kk) {
      float4 av = *(const float4*)&As[kk][ty * 4];
      float4 bv = *(const float4*)&Bs[kk][tx * 4];
      float a0 = av.x, a1 = av.y, a2 = av.z, a3 = av.w;
      float b0 = bv.x, b1 = bv.y, b2 = bv.z, b3 = bv.w;
      acc[0][0] += a0 * b0; acc[0][1] += a0 * b1; acc[0][2] += a0 * b2; acc[0][3] += a0 * b3;
      acc[1][0] += a1 * b0; acc[1][1] += a1 * b1; acc[1][2] += a1 * b2; acc[1][3] += a1 * b3;
      acc[2][0] += a2 * b0; acc[2][1] += a2 * b1; acc[2][2] += a2 * b2; acc[2][3] += a2 * b3;
      acc[3][0] += a3 * b0; acc[3][1] += a3 * b1; acc[3][2] += a3 * b2; acc[3][3] += a3 * b3;
    }
    __syncthreads();
  }
#pragma unroll
  for (int ii = 0; ii < 4; ++ii) {
    int row = m0 + ty * 4 + ii;
    float rs = rowscale ? rowscale[row] : 1.f;
#pragma unroll
    for (int jj = 0; jj < 4; ++jj) {
      int col = n0 + tx * 4 + jj;
      float v = acc[ii][jj] * rs;
      if (colscale) v *= colscale[col];
      if (bias) v += bias[col];
      if (ACT) v = (v > 0.f) ? v : 0.01f * v;
      Cc[(size_t)row * ldc + col] = v;
    }
  }
}

// ---------------- column softmax over S[N,C] ----------------
#define CPB 128   // partial blocks for column reductions
__global__ __launch_bounds__(256) void k_colmax_part(const float* __restrict__ S,
      float* __restrict__ part) {
  int t = threadIdx.x, b = blockIdx.x;
  int r0 = b * (N_ / CPB);
  float m0 = -FLT_MAX, m1 = -FLT_MAX;
  for (int r = 0; r < N_ / CPB; ++r) {
    const float* row = S + (size_t)(r0 + r) * C_;
    m0 = fmaxf(m0, row[t]);
    m1 = fmaxf(m1, row[t + 256]);
  }
  part[(size_t)b * C_ + t] = m0;
  part[(size_t)b * C_ + t + 256] = m1;
}

__global__ __launch_bounds__(256) void k_colsum_part(const float* __restrict__ S,
      const float* __restrict__ colmax, float* __restrict__ part) {
  int t = threadIdx.x, b = blockIdx.x;
  int r0 = b * (N_ / CPB);
  float cm0 = colmax[t], cm1 = colmax[t + 256];
  float s0 = 0.f, s1 = 0.f;
  for (int r = 0; r < N_ / CPB; ++r) {
    const float* row = S + (size_t)(r0 + r) * C_;
    s0 += __expf(row[t] - cm0);
    s1 += __expf(row[t + 256] - cm1);
  }
  part[(size_t)b * C_ + t] = s0;
  part[(size_t)b * C_ + t + 256] = s1;
}

__global__ __launch_bounds__(512) void k_colfin_max(const float* __restrict__ part,
      float* __restrict__ outv) {
  int c = threadIdx.x;
  float m = -FLT_MAX;
  for (int b = 0; b < CPB; ++b) m = fmaxf(m, part[(size_t)b * C_ + c]);
  outv[c] = m;
}

__global__ __launch_bounds__(512) void k_colfin_sum(const float* __restrict__ part,
      float* __restrict__ outv) {
  int c = threadIdx.x;
  float s = 0.f;
  for (int b = 0; b < CPB; ++b) s += part[(size_t)b * C_ + c];
  outv[c] = s;
}

// ---------------- row softmax (512 cols) with keep mask ----------------
__global__ __launch_bounds__(256) void k_rowsoftmax(float* __restrict__ Sm,
      const int* __restrict__ keep1) {
  __shared__ float buf[256];
  int i = blockIdx.x, t = threadIdx.x;
  float* row = Sm + (size_t)i * C_;
  int k0 = keep1[t], k1 = keep1[t + 256];
  float v0 = k0 ? row[t] : -FLT_MAX;
  float v1 = k1 ? row[t + 256] : -FLT_MAX;
  buf[t] = fmaxf(v0, v1); __syncthreads();
  for (int s = 128; s > 0; s >>= 1) {
    if (t < s) buf[t] = fmaxf(buf[t], buf[t + s]);
    __syncthreads();
  }
  float m = buf[0]; __syncthreads();
  float e0 = k0 ? expf(v0 - m) : 0.f;
  float e1 = k1 ? expf(v1 - m) : 0.f;
  buf[t] = e0 + e1; __syncthreads();
  for (int s = 128; s > 0; s >>= 1) {
    if (t < s) buf[t] += buf[t + s];
    __syncthreads();
  }
  float inv = 1.f / buf[0];
  row[t] = e0 * inv;
  row[t + 256] = e1 * inv;
}

// ---------------- gram prep: normalized rows split into bf16 hi + lo ----------------
__global__ __launch_bounds__(256) void k_prep_gram(const float* __restrict__ hs,
      const float* __restrict__ rn, ushort* __restrict__ Ghi, ushort* __restrict__ Glo) {
  int t = threadIdx.x;
  int row = blockIdx.x * 8 + (t >> 5);
  int c = (t & 31) * 4;
  float r = rn[row];
  float4 v = *(const float4*)&hs[(size_t)row * H_ + c];
  float q[4] = {v.x * r, v.y * r, v.z * r, v.w * r};
  ushort hi[4], lo[4];
#pragma unroll
  for (int k = 0; k < 4; ++k) {
    hi[k] = f2bf(q[k]);
    float hf = __uint_as_float(((unsigned)hi[k]) << 16);
    lo[k] = f2bf(q[k] - hf);
  }
  *(ushort4*)&Ghi[(size_t)row * H_ + c] = *(ushort4*)hi;
  *(ushort4*)&Glo[(size_t)row * H_ + c] = *(ushort4*)lo;
}

// ---------------- N x N Gram: 4-wave blocks, LDS-staged j-tiles, top-3 candidates ----
#define GSPLIT 8
__global__ __launch_bounds__(256) void k_gram_mfma(const ushort* __restrict__ Ghi,
      const ushort* __restrict__ Glo, int* __restrict__ Gip) {
  __shared__ ushort JH[64 * 136];   // stride 136 shorts = 68 dwords === 4 mod 32: 2-way max
  __shared__ ushort JL[64 * 136];
  int t = threadIdx.x;
  int l = t & 63, w = t >> 6;
  int lo16 = l & 15, quad = l >> 4;
  int i0 = blockIdx.x * 64;
  int sp = blockIdx.y;
  const int jspan = N_ / GSPLIT;   // 1024

  bfrag ahi[4], alo[4];
#pragma unroll
  for (int kc = 0; kc < 4; ++kc) {
    size_t base = (size_t)(i0 + w * 16 + lo16) * H_ + kc * 32 + quad * 8;
    ahi[kc] = *(const bfrag*)&Ghi[base];
    alo[kc] = *(const bfrag*)&Glo[base];
  }

  float tv[4][3]; int ti[4][3];
#pragma unroll
  for (int r = 0; r < 4; ++r)
#pragma unroll
    for (int s = 0; s < 3; ++s) { tv[r][s] = -FLT_MAX; ti[r][s] = 0x7fffffff; }

  int srow = t >> 2, scol = (t & 3) * 32;
  for (int jt = 0; jt < jspan / 64; ++jt) {
    int j0 = sp * jspan + jt * 64;
    __syncthreads();
    {
      const ushort* gh = &Ghi[(size_t)(j0 + srow) * H_ + scol];
      const ushort* gl = &Glo[(size_t)(j0 + srow) * H_ + scol];
      ushort* dh = &JH[srow * 136 + scol];
      ushort* dl = &JL[srow * 136 + scol];
#pragma unroll
      for (int u = 0; u < 32; u += 4) {
        *(ushort4*)&dh[u] = *(const ushort4*)&gh[u];
        *(ushort4*)&dl[u] = *(const ushort4*)&gl[u];
      }
    }
    __syncthreads();
#pragma unroll
    for (int js = 0; js < 4; ++js) {
      int jl_ = js * 16 + lo16;
      int j = j0 + jl_;
      bfrag bhi[4], blo[4];
#pragma unroll
      for (int kc = 0; kc < 4; ++kc) {
        int base = jl_ * 136 + kc * 32 + quad * 8;
        bhi[kc] = *(const bfrag*)&JH[base];
        blo[kc] = *(const bfrag*)&JL[base];
      }
      f4 ahh = (f4){0.f, 0.f, 0.f, 0.f};
      f4 ahl = (f4){0.f, 0.f, 0.f, 0.f};
      f4 alh = (f4){0.f, 0.f, 0.f, 0.f};
#pragma unroll
      for (int kc = 0; kc < 4; ++kc) {
        ahh = __builtin_amdgcn_mfma_f32_16x16x32_bf16(ahi[kc], bhi[kc], ahh, 0, 0, 0);
        ahl = __builtin_amdgcn_mfma_f32_16x16x32_bf16(ahi[kc], blo[kc], ahl, 0, 0, 0);
        alh = __builtin_amdgcn_mfma_f32_16x16x32_bf16(alo[kc], bhi[kc], alh, 0, 0, 0);
      }
#pragma unroll
      for (int r = 0; r < 4; ++r) {
        int gi = i0 + w * 16 + quad * 4 + r;
        float v = (j == gi) ? 0.f : (ahh[r] + ahl[r] + alh[r]);
        top3_ins(tv[r], ti[r], v, j);
      }
    }
  }
  // block-wide top-3 reduce; reuse staging LDS as scratch
  __syncthreads();
  float* svf = (float*)JH;
  int*   sif = (int*)JL;
#pragma unroll
  for (int r = 0; r < 4; ++r)
#pragma unroll
    for (int s = 0; s < 3; ++s) {
      svf[t * 12 + r * 3 + s] = tv[r][s];
      sif[t * 12 + r * 3 + s] = ti[r][s];
    }
  __syncthreads();
  if (t < 64) {
    int ww = t >> 4, qr = t & 15;
    int r2 = qr & 3, quad2 = qr >> 2;
    float bv[3] = {-FLT_MAX, -FLT_MAX, -FLT_MAX};
    int bi[3] = {0x7fffffff, 0x7fffffff, 0x7fffffff};
    for (int u = 0; u < 16; ++u) {
      int src = ww * 64 + quad2 * 16 + u;
#pragma unroll
      for (int s = 0; s < 3; ++s)
        top3_ins(bv, bi, svf[src * 12 + r2 * 3 + s], sif[src * 12 + r2 * 3 + s]);
    }
#pragma unroll
    for (int s = 0; s < 3; ++s)
      Gip[((size_t)sp * N_ + i0 + t) * 3 + s] = bi[s];
  }
}

// ---------------- exact fp32 rescore of 24 candidates/row -> final top-3 -------------
__global__ __launch_bounds__(256) void k_gram_rescore(const float* __restrict__ hs,
      const float* __restrict__ rn, const int* __restrict__ Gip,
      float* __restrict__ gvals, int* __restrict__ gidx) {
  int row = blockIdx.x * 4 + (threadIdx.x >> 6);
  int lane = threadIdx.x & 63;
  const float* qr = &hs[(size_t)row * H_];
  float q0 = qr[lane], q1 = qr[lane + 64];
  float rni = rn[row];
  float bv[3] = {-FLT_MAX, -FLT_MAX, -FLT_MAX};
  int bi[3] = {0x7fffffff, 0x7fffffff, 0x7fffffff};
  for (int s = 0; s < GSPLIT; ++s)
#pragma unroll
    for (int k = 0; k < 3; ++k) {
      int j = Gip[((size_t)s * N_ + row) * 3 + k];
      const float* jr = &hs[(size_t)j * H_];
      float d = q0 * jr[lane] + q1 * jr[lane + 64];
#pragma unroll
      for (int x = 1; x < 64; x <<= 1) d += __shfl_xor(d, x, 64);
      float v = (j == row) ? 0.f : d * rni * rn[j];
      top3_ins(bv, bi, v, j);
    }
  if (lane == 0) {
#pragma unroll
    for (int s = 0; s < 3; ++s) {
      gvals[(size_t)row * 3 + s] = bv[s];
      gidx[(size_t)row * 3 + s] = bi[s];
    }
  }
}

// ---------------- sparse scatter: hidden3 = hs2c^T @ h_shared ----------------
__global__ __launch_bounds__(128) void k_scatter(const float* __restrict__ hs,
      const float* __restrict__ gvals, const int* __restrict__ gidx,
      float* __restrict__ hidden3, float* __restrict__ colsum3) {
  int i = blockIdx.x, t = threadIdx.x;
  float xs = hs[(size_t)i * H_ + t];
#pragma unroll
  for (int k = 0; k < 3; ++k) {
    int j = gidx[i * 3 + k];
    float v = gvals[i * 3 + k];
    atomicAdd(&hidden3[(size_t)j * H_ + t], v * xs);
  }
  if (t == 0) {
#pragma unroll
    for (int k = 0; k < 3; ++k) atomicAdd(&colsum3[gidx[i * 3 + k]], gvals[i * 3 + k]);
  }
}

__global__ __launch_bounds__(128) void k_h3fin(float* __restrict__ hidden3,
      const float* __restrict__ hs, const float* __restrict__ colsum3,
      const float* __restrict__ diagv, float* __restrict__ rn3, int* __restrict__ keep2) {
  __shared__ float buf[128];
  int j = blockIdx.x, t = threadIdx.x;
  float v = hidden3[(size_t)j * H_ + t];
  if (colsum3[j] != 0.f) v += diagv[j] * hs[(size_t)j * H_ + t];
  hidden3[(size_t)j * H_ + t] = v;
  float ss = bred_sum128(v * v, buf);
  float sm = bred_sum128(v, buf);
  if (t == 0) {
    rn3[j] = (ss > 0.f) ? 1.f / sqrtf(ss) : 0.f;
    keep2[j] = (sm != 0.f) ? 1 : 0;
  }
}

// ---------------- attention prep: bf16 Qn/Kn, transposed V, keep as float ----------
__global__ __launch_bounds__(256) void k_prep_attn(const float* __restrict__ hs,
      const float* __restrict__ h3, const float* __restrict__ rqh,
      const float* __restrict__ rn3, const int* __restrict__ keep2,
      ushort* __restrict__ Qn, ushort* __restrict__ Kn, ushort* __restrict__ Vt,
      float* __restrict__ keepf) {
  __shared__ ushort T[H_][68];
  int t = threadIdx.x;
  int i0 = blockIdx.x * 64;
  int r = i0 + (t >> 2);
  int c0 = (t & 3) * 32;
  float rq = rqh[r], r3 = rn3[r];
  for (int c = c0; c < c0 + 32; c += 4) {
    float4 hv = *(const float4*)&hs[(size_t)r * H_ + c];
    float4 h3v = *(const float4*)&h3[(size_t)r * H_ + c];
    ushort q4[4] = {f2bf(hv.x * rq), f2bf(hv.y * rq), f2bf(hv.z * rq), f2bf(hv.w * rq)};
    ushort k4[4] = {f2bf(h3v.x * r3), f2bf(h3v.y * r3), f2bf(h3v.z * r3), f2bf(h3v.w * r3)};
    *(ushort4*)&Qn[(size_t)r * H_ + c] = *(ushort4*)q4;
    *(ushort4*)&Kn[(size_t)r * H_ + c] = *(ushort4*)k4;
    T[c + 0][r - i0] = f2bf(h3v.x);
    T[c + 1][r - i0] = f2bf(h3v.y);
    T[c + 2][r - i0] = f2bf(h3v.z);
    T[c + 3][r - i0] = f2bf(h3v.w);
  }
  if (t < 64) keepf[i0 + t] = (float)keep2[i0 + t];
  __syncthreads();
  int h = t >> 1, off = (t & 1) * 32;
  for (int u = 0; u < 32; u += 4) {
    ushort4 vv;
    vv.x = T[h][off + u]; vv.y = T[h][off + u + 1];
    vv.z = T[h][off + u + 2]; vv.w = T[h][off + u + 3];
    *(ushort4*)&Vt[(size_t)h * N_ + i0 + off + u] = vv;
  }
}

// ---------------- MFMA flash attention: 4-wave blocks, LDS-staged K/V, fixed-max ----
#define JSPLIT 8
__global__ __launch_bounds__(256) void k_attn_mfma(const ushort* __restrict__ Qn,
      const ushort* __restrict__ Kn, const ushort* __restrict__ Vt,
      const float* __restrict__ keepf, float* __restrict__ Opart,
      float* __restrict__ Lpart) {
  __shared__ ushort Ks[64 * 136];      // [j][k] stride 136
  __shared__ ushort Vs[128 * 72];      // [h][j] stride 72
  __shared__ ushort Ps[4][16 * 72];    // per-wave P tile
  int t = threadIdx.x;
  int l = t & 63, w = t >> 6;
  int lo16 = l & 15, quad = l >> 4;
  int i0 = blockIdx.x * 64;
  int sp = blockIdx.y;
  const int jspan = N_ / JSPLIT;   // 1024

  bfrag aq[4];
#pragma unroll
  for (int kc = 0; kc < 4; ++kc)
    aq[kc] = *(const bfrag*)&Qn[(size_t)(i0 + w * 16 + lo16) * H_ + kc * 32 + quad * 8];

  f4 O[8];
#pragma unroll
  for (int ns = 0; ns < 8; ++ns) O[ns] = (f4){0.f, 0.f, 0.f, 0.f};
  f4 lsum = (f4){0.f, 0.f, 0.f, 0.f};

  int krow = t >> 2, kcol = (t & 3) * 32;
  int vrow = t >> 1, vcol = (t & 1) * 32;
  for (int jt = 0; jt < jspan / 64; ++jt) {
    int j0 = sp * jspan + jt * 64;
    __syncthreads();
    {
      const ushort* gk = &Kn[(size_t)(j0 + krow) * H_ + kcol];
      ushort* dk = &Ks[krow * 136 + kcol];
#pragma unroll
      for (int u = 0; u < 32; u += 4)
        *(ushort4*)&dk[u] = *(const ushort4*)&gk[u];
      const ushort* gv = &Vt[(size_t)vrow * N_ + j0 + vcol];
      ushort* dv = &Vs[vrow * 72 + vcol];
#pragma unroll
      for (int u = 0; u < 32; u += 4)
        *(ushort4*)&dv[u] = *(const ushort4*)&gv[u];
    }
    __syncthreads();
    float kp[4];
#pragma unroll
    for (int js = 0; js < 4; ++js) kp[js] = keepf[j0 + js * 16 + lo16];
    f4 S[4];
#pragma unroll
    for (int js = 0; js < 4; ++js) {
      f4 acc = (f4){0.f, 0.f, 0.f, 0.f};
#pragma unroll
      for (int kc = 0; kc < 4; ++kc) {
        bfrag b = *(const bfrag*)&Ks[(js * 16 + lo16) * 136 + kc * 32 + quad * 8];
        acc = __builtin_amdgcn_mfma_f32_16x16x32_bf16(aq[kc], b, acc, 0, 0, 0);
      }
      S[js] = acc;
    }
#pragma unroll
    for (int js = 0; js < 4; ++js)
#pragma unroll
      for (int r = 0; r < 4; ++r) {
        float p = kp[js] * __expf(S[js][r] - 1.f);
        lsum[r] += p;
        Ps[w][(quad * 4 + r) * 72 + js * 16 + lo16] = f2bf(p);
      }
    __syncthreads();
#pragma unroll
    for (int kc = 0; kc < 2; ++kc) {
      bfrag ap = *(const bfrag*)&Ps[w][lo16 * 72 + kc * 32 + quad * 8];
#pragma unroll
      for (int ns = 0; ns < 8; ++ns) {
        bfrag bv = *(const bfrag*)&Vs[(ns * 16 + lo16) * 72 + kc * 32 + quad * 8];
        O[ns] = __builtin_amdgcn_mfma_f32_16x16x32_bf16(ap, bv, O[ns], 0, 0, 0);
      }
    }
  }
  // write partial O (unnormalized)
#pragma unroll
  for (int ns = 0; ns < 8; ++ns)
#pragma unroll
    for (int r = 0; r < 4; ++r) {
      int row = i0 + w * 16 + quad * 4 + r;
      Opart[((size_t)sp * N_ + row) * H_ + ns * 16 + lo16] = O[ns][r];
    }
#pragma unroll
  for (int x = 1; x <= 8; x <<= 1)
#pragma unroll
    for (int r = 0; r < 4; ++r) lsum[r] += __shfl_xor(lsum[r], x, 16);
  if (lo16 == 0) {
#pragma unroll
    for (int r = 0; r < 4; ++r)
      Lpart[(size_t)sp * N_ + i0 + w * 16 + quad * 4 + r] = lsum[r];
  }
}

__global__ __launch_bounds__(128) void k_attn_merge(const float* __restrict__ Opart,
      const float* __restrict__ Lpart, float* __restrict__ outp) {
  int i = blockIdx.x, t = threadIdx.x;
  float lg = 0.f;
#pragma unroll
  for (int s = 0; s < JSPLIT; ++s) lg += Lpart[(size_t)s * N_ + i];
  float inv = (lg > 0.f) ? 1.f / lg : 0.f;
  float acc = 0.f;
#pragma unroll
  for (int s = 0; s < JSPLIT; ++s)
    acc += Opart[((size_t)s * N_ + i) * H_ + t];
  outp[(size_t)i * H_ + t] = acc * inv;
}

// ---------------- elementwise ----------------
__global__ __launch_bounds__(256) void k_sub2(const float4* __restrict__ a,
      const float4* __restrict__ b, float4* __restrict__ o) {
  int i = blockIdx.x * 256 + threadIdx.x;
  float4 x = a[i], y = b[i], r;
  r.x = x.x - y.x; r.y = x.y - y.y; r.z = x.z - y.z; r.w = x.w - y.w;
  o[i] = r;
}

__global__ __launch_bounds__(256) void k_sub3(const float4* __restrict__ a,
      const float4* __restrict__ b, const float4* __restrict__ c, float4* __restrict__ o) {
  int i = blockIdx.x * 256 + threadIdx.x;
  float4 x = a[i], y = b[i], z = c[i], r;
  r.x = x.x - y.x - z.x; r.y = x.y - y.y - z.y; r.z = x.z - y.z - z.z; r.w = x.w - y.w - z.w;
  o[i] = r;
}

__global__ __launch_bounds__(128) void k_pred(const float* __restrict__ a,
      const float* __restrict__ b, const float* __restrict__ c,
      const float* __restrict__ wout, const float* __restrict__ bout,
      float* __restrict__ outp) {
  __shared__ float buf[128];
  int i = blockIdx.x, t = threadIdx.x;
  size_t idx = (size_t)i * H_ + t;
  float v = (a[idx] + b[idx] + c[idx]) * wout[t];
  float s = bred_sum128(v, buf);
  if (t == 0) outp[i] = s + bout[0];
}

// ---------------- host ----------------
extern "C" void kernel_launch(void* const* d_in, const int* in_sizes, int n_in,
                              void* d_out, int out_size, void* d_ws, size_t ws_size,
                              hipStream_t stream) {
  const float* x          = (const float*)d_in[0];
  const float* mv         = (const float*)d_in[1];
  const int*   cm         = (const int*)d_in[2];
  const float* W_ps       = (const float*)d_in[3];
  const float* b_ps       = (const float*)d_in[4];
  const float* W_hs       = (const float*)d_in[5];
  const float* b_hs       = (const float*)d_in[6];
  const float* W_ps_fore  = (const float*)d_in[7];
  const float* b_ps_fore  = (const float*)d_in[8];
  const float* W_hs_fore  = (const float*)d_in[9];
  const float* b_hs_fore  = (const float*)d_in[10];
  const float* W_ps_back  = (const float*)d_in[11];
  const float* b_ps_back  = (const float*)d_in[12];
  const float* W_hs_back  = (const float*)d_in[13];
  const float* b_hs_back  = (const float*)d_in[14];
  const float* W_indi     = (const float*)d_in[15];
  const float* b_indi     = (const float*)d_in[16];
  const float* W_out      = (const float*)d_in[23];
  const float* b_out      = (const float*)d_in[24];
  float* outp = (float*)d_out;

  float* W = (float*)d_ws;
  const size_t NC = (size_t)N_ * C_;   // NC = 4*NH
  const size_t NH = (size_t)N_ * H_;
  const size_t CH = (size_t)C_ * H_;
  float* Sbuf = W;
  float* pback   = Sbuf;
  float* outps   = Sbuf + NH;
  float* hback   = Sbuf + 2 * NH;
  float* outindi = Sbuf + 3 * NH;
  size_t off = NC;
  float* T1       = W + off; off += NH;
  float* p_shared = W + off; off += NH;
  float* h_shared = W + off; off += NH;
  float* hidden3  = W + off; off += NH;
  float* h_info   = W + off; off += NH;
  float* out_hs   = W + off; off += NH;
  float* hidden1  = W + off; off += CH;
  float* hidden2  = W + off; off += CH;
  float* colsum1   = W + off; off += C_;
  float* colmax    = W + off; off += C_;
  float* colsumexp = W + off; off += C_;
  float* rny2      = W + off; off += C_;
  float* partb     = W + off; off += (size_t)CPB * C_;
  float* rnx     = W + off; off += N_;
  float* rqh     = W + off; off += N_;
  float* diagv   = W + off; off += N_;
  float* colsum3 = W + off; off += N_;
  float* rn3     = W + off; off += N_;
  float* gvals   = W + off; off += 3 * N_;
  float* Lpart   = W + off; off += (size_t)JSPLIT * N_;
  float* keepf   = W + off; off += N_;
  int* keep1 = (int*)(W + off); off += C_;
  int* keep2 = (int*)(W + off); off += N_;
  int* gidx  = (int*)(W + off); off += 3 * N_;
  ushort* Qn = (ushort*)(W + off); off += NH / 2;
  ushort* Kn = (ushort*)(W + off); off += NH / 2;
  ushort* Vt = (ushort*)(W + off); off += NH / 2;
  float* Opart = W + off; off += (size_t)JSPLIT * NH;   // stage-5 only
  // Gram scratch ALIASES Opart (stage-4 only; disjoint in time from attention):
  ushort* Ghi = (ushort*)Opart;
  ushort* Glo = Ghi + NH;
  int*    Gip = (int*)(Opart + NH);

  hipMemsetAsync(colsum1, 0, C_ * sizeof(float), stream);
  hipMemsetAsync(hidden1, 0, CH * sizeof(float), stream);
  hipMemsetAsync(hidden2, 0, CH * sizeof(float), stream);
  hipMemsetAsync(hidden3, 0, NH * sizeof(float), stream);
  hipMemsetAsync(colsum3, 0, N_ * sizeof(float), stream);

  // stage 1: market-value aggregation
  k_colsum1<<<dim3(2, 128), 256, 0, stream>>>(cm, mv, colsum1);
  k_agg<0><<<dim3(16, 64), 256, 0, stream>>>(x, cm, mv, nullptr, nullptr, hidden1);
  k_fin_hidden1<<<C_, 128, 0, stream>>>(hidden1, colsum1, keep1);
  k_rowstats<<<N_, 128, 0, stream>>>(x, rnx, nullptr, nullptr);

  // stage 2: softmax over stocks, hidden2
  k_gemm<1, 0><<<dim3(C_ / 64, N_ / 64), 256, 0, stream>>>(
      x, H_, hidden1, H_, Sbuf, C_, N_, C_, H_, nullptr, nullptr, nullptr);
  k_colmax_part<<<CPB, 256, 0, stream>>>(Sbuf, partb);
  k_colfin_max<<<1, 512, 0, stream>>>(partb, colmax);
  k_colsum_part<<<CPB, 256, 0, stream>>>(Sbuf, colmax, partb);
  k_colfin_sum<<<1, 512, 0, stream>>>(partb, colsumexp);
  k_agg<1><<<dim3(16, 64), 256, 0, stream>>>(x, nullptr, nullptr, Sbuf, colmax, hidden2);
  k_fin_hidden2<<<C_, 128, 0, stream>>>(hidden2, colsumexp, rny2);

  // stage 3: c2s softmax + p branch
  k_gemm<1, 0><<<dim3(C_ / 64, N_ / 64), 256, 0, stream>>>(
      x, H_, hidden2, H_, Sbuf, C_, N_, C_, H_, nullptr, rnx, rny2);
  k_rowsoftmax<<<N_, 256, 0, stream>>>(Sbuf, keep1);
  k_gemm<0, 0><<<dim3(H_ / 64, N_ / 64), 256, 0, stream>>>(
      Sbuf, C_, hidden2, H_, T1, H_, N_, H_, C_, nullptr, nullptr, nullptr);
  k_gemm<0, 0><<<dim3(2, 128), 256, 0, stream>>>(
      T1, H_, W_ps, H_, p_shared, H_, N_, H_, H_, b_ps, nullptr, nullptr);
  k_gemm<0, 0><<<dim3(2, 128), 256, 0, stream>>>(
      p_shared, H_, W_ps_back, H_, pback, H_, N_, H_, H_, b_ps_back, nullptr, nullptr);
  k_gemm<0, 1><<<dim3(2, 128), 256, 0, stream>>>(
      p_shared, H_, W_ps_fore, H_, outps, H_, N_, H_, H_, b_ps_fore, nullptr, nullptr);

  // stage 4: h_shared, N x N top-3 graph (MFMA candidates + exact rescore)
  k_sub2<<<NH / 4 / 256, 256, 0, stream>>>((const float4*)x, (const float4*)pback,
                                           (float4*)h_shared);
  k_rowstats<<<N_, 128, 0, stream>>>(h_shared, rqh, diagv, nullptr);
  k_prep_gram<<<N_ / 8, 256, 0, stream>>>(h_shared, rqh, Ghi, Glo);
  k_gram_mfma<<<dim3(N_ / 64, GSPLIT), 256, 0, stream>>>(Ghi, Glo, Gip);
  k_gram_rescore<<<N_ / 4, 256, 0, stream>>>(h_shared, rqh, Gip, gvals, gidx);
  k_scatter<<<N_, 128, 0, stream>>>(h_shared, gvals, gidx, hidden3, colsum3);
  k_h3fin<<<N_, 128, 0, stream>>>(hidden3, h_shared, colsum3, diagv, rn3, keep2);

  // stage 5: MFMA flash attention (fixed-max, LDS-staged K/V), h branch
  k_prep_attn<<<N_ / 64, 256, 0, stream>>>(h_shared, hidden3, rqh, rn3, keep2,
                                           Qn, Kn, Vt, keepf);
  k_attn_mfma<<<dim3(N_ / 64, JSPLIT), 256, 0, stream>>>(Qn, Kn, Vt, keepf,
                                                         Opart, Lpart);
  k_attn_merge<<<N_, 128, 0, stream>>>(Opart, Lpart, T1);
  k_gemm<0, 0><<<dim3(2, 128), 256, 0, stream>>>(
      T1, H_, W_hs, H_, h_info, H_, N_, H_, H_, b_hs, nullptr, nullptr);
  k_gemm<0, 0><<<dim3(2, 128), 256, 0, stream>>>(
      h_info, H_, W_hs_back, H_, hback, H_, N_, H_, H_, b_hs_back, nullptr, nullptr);
  k_gemm<0, 1><<<dim3(2, 128), 256, 0, stream>>>(
      h_info, H_, W_hs_fore, H_, out_hs, H_, N_, H_, H_, b_hs_fore, nullptr, nullptr);

  // stage 6: individual branch + final projection
  k_sub3<<<NH / 4 / 256, 256, 0, stream>>>((const float4*)x, (const float4*)pback,
                                           (const float4*)hback, (float4*)h_shared);
  k_gemm<0, 1><<<dim3(2, 128), 256, 0, stream>>>(
      h_shared, H_, W_indi, H_, outindi, H_, N_, H_, H_, b_indi, nullptr, nullptr);
  k_pred<<<N_, 128, 0, stream>>>(outps, out_hs, outindi, W_out, b_out, outp);
}

// Round 8
// 733.997 us; speedup vs baseline: 1.7219x; 1.0553x over previous
//
#include <hip/hip_runtime.h>
#include <float.h>
#include <math.h>

#define N_ 8192
#define C_ 512
#define H_ 128

typedef __attribute__((ext_vector_type(8))) short bfrag;
typedef __attribute__((ext_vector_type(4))) float f4;

__device__ __forceinline__ ushort f2bf(float f) {
  unsigned u = __float_as_uint(f);
  unsigned r = (u + 0x7fffu + ((u >> 16) & 1u)) >> 16;
  return (ushort)r;
}

// ---------------- helpers ----------------
__device__ __forceinline__ float bred_sum128(float v, float* buf) {
  int t = threadIdx.x;
  buf[t] = v; __syncthreads();
  for (int s = 64; s > 0; s >>= 1) {
    if (t < s) buf[t] += buf[t + s];
    __syncthreads();
  }
  float r = buf[0]; __syncthreads();
  return r;
}

// full insert with index tie-break (lowest index wins on ties)
__device__ __forceinline__ void top3_ins(float (&tv)[3], int (&ti)[3], float v, int j) {
  bool b2 = (v > tv[2]) || (v == tv[2] && j < ti[2]);
  if (!b2) return;
  bool b1 = (v > tv[1]) || (v == tv[1] && j < ti[1]);
  if (b1) {
    tv[2] = tv[1]; ti[2] = ti[1];
    bool b0 = (v > tv[0]) || (v == tv[0] && j < ti[0]);
    if (b0) { tv[1] = tv[0]; ti[1] = ti[0]; tv[0] = v; ti[0] = j; }
    else    { tv[1] = v;     ti[1] = j; }
  } else { tv[2] = v; ti[2] = j; }
}

// fast insert, no tie-break: per-lane stream is j-ascending, strict > keeps lowest j on ties
__device__ __forceinline__ void top3_fast(float (&tv)[3], int (&ti)[3], float v, int j) {
  if (v <= tv[2]) return;
  if (v > tv[1]) {
    tv[2] = tv[1]; ti[2] = ti[1];
    if (v > tv[0]) { tv[1] = tv[0]; ti[1] = ti[0]; tv[0] = v; ti[0] = j; }
    else           { tv[1] = v;     ti[1] = j; }
  } else { tv[2] = v; ti[2] = j; }
}

// ---------------- stage 1: concept aggregation ----------------
__global__ __launch_bounds__(256) void k_colsum1(const int* __restrict__ cm,
      const float* __restrict__ mv, float* __restrict__ colsum1) {
  int t = threadIdx.x;
  int c = blockIdx.x * 256 + t;
  int r0 = blockIdx.y * 64;
  float acc = 0.f;
  for (int r = 0; r < 64; ++r) {
    int i = r0 + r;
    acc += (float)cm[(size_t)i * C_ + c] * mv[i];
  }
  atomicAdd(&colsum1[c], acc);
}

template<int MODE>
__global__ __launch_bounds__(256) void k_agg(const float* __restrict__ x,
      const int* __restrict__ cm, const float* __restrict__ mv,
      const float* __restrict__ S, const float* __restrict__ colmax,
      float* __restrict__ outCH) {
  __shared__ float ws[8][32];
  int t = threadIdx.x;
  int cbase = blockIdx.x * 32;
  int h = t & 127, half = t >> 7;
  float acc[16];
#pragma unroll
  for (int k = 0; k < 16; ++k) acc[k] = 0.f;
  int sr = t >> 5, sc = t & 31;
  for (int sub = 0; sub < 16; ++sub) {
    int ibase = blockIdx.y * 128 + sub * 8;
    {
      int i = ibase + sr, c = cbase + sc;
      float w;
      if (MODE == 0) w = cm[(size_t)i * C_ + c] ? mv[i] : 0.f;
      else           w = __expf(S[(size_t)i * C_ + c] - colmax[c]);
      ws[sr][sc] = w;
    }
    __syncthreads();
#pragma unroll
    for (int r = 0; r < 8; ++r) {
      float xv = x[(size_t)(ibase + r) * H_ + h];
      const float* wr = &ws[r][half * 16];
#pragma unroll
      for (int k = 0; k < 16; ++k) acc[k] += wr[k] * xv;
    }
    __syncthreads();
  }
#pragma unroll
  for (int k = 0; k < 16; ++k)
    atomicAdd(&outCH[(size_t)(cbase + half * 16 + k) * H_ + h], acc[k]);
}

__global__ __launch_bounds__(128) void k_fin_hidden1(float* __restrict__ h1,
      const float* __restrict__ colsum1, int* __restrict__ keep1) {
  __shared__ float buf[128];
  int c = blockIdx.x, t = threadIdx.x;
  float v = h1[(size_t)c * H_ + t] / (colsum1[c] + 1.f);
  h1[(size_t)c * H_ + t] = v;
  float sm = bred_sum128(v, buf);
  if (t == 0) keep1[c] = (sm != 0.f) ? 1 : 0;
}

__global__ __launch_bounds__(128) void k_fin_hidden2(float* __restrict__ h2,
      const float* __restrict__ colsumexp, float* __restrict__ rny) {
  __shared__ float buf[128];
  int c = blockIdx.x, t = threadIdx.x;
  float v = h2[(size_t)c * H_ + t] / colsumexp[c];
  h2[(size_t)c * H_ + t] = v;
  float ss = bred_sum128(v * v, buf);
  if (t == 0) rny[c] = (ss > 0.f) ? 1.f / sqrtf(ss) : 0.f;
}

__global__ __launch_bounds__(128) void k_rowstats(const float* __restrict__ A,
      float* __restrict__ rinv, float* __restrict__ diag, int* __restrict__ keep) {
  __shared__ float buf[128];
  int i = blockIdx.x, t = threadIdx.x;
  float v = A[(size_t)i * H_ + t];
  float ss = bred_sum128(v * v, buf);
  float sm = bred_sum128(v, buf);
  if (t == 0) {
    float nr = sqrtf(ss);
    if (rinv) rinv[i] = (ss > 0.f) ? 1.f / nr : 0.f;
    if (diag) diag[i] = (ss > 0.f) ? ss / (nr * nr) : 0.f;
    if (keep) keep[i] = (sm != 0.f) ? 1 : 0;
  }
}

// ---------------- generic fp32 tiled GEMM ----------------
template<int TRANSB, int ACT>
__global__ __launch_bounds__(256) void k_gemm(const float* __restrict__ A, int lda,
      const float* __restrict__ B, int ldb, float* __restrict__ Cc, int ldc,
      int M, int Nn, int Kk, const float* __restrict__ bias,
      const float* __restrict__ rowscale, const float* __restrict__ colscale) {
  __shared__ float As[16][68];
  __shared__ float Bs[16][68];
  int t = threadIdx.x;
  int n0 = blockIdx.x * 64, m0 = blockIdx.y * 64;
  int ty = t >> 4, tx = t & 15;
  float acc[4][4] = {};
  for (int k0 = 0; k0 < Kk; k0 += 16) {
#pragma unroll
    for (int li = t; li < 1024; li += 256) {
      int r = li >> 4, c = li & 15;
      As[c][r] = A[(size_t)(m0 + r) * lda + k0 + c];
    }
    if (TRANSB) {
#pragma unroll
      for (int li = t; li < 1024; li += 256) {
        int r = li >> 4, c = li & 15;
        Bs[c][r] = B[(size_t)(n0 + r) * ldb + k0 + c];
      }
    } else {
#pragma unroll
      for (int li = t; li < 1024; li += 256) {
        int nn = li & 63, c = li >> 6;
        Bs[c][nn] = B[(size_t)(k0 + c) * ldb + n0 + nn];
      }
    }
    __syncthreads();
#pragma unroll
    for (int kk = 0; kk < 16; ++kk) {
      float4 av = *(const float4*)&As[kk][ty * 4];
      float4 bv = *(const float4*)&Bs[kk][tx * 4];
      float a0 = av.x, a1 = av.y, a2 = av.z, a3 = av.w;
      float b0 = bv.x, b1 = bv.y, b2 = bv.z, b3 = bv.w;
      acc[0][0] += a0 * b0; acc[0][1] += a0 * b1; acc[0][2] += a0 * b2; acc[0][3] += a0 * b3;
      acc[1][0] += a1 * b0; acc[1][1] += a1 * b1; acc[1][2] += a1 * b2; acc[1][3] += a1 * b3;
      acc[2][0] += a2 * b0; acc[2][1] += a2 * b1; acc[2][2] += a2 * b2; acc[2][3] += a2 * b3;
      acc[3][0] += a3 * b0; acc[3][1] += a3 * b1; acc[3][2] += a3 * b2; acc[3][3] += a3 * b3;
    }
    __syncthreads();
  }
#pragma unroll
  for (int ii = 0; ii < 4; ++ii) {
    int row = m0 + ty * 4 + ii;
    float rs = rowscale ? rowscale[row] : 1.f;
#pragma unroll
    for (int jj = 0; jj < 4; ++jj) {
      int col = n0 + tx * 4 + jj;
      float v = acc[ii][jj] * rs;
      if (colscale) v *= colscale[col];
      if (bias) v += bias[col];
      if (ACT) v = (v > 0.f) ? v : 0.01f * v;
      Cc[(size_t)row * ldc + col] = v;
    }
  }
}

// ---------------- column softmax over S[N,C] ----------------
#define CPB 128
__global__ __launch_bounds__(256) void k_colmax_part(const float* __restrict__ S,
      float* __restrict__ part) {
  int t = threadIdx.x, b = blockIdx.x;
  int r0 = b * (N_ / CPB);
  float m0 = -FLT_MAX, m1 = -FLT_MAX;
  for (int r = 0; r < N_ / CPB; ++r) {
    const float* row = S + (size_t)(r0 + r) * C_;
    m0 = fmaxf(m0, row[t]);
    m1 = fmaxf(m1, row[t + 256]);
  }
  part[(size_t)b * C_ + t] = m0;
  part[(size_t)b * C_ + t + 256] = m1;
}

__global__ __launch_bounds__(256) void k_colsum_part(const float* __restrict__ S,
      const float* __restrict__ colmax, float* __restrict__ part) {
  int t = threadIdx.x, b = blockIdx.x;
  int r0 = b * (N_ / CPB);
  float cm0 = colmax[t], cm1 = colmax[t + 256];
  float s0 = 0.f, s1 = 0.f;
  for (int r = 0; r < N_ / CPB; ++r) {
    const float* row = S + (size_t)(r0 + r) * C_;
    s0 += __expf(row[t] - cm0);
    s1 += __expf(row[t + 256] - cm1);
  }
  part[(size_t)b * C_ + t] = s0;
  part[(size_t)b * C_ + t + 256] = s1;
}

__global__ __launch_bounds__(512) void k_colfin_max(const float* __restrict__ part,
      float* __restrict__ outv) {
  int c = threadIdx.x;
  float m = -FLT_MAX;
  for (int b = 0; b < CPB; ++b) m = fmaxf(m, part[(size_t)b * C_ + c]);
  outv[c] = m;
}

__global__ __launch_bounds__(512) void k_colfin_sum(const float* __restrict__ part,
      float* __restrict__ outv) {
  int c = threadIdx.x;
  float s = 0.f;
  for (int b = 0; b < CPB; ++b) s += part[(size_t)b * C_ + c];
  outv[c] = s;
}

// ---------------- row softmax (512 cols) with keep mask ----------------
__global__ __launch_bounds__(256) void k_rowsoftmax(float* __restrict__ Sm,
      const int* __restrict__ keep1) {
  __shared__ float buf[256];
  int i = blockIdx.x, t = threadIdx.x;
  float* row = Sm + (size_t)i * C_;
  int k0 = keep1[t], k1 = keep1[t + 256];
  float v0 = k0 ? row[t] : -FLT_MAX;
  float v1 = k1 ? row[t + 256] : -FLT_MAX;
  buf[t] = fmaxf(v0, v1); __syncthreads();
  for (int s = 128; s > 0; s >>= 1) {
    if (t < s) buf[t] = fmaxf(buf[t], buf[t + s]);
    __syncthreads();
  }
  float m = buf[0]; __syncthreads();
  float e0 = k0 ? expf(v0 - m) : 0.f;
  float e1 = k1 ? expf(v1 - m) : 0.f;
  buf[t] = e0 + e1; __syncthreads();
  for (int s = 128; s > 0; s >>= 1) {
    if (t < s) buf[t] += buf[t + s];
    __syncthreads();
  }
  float inv = 1.f / buf[0];
  row[t] = e0 * inv;
  row[t + 256] = e1 * inv;
}

// ---------------- gram prep: normalized rows split into bf16 hi + lo ----------------
__global__ __launch_bounds__(256) void k_prep_gram(const float* __restrict__ hs,
      const float* __restrict__ rn, ushort* __restrict__ Ghi, ushort* __restrict__ Glo) {
  int t = threadIdx.x;
  int row = blockIdx.x * 8 + (t >> 5);
  int c = (t & 31) * 4;
  float r = rn[row];
  float4 v = *(const float4*)&hs[(size_t)row * H_ + c];
  float q[4] = {v.x * r, v.y * r, v.z * r, v.w * r};
  ushort hi[4], lo[4];
#pragma unroll
  for (int k = 0; k < 4; ++k) {
    hi[k] = f2bf(q[k]);
    float hf = __uint_as_float(((unsigned)hi[k]) << 16);
    lo[k] = f2bf(q[k] - hf);
  }
  *(ushort4*)&Ghi[(size_t)row * H_ + c] = *(ushort4*)hi;
  *(ushort4*)&Glo[(size_t)row * H_ + c] = *(ushort4*)lo;
}

// ---------------- N x N Gram: 4-wave blocks, 32 rows/wave (2 m-tiles), LDS j-tiles ---
// Fragments amortized over 2 m-tiles (half the LDS read volume per unit MFMA work).
// Per-row top-3 reduced in-wave via shfl butterfly (rows are wave-owned).
#define GSPLIT 8
__global__ __launch_bounds__(256) void k_gram_mfma(const ushort* __restrict__ Ghi,
      const ushort* __restrict__ Glo, int* __restrict__ Gip) {
  __shared__ ushort JH[64 * 136];
  __shared__ ushort JL[64 * 136];
  int t = threadIdx.x;
  int l = t & 63, w = t >> 6;
  int lo16 = l & 15, quad = l >> 4;
  int i0 = blockIdx.x * 128;
  int rbase = i0 + w * 32;
  int sp = blockIdx.y;
  const int jspan = N_ / GSPLIT;   // 1024

  bfrag ahi[2][4], alo[2][4];
#pragma unroll
  for (int mt = 0; mt < 2; ++mt)
#pragma unroll
    for (int kc = 0; kc < 4; ++kc) {
      size_t base = (size_t)(rbase + mt * 16 + lo16) * H_ + kc * 32 + quad * 8;
      ahi[mt][kc] = *(const bfrag*)&Ghi[base];
      alo[mt][kc] = *(const bfrag*)&Glo[base];
    }

  float tv[2][4][3]; int ti[2][4][3];
#pragma unroll
  for (int mt = 0; mt < 2; ++mt)
#pragma unroll
    for (int r = 0; r < 4; ++r)
#pragma unroll
      for (int s = 0; s < 3; ++s) { tv[mt][r][s] = -FLT_MAX; ti[mt][r][s] = 0x7fffffff; }

  int srow = t >> 2, scol = (t & 3) * 32;
  for (int jt = 0; jt < jspan / 64; ++jt) {
    int j0 = sp * jspan + jt * 64;
    __syncthreads();
    {
      const ushort* gh = &Ghi[(size_t)(j0 + srow) * H_ + scol];
      const ushort* gl = &Glo[(size_t)(j0 + srow) * H_ + scol];
      ushort* dh = &JH[srow * 136 + scol];
      ushort* dl = &JL[srow * 136 + scol];
#pragma unroll
      for (int u = 0; u < 32; u += 4) {
        *(ushort4*)&dh[u] = *(const ushort4*)&gh[u];
        *(ushort4*)&dl[u] = *(const ushort4*)&gl[u];
      }
    }
    __syncthreads();
#pragma unroll
    for (int js = 0; js < 4; ++js) {
      int jl_ = js * 16 + lo16;
      int j = j0 + jl_;
      bfrag bhi[4], blo[4];
#pragma unroll
      for (int kc = 0; kc < 4; ++kc) {
        int base = jl_ * 136 + kc * 32 + quad * 8;
        bhi[kc] = *(const bfrag*)&JH[base];
        blo[kc] = *(const bfrag*)&JL[base];
      }
#pragma unroll
      for (int mt = 0; mt < 2; ++mt) {
        f4 ahh = (f4){0.f, 0.f, 0.f, 0.f};
        f4 ahl = (f4){0.f, 0.f, 0.f, 0.f};
        f4 alh = (f4){0.f, 0.f, 0.f, 0.f};
#pragma unroll
        for (int kc = 0; kc < 4; ++kc) {
          ahh = __builtin_amdgcn_mfma_f32_16x16x32_bf16(ahi[mt][kc], bhi[kc], ahh, 0, 0, 0);
          ahl = __builtin_amdgcn_mfma_f32_16x16x32_bf16(ahi[mt][kc], blo[kc], ahl, 0, 0, 0);
          alh = __builtin_amdgcn_mfma_f32_16x16x32_bf16(alo[mt][kc], bhi[kc], alh, 0, 0, 0);
        }
#pragma unroll
        for (int r = 0; r < 4; ++r) {
          int gi = rbase + mt * 16 + quad * 4 + r;
          float v = (j == gi) ? 0.f : (ahh[r] + ahl[r] + alh[r]);
          top3_fast(tv[mt][r], ti[mt][r], v, j);
        }
      }
    }
  }
  // in-wave butterfly merge across the 16 lanes (same quad group) sharing each row
#pragma unroll
  for (int mt = 0; mt < 2; ++mt)
#pragma unroll
    for (int r = 0; r < 4; ++r) {
#pragma unroll
      for (int x = 1; x <= 8; x <<= 1) {
        float vv[3]; int ii[3];
#pragma unroll
        for (int s = 0; s < 3; ++s) {
          vv[s] = __shfl_xor(tv[mt][r][s], x, 16);
          ii[s] = __shfl_xor(ti[mt][r][s], x, 16);
        }
#pragma unroll
        for (int s = 0; s < 3; ++s) top3_ins(tv[mt][r], ti[mt][r], vv[s], ii[s]);
      }
    }
  if (lo16 == 0) {
#pragma unroll
    for (int mt = 0; mt < 2; ++mt)
#pragma unroll
      for (int r = 0; r < 4; ++r) {
        int row = rbase + mt * 16 + quad * 4 + r;
#pragma unroll
        for (int s = 0; s < 3; ++s)
          Gip[((size_t)sp * N_ + row) * 3 + s] = ti[mt][r][s];
      }
  }
}

// ---------------- exact fp32 rescore of 24 candidates/row -> final top-3 -------------
__global__ __launch_bounds__(256) void k_gram_rescore(const float* __restrict__ hs,
      const float* __restrict__ rn, const int* __restrict__ Gip,
      float* __restrict__ gvals, int* __restrict__ gidx) {
  int row = blockIdx.x * 4 + (threadIdx.x >> 6);
  int lane = threadIdx.x & 63;
  const float* qr = &hs[(size_t)row * H_];
  float q0 = qr[lane], q1 = qr[lane + 64];
  float rni = rn[row];
  float bv[3] = {-FLT_MAX, -FLT_MAX, -FLT_MAX};
  int bi[3] = {0x7fffffff, 0x7fffffff, 0x7fffffff};
  for (int s = 0; s < GSPLIT; ++s)
#pragma unroll
    for (int k = 0; k < 3; ++k) {
      int j = Gip[((size_t)s * N_ + row) * 3 + k];
      const float* jr = &hs[(size_t)j * H_];
      float d = q0 * jr[lane] + q1 * jr[lane + 64];
#pragma unroll
      for (int x = 1; x < 64; x <<= 1) d += __shfl_xor(d, x, 64);
      float v = (j == row) ? 0.f : d * rni * rn[j];
      top3_ins(bv, bi, v, j);
    }
  if (lane == 0) {
#pragma unroll
    for (int s = 0; s < 3; ++s) {
      gvals[(size_t)row * 3 + s] = bv[s];
      gidx[(size_t)row * 3 + s] = bi[s];
    }
  }
}

// ---------------- sparse scatter: hidden3 = hs2c^T @ h_shared ----------------
__global__ __launch_bounds__(128) void k_scatter(const float* __restrict__ hs,
      const float* __restrict__ gvals, const int* __restrict__ gidx,
      float* __restrict__ hidden3, float* __restrict__ colsum3) {
  int i = blockIdx.x, t = threadIdx.x;
  float xs = hs[(size_t)i * H_ + t];
#pragma unroll
  for (int k = 0; k < 3; ++k) {
    int j = gidx[i * 3 + k];
    float v = gvals[i * 3 + k];
    atomicAdd(&hidden3[(size_t)j * H_ + t], v * xs);
  }
  if (t == 0) {
#pragma unroll
    for (int k = 0; k < 3; ++k) atomicAdd(&colsum3[gidx[i * 3 + k]], gvals[i * 3 + k]);
  }
}

__global__ __launch_bounds__(128) void k_h3fin(float* __restrict__ hidden3,
      const float* __restrict__ hs, const float* __restrict__ colsum3,
      const float* __restrict__ diagv, float* __restrict__ rn3, int* __restrict__ keep2) {
  __shared__ float buf[128];
  int j = blockIdx.x, t = threadIdx.x;
  float v = hidden3[(size_t)j * H_ + t];
  if (colsum3[j] != 0.f) v += diagv[j] * hs[(size_t)j * H_ + t];
  hidden3[(size_t)j * H_ + t] = v;
  float ss = bred_sum128(v * v, buf);
  float sm = bred_sum128(v, buf);
  if (t == 0) {
    rn3[j] = (ss > 0.f) ? 1.f / sqrtf(ss) : 0.f;
    keep2[j] = (sm != 0.f) ? 1 : 0;
  }
}

// ---------------- attention prep: bf16 Qn/Kn, transposed V, keep as float ----------
__global__ __launch_bounds__(256) void k_prep_attn(const float* __restrict__ hs,
      const float* __restrict__ h3, const float* __restrict__ rqh,
      const float* __restrict__ rn3, const int* __restrict__ keep2,
      ushort* __restrict__ Qn, ushort* __restrict__ Kn, ushort* __restrict__ Vt,
      float* __restrict__ keepf) {
  __shared__ ushort T[H_][68];
  int t = threadIdx.x;
  int i0 = blockIdx.x * 64;
  int r = i0 + (t >> 2);
  int c0 = (t & 3) * 32;
  float rq = rqh[r], r3 = rn3[r];
  for (int c = c0; c < c0 + 32; c += 4) {
    float4 hv = *(const float4*)&hs[(size_t)r * H_ + c];
    float4 h3v = *(const float4*)&h3[(size_t)r * H_ + c];
    ushort q4[4] = {f2bf(hv.x * rq), f2bf(hv.y * rq), f2bf(hv.z * rq), f2bf(hv.w * rq)};
    ushort k4[4] = {f2bf(h3v.x * r3), f2bf(h3v.y * r3), f2bf(h3v.z * r3), f2bf(h3v.w * r3)};
    *(ushort4*)&Qn[(size_t)r * H_ + c] = *(ushort4*)q4;
    *(ushort4*)&Kn[(size_t)r * H_ + c] = *(ushort4*)k4;
    T[c + 0][r - i0] = f2bf(h3v.x);
    T[c + 1][r - i0] = f2bf(h3v.y);
    T[c + 2][r - i0] = f2bf(h3v.z);
    T[c + 3][r - i0] = f2bf(h3v.w);
  }
  if (t < 64) keepf[i0 + t] = (float)keep2[i0 + t];
  __syncthreads();
  int h = t >> 1, off = (t & 1) * 32;
  for (int u = 0; u < 32; u += 4) {
    ushort4 vv;
    vv.x = T[h][off + u]; vv.y = T[h][off + u + 1];
    vv.z = T[h][off + u + 2]; vv.w = T[h][off + u + 3];
    *(ushort4*)&Vt[(size_t)h * N_ + i0 + off + u] = vv;
  }
}

// ---------------- MFMA flash attention: 4-wave blocks, 32 rows/wave, LDS K/V --------
#define JSPLIT 8
__global__ __launch_bounds__(256) void k_attn_mfma(const ushort* __restrict__ Qn,
      const ushort* __restrict__ Kn, const ushort* __restrict__ Vt,
      const float* __restrict__ keepf, float* __restrict__ Opart,
      float* __restrict__ Lpart) {
  __shared__ ushort Ks[64 * 136];      // [j][k] stride 136
  __shared__ ushort Vs[128 * 72];      // [h][j] stride 72
  __shared__ ushort Ps[4][32 * 72];    // per-wave P tile (32 q-rows x 64 j)
  int t = threadIdx.x;
  int l = t & 63, w = t >> 6;
  int lo16 = l & 15, quad = l >> 4;
  int i0 = blockIdx.x * 128;
  int rbase = i0 + w * 32;
  int sp = blockIdx.y;
  const int jspan = N_ / JSPLIT;   // 1024

  bfrag aq[2][4];
#pragma unroll
  for (int mt = 0; mt < 2; ++mt)
#pragma unroll
    for (int kc = 0; kc < 4; ++kc)
      aq[mt][kc] = *(const bfrag*)&Qn[(size_t)(rbase + mt * 16 + lo16) * H_ + kc * 32 + quad * 8];

  f4 O[2][8];
#pragma unroll
  for (int mt = 0; mt < 2; ++mt)
#pragma unroll
    for (int ns = 0; ns < 8; ++ns) O[mt][ns] = (f4){0.f, 0.f, 0.f, 0.f};
  f4 lsum[2];
  lsum[0] = (f4){0.f, 0.f, 0.f, 0.f};
  lsum[1] = (f4){0.f, 0.f, 0.f, 0.f};

  int krow = t >> 2, kcol = (t & 3) * 32;
  int vrow = t >> 1, vcol = (t & 1) * 32;
  for (int jt = 0; jt < jspan / 64; ++jt) {
    int j0 = sp * jspan + jt * 64;
    __syncthreads();
    {
      const ushort* gk = &Kn[(size_t)(j0 + krow) * H_ + kcol];
      ushort* dk = &Ks[krow * 136 + kcol];
#pragma unroll
      for (int u = 0; u < 32; u += 4)
        *(ushort4*)&dk[u] = *(const ushort4*)&gk[u];
      const ushort* gv = &Vt[(size_t)vrow * N_ + j0 + vcol];
      ushort* dv = &Vs[vrow * 72 + vcol];
#pragma unroll
      for (int u = 0; u < 32; u += 4)
        *(ushort4*)&dv[u] = *(const ushort4*)&gv[u];
    }
    __syncthreads();
    float kp[4];
#pragma unroll
    for (int js = 0; js < 4; ++js) kp[js] = keepf[j0 + js * 16 + lo16];
#pragma unroll
    for (int js = 0; js < 4; ++js) {
      bfrag bk[4];
#pragma unroll
      for (int kc = 0; kc < 4; ++kc)
        bk[kc] = *(const bfrag*)&Ks[(js * 16 + lo16) * 136 + kc * 32 + quad * 8];
#pragma unroll
      for (int mt = 0; mt < 2; ++mt) {
        f4 acc = (f4){0.f, 0.f, 0.f, 0.f};
#pragma unroll
        for (int kc = 0; kc < 4; ++kc)
          acc = __builtin_amdgcn_mfma_f32_16x16x32_bf16(aq[mt][kc], bk[kc], acc, 0, 0, 0);
#pragma unroll
        for (int r = 0; r < 4; ++r) {
          float p = kp[js] * __expf(acc[r] - 1.f);   // cos-sim scores bounded: fixed max
          lsum[mt][r] += p;
          Ps[w][(mt * 16 + quad * 4 + r) * 72 + js * 16 + lo16] = f2bf(p);
        }
      }
    }
    // no barrier needed: Ps is per-wave; Vs stays valid until next loop-top barrier
#pragma unroll
    for (int kc = 0; kc < 2; ++kc) {
      bfrag ap0 = *(const bfrag*)&Ps[w][lo16 * 72 + kc * 32 + quad * 8];
      bfrag ap1 = *(const bfrag*)&Ps[w][(16 + lo16) * 72 + kc * 32 + quad * 8];
#pragma unroll
      for (int ns = 0; ns < 8; ++ns) {
        bfrag bv = *(const bfrag*)&Vs[(ns * 16 + lo16) * 72 + kc * 32 + quad * 8];
        O[0][ns] = __builtin_amdgcn_mfma_f32_16x16x32_bf16(ap0, bv, O[0][ns], 0, 0, 0);
        O[1][ns] = __builtin_amdgcn_mfma_f32_16x16x32_bf16(ap1, bv, O[1][ns], 0, 0, 0);
      }
    }
  }
  // write partial O (unnormalized)
#pragma unroll
  for (int mt = 0; mt < 2; ++mt)
#pragma unroll
    for (int ns = 0; ns < 8; ++ns)
#pragma unroll
      for (int r = 0; r < 4; ++r) {
        int row = rbase + mt * 16 + quad * 4 + r;
        Opart[((size_t)sp * N_ + row) * H_ + ns * 16 + lo16] = O[mt][ns][r];
      }
#pragma unroll
  for (int x = 1; x <= 8; x <<= 1)
#pragma unroll
    for (int mt = 0; mt < 2; ++mt)
#pragma unroll
      for (int r = 0; r < 4; ++r) lsum[mt][r] += __shfl_xor(lsum[mt][r], x, 16);
  if (lo16 == 0) {
#pragma unroll
    for (int mt = 0; mt < 2; ++mt)
#pragma unroll
      for (int r = 0; r < 4; ++r)
        Lpart[(size_t)sp * N_ + rbase + mt * 16 + quad * 4 + r] = lsum[mt][r];
  }
}

__global__ __launch_bounds__(128) void k_attn_merge(const float* __restrict__ Opart,
      const float* __restrict__ Lpart, float* __restrict__ outp) {
  int i = blockIdx.x, t = threadIdx.x;
  float lg = 0.f;
#pragma unroll
  for (int s = 0; s < JSPLIT; ++s) lg += Lpart[(size_t)s * N_ + i];
  float inv = (lg > 0.f) ? 1.f / lg : 0.f;
  float acc = 0.f;
#pragma unroll
  for (int s = 0; s < JSPLIT; ++s)
    acc += Opart[((size_t)s * N_ + i) * H_ + t];
  outp[(size_t)i * H_ + t] = acc * inv;
}

// ---------------- elementwise ----------------
__global__ __launch_bounds__(256) void k_sub2(const float4* __restrict__ a,
      const float4* __restrict__ b, float4* __restrict__ o) {
  int i = blockIdx.x * 256 + threadIdx.x;
  float4 x = a[i], y = b[i], r;
  r.x = x.x - y.x; r.y = x.y - y.y; r.z = x.z - y.z; r.w = x.w - y.w;
  o[i] = r;
}

__global__ __launch_bounds__(256) void k_sub3(const float4* __restrict__ a,
      const float4* __restrict__ b, const float4* __restrict__ c, float4* __restrict__ o) {
  int i = blockIdx.x * 256 + threadIdx.x;
  float4 x = a[i], y = b[i], z = c[i], r;
  r.x = x.x - y.x - z.x; r.y = x.y - y.y - z.y; r.z = x.z - y.z - z.z; r.w = x.w - y.w - z.w;
  o[i] = r;
}

__global__ __launch_bounds__(128) void k_pred(const float* __restrict__ a,
      const float* __restrict__ b, const float* __restrict__ c,
      const float* __restrict__ wout, const float* __restrict__ bout,
      float* __restrict__ outp) {
  __shared__ float buf[128];
  int i = blockIdx.x, t = threadIdx.x;
  size_t idx = (size_t)i * H_ + t;
  float v = (a[idx] + b[idx] + c[idx]) * wout[t];
  float s = bred_sum128(v, buf);
  if (t == 0) outp[i] = s + bout[0];
}

// ---------------- host ----------------
extern "C" void kernel_launch(void* const* d_in, const int* in_sizes, int n_in,
                              void* d_out, int out_size, void* d_ws, size_t ws_size,
                              hipStream_t stream) {
  const float* x          = (const float*)d_in[0];
  const float* mv         = (const float*)d_in[1];
  const int*   cm         = (const int*)d_in[2];
  const float* W_ps       = (const float*)d_in[3];
  const float* b_ps       = (const float*)d_in[4];
  const float* W_hs       = (const float*)d_in[5];
  const float* b_hs       = (const float*)d_in[6];
  const float* W_ps_fore  = (const float*)d_in[7];
  const float* b_ps_fore  = (const float*)d_in[8];
  const float* W_hs_fore  = (const float*)d_in[9];
  const float* b_hs_fore  = (const float*)d_in[10];
  const float* W_ps_back  = (const float*)d_in[11];
  const float* b_ps_back  = (const float*)d_in[12];
  const float* W_hs_back  = (const float*)d_in[13];
  const float* b_hs_back  = (const float*)d_in[14];
  const float* W_indi     = (const float*)d_in[15];
  const float* b_indi     = (const float*)d_in[16];
  const float* W_out      = (const float*)d_in[23];
  const float* b_out      = (const float*)d_in[24];
  float* outp = (float*)d_out;

  float* W = (float*)d_ws;
  const size_t NC = (size_t)N_ * C_;   // NC = 4*NH
  const size_t NH = (size_t)N_ * H_;
  const size_t CH = (size_t)C_ * H_;
  float* Sbuf = W;
  float* pback   = Sbuf;
  float* outps   = Sbuf + NH;
  float* hback   = Sbuf + 2 * NH;
  float* outindi = Sbuf + 3 * NH;
  size_t off = NC;
  float* T1       = W + off; off += NH;
  float* p_shared = W + off; off += NH;
  float* h_shared = W + off; off += NH;
  float* hidden3  = W + off; off += NH;
  float* h_info   = W + off; off += NH;
  float* out_hs   = W + off; off += NH;
  float* hidden1  = W + off; off += CH;
  float* hidden2  = W + off; off += CH;
  float* colsum1   = W + off; off += C_;
  float* colmax    = W + off; off += C_;
  float* colsumexp = W + off; off += C_;
  float* rny2      = W + off; off += C_;
  float* partb     = W + off; off += (size_t)CPB * C_;
  float* rnx     = W + off; off += N_;
  float* rqh     = W + off; off += N_;
  float* diagv   = W + off; off += N_;
  float* colsum3 = W + off; off += N_;
  float* rn3     = W + off; off += N_;
  float* gvals   = W + off; off += 3 * N_;
  float* Lpart   = W + off; off += (size_t)JSPLIT * N_;
  float* keepf   = W + off; off += N_;
  int* keep1 = (int*)(W + off); off += C_;
  int* keep2 = (int*)(W + off); off += N_;
  int* gidx  = (int*)(W + off); off += 3 * N_;
  ushort* Qn = (ushort*)(W + off); off += NH / 2;
  ushort* Kn = (ushort*)(W + off); off += NH / 2;
  ushort* Vt = (ushort*)(W + off); off += NH / 2;
  float* Opart = W + off; off += (size_t)JSPLIT * NH;   // stage-5 only
  // Gram scratch ALIASES Opart (stage-4 only; disjoint in time from attention):
  ushort* Ghi = (ushort*)Opart;
  ushort* Glo = Ghi + NH;
  int*    Gip = (int*)(Opart + NH);

  hipMemsetAsync(colsum1, 0, C_ * sizeof(float), stream);
  hipMemsetAsync(hidden1, 0, CH * sizeof(float), stream);
  hipMemsetAsync(hidden2, 0, CH * sizeof(float), stream);
  hipMemsetAsync(hidden3, 0, NH * sizeof(float), stream);
  hipMemsetAsync(colsum3, 0, N_ * sizeof(float), stream);

  // stage 1: market-value aggregation
  k_colsum1<<<dim3(2, 128), 256, 0, stream>>>(cm, mv, colsum1);
  k_agg<0><<<dim3(16, 64), 256, 0, stream>>>(x, cm, mv, nullptr, nullptr, hidden1);
  k_fin_hidden1<<<C_, 128, 0, stream>>>(hidden1, colsum1, keep1);
  k_rowstats<<<N_, 128, 0, stream>>>(x, rnx, nullptr, nullptr);

  // stage 2: softmax over stocks, hidden2
  k_gemm<1, 0><<<dim3(C_ / 64, N_ / 64), 256, 0, stream>>>(
      x, H_, hidden1, H_, Sbuf, C_, N_, C_, H_, nullptr, nullptr, nullptr);
  k_colmax_part<<<CPB, 256, 0, stream>>>(Sbuf, partb);
  k_colfin_max<<<1, 512, 0, stream>>>(partb, colmax);
  k_colsum_part<<<CPB, 256, 0, stream>>>(Sbuf, colmax, partb);
  k_colfin_sum<<<1, 512, 0, stream>>>(partb, colsumexp);
  k_agg<1><<<dim3(16, 64), 256, 0, stream>>>(x, nullptr, nullptr, Sbuf, colmax, hidden2);
  k_fin_hidden2<<<C_, 128, 0, stream>>>(hidden2, colsumexp, rny2);

  // stage 3: c2s softmax + p branch
  k_gemm<1, 0><<<dim3(C_ / 64, N_ / 64), 256, 0, stream>>>(
      x, H_, hidden2, H_, Sbuf, C_, N_, C_, H_, nullptr, rnx, rny2);
  k_rowsoftmax<<<N_, 256, 0, stream>>>(Sbuf, keep1);
  k_gemm<0, 0><<<dim3(H_ / 64, N_ / 64), 256, 0, stream>>>(
      Sbuf, C_, hidden2, H_, T1, H_, N_, H_, C_, nullptr, nullptr, nullptr);
  k_gemm<0, 0><<<dim3(2, 128), 256, 0, stream>>>(
      T1, H_, W_ps, H_, p_shared, H_, N_, H_, H_, b_ps, nullptr, nullptr);
  k_gemm<0, 0><<<dim3(2, 128), 256, 0, stream>>>(
      p_shared, H_, W_ps_back, H_, pback, H_, N_, H_, H_, b_ps_back, nullptr, nullptr);
  k_gemm<0, 1><<<dim3(2, 128), 256, 0, stream>>>(
      p_shared, H_, W_ps_fore, H_, outps, H_, N_, H_, H_, b_ps_fore, nullptr, nullptr);

  // stage 4: h_shared, N x N top-3 graph (MFMA candidates + exact rescore)
  k_sub2<<<NH / 4 / 256, 256, 0, stream>>>((const float4*)x, (const float4*)pback,
                                           (float4*)h_shared);
  k_rowstats<<<N_, 128, 0, stream>>>(h_shared, rqh, diagv, nullptr);
  k_prep_gram<<<N_ / 8, 256, 0, stream>>>(h_shared, rqh, Ghi, Glo);
  k_gram_mfma<<<dim3(N_ / 128, GSPLIT), 256, 0, stream>>>(Ghi, Glo, Gip);
  k_gram_rescore<<<N_ / 4, 256, 0, stream>>>(h_shared, rqh, Gip, gvals, gidx);
  k_scatter<<<N_, 128, 0, stream>>>(h_shared, gvals, gidx, hidden3, colsum3);
  k_h3fin<<<N_, 128, 0, stream>>>(hidden3, h_shared, colsum3, diagv, rn3, keep2);

  // stage 5: MFMA flash attention (fixed-max, LDS-staged K/V), h branch
  k_prep_attn<<<N_ / 64, 256, 0, stream>>>(h_shared, hidden3, rqh, rn3, keep2,
                                           Qn, Kn, Vt, keepf);
  k_attn_mfma<<<dim3(N_ / 128, JSPLIT), 256, 0, stream>>>(Qn, Kn, Vt, keepf,
                                                          Opart, Lpart);
  k_attn_merge<<<N_, 128, 0, stream>>>(Opart, Lpart, T1);
  k_gemm<0, 0><<<dim3(2, 128), 256, 0, stream>>>(
      T1, H_, W_hs, H_, h_info, H_, N_, H_, H_, b_hs, nullptr, nullptr);
  k_gemm<0, 0><<<dim3(2, 128), 256, 0, stream>>>(
      h_info, H_, W_hs_back, H_, hback, H_, N_, H_, H_, b_hs_back, nullptr, nullptr);
  k_gemm<0, 1><<<dim3(2, 128), 256, 0, stream>>>(
      h_info, H_, W_hs_fore, H_, out_hs, H_, N_, H_, H_, b_hs_fore, nullptr, nullptr);

  // stage 6: individual branch + final projection
  k_sub3<<<NH / 4 / 256, 256, 0, stream>>>((const float4*)x, (const float4*)pback,
                                           (const float4*)hback, (float4*)h_shared);
  k_gemm<0, 1><<<dim3(2, 128), 256, 0, stream>>>(
      h_shared, H_, W_indi, H_, outindi, H_, N_, H_, H_, b_indi, nullptr, nullptr);
  k_pred<<<N_, 128, 0, stream>>>(outps, out_hs, outindi, W_out, b_out, outp);
}

// Round 9
// 617.440 us; speedup vs baseline: 2.0470x; 1.1888x over previous
//
#include <hip/hip_runtime.h>
#include <float.h>
#include <math.h>

#define N_ 8192
#define C_ 512
#define H_ 128

typedef __attribute__((ext_vector_type(8))) short bfrag;
typedef __attribute__((ext_vector_type(4))) float f4;

__device__ __forceinline__ ushort f2bf(float f) {
  unsigned u = __float_as_uint(f);
  unsigned r = (u + 0x7fffu + ((u >> 16) & 1u)) >> 16;
  return (ushort)r;
}

// split 8 consecutive fp32 into bf16 hi/lo, write to (possibly strided) dst
__device__ __forceinline__ void split8_contig(const float* __restrict__ src,
      ushort* __restrict__ dh, ushort* __restrict__ dl) {
  float4 v0 = *(const float4*)src;
  float4 v1 = *(const float4*)(src + 4);
  float a[8] = {v0.x, v0.y, v0.z, v0.w, v1.x, v1.y, v1.z, v1.w};
  ushort hh[8], ll[8];
#pragma unroll
  for (int i = 0; i < 8; ++i) {
    hh[i] = f2bf(a[i]);
    float hf = __uint_as_float(((unsigned)hh[i]) << 16);
    ll[i] = f2bf(a[i] - hf);
  }
  *(ushort4*)&dh[0] = *(ushort4*)&hh[0];
  *(ushort4*)&dh[4] = *(ushort4*)&hh[4];
  *(ushort4*)&dl[0] = *(ushort4*)&ll[0];
  *(ushort4*)&dl[4] = *(ushort4*)&ll[4];
}

// ---------------- helpers ----------------
__device__ __forceinline__ float bred_sum128(float v, float* buf) {
  int t = threadIdx.x;
  buf[t] = v; __syncthreads();
  for (int s = 64; s > 0; s >>= 1) {
    if (t < s) buf[t] += buf[t + s];
    __syncthreads();
  }
  float r = buf[0]; __syncthreads();
  return r;
}

__device__ __forceinline__ void top3_ins(float (&tv)[3], int (&ti)[3], float v, int j) {
  bool b2 = (v > tv[2]) || (v == tv[2] && j < ti[2]);
  if (!b2) return;
  bool b1 = (v > tv[1]) || (v == tv[1] && j < ti[1]);
  if (b1) {
    tv[2] = tv[1]; ti[2] = ti[1];
    bool b0 = (v > tv[0]) || (v == tv[0] && j < ti[0]);
    if (b0) { tv[1] = tv[0]; ti[1] = ti[0]; tv[0] = v; ti[0] = j; }
    else    { tv[1] = v;     ti[1] = j; }
  } else { tv[2] = v; ti[2] = j; }
}

// fast insert: per-lane stream is j-ascending, strict > keeps lowest j on ties
__device__ __forceinline__ void top3_fast(float (&tv)[3], int (&ti)[3], float v, int j) {
  if (v <= tv[2]) return;
  if (v > tv[1]) {
    tv[2] = tv[1]; ti[2] = ti[1];
    if (v > tv[0]) { tv[1] = tv[0]; ti[1] = ti[0]; tv[0] = v; ti[0] = j; }
    else           { tv[1] = v;     ti[1] = j; }
  } else { tv[2] = v; ti[2] = j; }
}

// ---------------- stage 1: concept aggregation ----------------
__global__ __launch_bounds__(256) void k_colsum1(const int* __restrict__ cm,
      const float* __restrict__ mv, float* __restrict__ colsum1) {
  int t = threadIdx.x;
  int c = blockIdx.x * 256 + t;
  int r0 = blockIdx.y * 64;
  float acc = 0.f;
  for (int r = 0; r < 64; ++r) {
    int i = r0 + r;
    acc += (float)cm[(size_t)i * C_ + c] * mv[i];
  }
  atomicAdd(&colsum1[c], acc);
}

template<int MODE>
__global__ __launch_bounds__(256) void k_agg(const float* __restrict__ x,
      const int* __restrict__ cm, const float* __restrict__ mv,
      const float* __restrict__ S, const float* __restrict__ colmax,
      float* __restrict__ outCH) {
  __shared__ float ws[8][32];
  int t = threadIdx.x;
  int cbase = blockIdx.x * 32;
  int h = t & 127, half = t >> 7;
  float acc[16];
#pragma unroll
  for (int k = 0; k < 16; ++k) acc[k] = 0.f;
  int sr = t >> 5, sc = t & 31;
  for (int sub = 0; sub < 16; ++sub) {
    int ibase = blockIdx.y * 128 + sub * 8;
    {
      int i = ibase + sr, c = cbase + sc;
      float w;
      if (MODE == 0) w = cm[(size_t)i * C_ + c] ? mv[i] : 0.f;
      else           w = __expf(S[(size_t)i * C_ + c] - colmax[c]);
      ws[sr][sc] = w;
    }
    __syncthreads();
#pragma unroll
    for (int r = 0; r < 8; ++r) {
      float xv = x[(size_t)(ibase + r) * H_ + h];
      const float* wr = &ws[r][half * 16];
#pragma unroll
      for (int k = 0; k < 16; ++k) acc[k] += wr[k] * xv;
    }
    __syncthreads();
  }
#pragma unroll
  for (int k = 0; k < 16; ++k)
    atomicAdd(&outCH[(size_t)(cbase + half * 16 + k) * H_ + h], acc[k]);
}

__global__ __launch_bounds__(128) void k_fin_hidden1(float* __restrict__ h1,
      const float* __restrict__ colsum1, int* __restrict__ keep1) {
  __shared__ float buf[128];
  int c = blockIdx.x, t = threadIdx.x;
  float v = h1[(size_t)c * H_ + t] / (colsum1[c] + 1.f);
  h1[(size_t)c * H_ + t] = v;
  float sm = bred_sum128(v, buf);
  if (t == 0) keep1[c] = (sm != 0.f) ? 1 : 0;
}

__global__ __launch_bounds__(128) void k_fin_hidden2(float* __restrict__ h2,
      const float* __restrict__ colsumexp, float* __restrict__ rny) {
  __shared__ float buf[128];
  int c = blockIdx.x, t = threadIdx.x;
  float v = h2[(size_t)c * H_ + t] / colsumexp[c];
  h2[(size_t)c * H_ + t] = v;
  float ss = bred_sum128(v * v, buf);
  if (t == 0) rny[c] = (ss > 0.f) ? 1.f / sqrtf(ss) : 0.f;
}

__global__ __launch_bounds__(128) void k_rowstats(const float* __restrict__ A,
      float* __restrict__ rinv, float* __restrict__ diag, int* __restrict__ keep) {
  __shared__ float buf[128];
  int i = blockIdx.x, t = threadIdx.x;
  float v = A[(size_t)i * H_ + t];
  float ss = bred_sum128(v * v, buf);
  float sm = bred_sum128(v, buf);
  if (t == 0) {
    float nr = sqrtf(ss);
    if (rinv) rinv[i] = (ss > 0.f) ? 1.f / nr : 0.f;
    if (diag) diag[i] = (ss > 0.f) ? ss / (nr * nr) : 0.f;
    if (keep) keep[i] = (sm != 0.f) ? 1 : 0;
  }
}

// ---------------- MFMA GEMM, hi/lo-compensated bf16, fused split ----------------
// C[M,Nn] = A[M,K] @ B   (TRANSB=1: B is [Nn,K] row-major; 0: B is [K,Nn] row-major)
// 64x64 tile, 256 thr: wave w -> m-tiles {(w&1)*2,+1}, n-tiles {(w>>1)*2,+1}.
// LDS stride 40 shorts (20 dwords): frag-read rows hit banks 2-way max (free).
template<int TRANSB, int ACT>
__global__ __launch_bounds__(256) void k_mgemm(const float* __restrict__ A, int lda,
      const float* __restrict__ B, int ldb, float* __restrict__ Cc, int ldc, int Kk,
      const float* __restrict__ bias, const float* __restrict__ rowscale,
      const float* __restrict__ colscale) {
  __shared__ ushort Ah[64 * 40], Al[64 * 40], Bh[64 * 40], Bl[64 * 40];
  int t = threadIdx.x;
  int l = t & 63, w = t >> 6;
  int lo16 = l & 15, quad = l >> 4;
  int n0 = blockIdx.x * 64, m0 = blockIdx.y * 64;
  int mt0 = (w & 1) * 2, nt0 = (w >> 1) * 2;
  f4 acc[2][2];
#pragma unroll
  for (int mt = 0; mt < 2; ++mt)
#pragma unroll
    for (int nt = 0; nt < 2; ++nt) acc[mt][nt] = (f4){0.f, 0.f, 0.f, 0.f};

  int ar = t >> 2, ac = (t & 3) * 8;        // A stage: 64 rows x 32 k
  int kr = t >> 3, nc = (t & 7) * 8;        // B stage (TRANSB=0): 32 k x 64 n
  for (int k0 = 0; k0 < Kk; k0 += 32) {
    __syncthreads();
    split8_contig(&A[(size_t)(m0 + ar) * lda + k0 + ac], &Ah[ar * 40 + ac], &Al[ar * 40 + ac]);
    if (TRANSB) {
      split8_contig(&B[(size_t)(n0 + ar) * ldb + k0 + ac], &Bh[ar * 40 + ac], &Bl[ar * 40 + ac]);
    } else {
      const float* src = &B[(size_t)(k0 + kr) * ldb + n0 + nc];
      float4 v0 = *(const float4*)src;
      float4 v1 = *(const float4*)(src + 4);
      float a[8] = {v0.x, v0.y, v0.z, v0.w, v1.x, v1.y, v1.z, v1.w};
#pragma unroll
      for (int i = 0; i < 8; ++i) {
        ushort hh = f2bf(a[i]);
        float hf = __uint_as_float(((unsigned)hh) << 16);
        Bh[(nc + i) * 40 + kr] = hh;
        Bl[(nc + i) * 40 + kr] = f2bf(a[i] - hf);
      }
    }
    __syncthreads();
    bfrag ah[2], al_[2], bh[2], bl[2];
#pragma unroll
    for (int mt = 0; mt < 2; ++mt) {
      int row = (mt0 + mt) * 16 + lo16;
      ah[mt]  = *(const bfrag*)&Ah[row * 40 + quad * 8];
      al_[mt] = *(const bfrag*)&Al[row * 40 + quad * 8];
    }
#pragma unroll
    for (int nt = 0; nt < 2; ++nt) {
      int col = (nt0 + nt) * 16 + lo16;
      bh[nt] = *(const bfrag*)&Bh[col * 40 + quad * 8];
      bl[nt] = *(const bfrag*)&Bl[col * 40 + quad * 8];
    }
#pragma unroll
    for (int mt = 0; mt < 2; ++mt)
#pragma unroll
      for (int nt = 0; nt < 2; ++nt) {
        f4 a0 = __builtin_amdgcn_mfma_f32_16x16x32_bf16(al_[mt], bh[nt], acc[mt][nt], 0, 0, 0);
        a0 = __builtin_amdgcn_mfma_f32_16x16x32_bf16(ah[mt], bl[nt], a0, 0, 0, 0);
        acc[mt][nt] = __builtin_amdgcn_mfma_f32_16x16x32_bf16(ah[mt], bh[nt], a0, 0, 0, 0);
      }
  }
#pragma unroll
  for (int mt = 0; mt < 2; ++mt)
#pragma unroll
    for (int r = 0; r < 4; ++r) {
      int row = m0 + (mt0 + mt) * 16 + quad * 4 + r;
      float rs = rowscale ? rowscale[row] : 1.f;
#pragma unroll
      for (int nt = 0; nt < 2; ++nt) {
        int col = n0 + (nt0 + nt) * 16 + lo16;
        float v = acc[mt][nt][r] * rs;
        if (colscale) v *= colscale[col];
        if (bias) v += bias[col];
        if (ACT) v = (v > 0.f) ? v : 0.01f * v;
        Cc[(size_t)row * ldc + col] = v;
      }
    }
}

// ---------------- column softmax over S[N,C] ----------------
#define CPB 128
__global__ __launch_bounds__(256) void k_colmax_part(const float* __restrict__ S,
      float* __restrict__ part) {
  int t = threadIdx.x, b = blockIdx.x;
  int r0 = b * (N_ / CPB);
  float m0 = -FLT_MAX, m1 = -FLT_MAX;
  for (int r = 0; r < N_ / CPB; ++r) {
    const float* row = S + (size_t)(r0 + r) * C_;
    m0 = fmaxf(m0, row[t]);
    m1 = fmaxf(m1, row[t + 256]);
  }
  part[(size_t)b * C_ + t] = m0;
  part[(size_t)b * C_ + t + 256] = m1;
}

__global__ __launch_bounds__(256) void k_colsum_part(const float* __restrict__ S,
      const float* __restrict__ colmax, float* __restrict__ part) {
  int t = threadIdx.x, b = blockIdx.x;
  int r0 = b * (N_ / CPB);
  float cm0 = colmax[t], cm1 = colmax[t + 256];
  float s0 = 0.f, s1 = 0.f;
  for (int r = 0; r < N_ / CPB; ++r) {
    const float* row = S + (size_t)(r0 + r) * C_;
    s0 += __expf(row[t] - cm0);
    s1 += __expf(row[t + 256] - cm1);
  }
  part[(size_t)b * C_ + t] = s0;
  part[(size_t)b * C_ + t + 256] = s1;
}

__global__ __launch_bounds__(512) void k_colfin_max(const float* __restrict__ part,
      float* __restrict__ outv) {
  int c = threadIdx.x;
  float m = -FLT_MAX;
  for (int b = 0; b < CPB; ++b) m = fmaxf(m, part[(size_t)b * C_ + c]);
  outv[c] = m;
}

__global__ __launch_bounds__(512) void k_colfin_sum(const float* __restrict__ part,
      float* __restrict__ outv) {
  int c = threadIdx.x;
  float s = 0.f;
  for (int b = 0; b < CPB; ++b) s += part[(size_t)b * C_ + c];
  outv[c] = s;
}

// ---------------- row softmax (512 cols) with keep mask ----------------
__global__ __launch_bounds__(256) void k_rowsoftmax(float* __restrict__ Sm,
      const int* __restrict__ keep1) {
  __shared__ float buf[256];
  int i = blockIdx.x, t = threadIdx.x;
  float* row = Sm + (size_t)i * C_;
  int k0 = keep1[t], k1 = keep1[t + 256];
  float v0 = k0 ? row[t] : -FLT_MAX;
  float v1 = k1 ? row[t + 256] : -FLT_MAX;
  buf[t] = fmaxf(v0, v1); __syncthreads();
  for (int s = 128; s > 0; s >>= 1) {
    if (t < s) buf[t] = fmaxf(buf[t], buf[t + s]);
    __syncthreads();
  }
  float m = buf[0]; __syncthreads();
  float e0 = k0 ? expf(v0 - m) : 0.f;
  float e1 = k1 ? expf(v1 - m) : 0.f;
  buf[t] = e0 + e1; __syncthreads();
  for (int s = 128; s > 0; s >>= 1) {
    if (t < s) buf[t] += buf[t + s];
    __syncthreads();
  }
  float inv = 1.f / buf[0];
  row[t] = e0 * inv;
  row[t + 256] = e1 * inv;
}

// ---------------- gram prep: normalized rows split into bf16 hi + lo ----------------
__global__ __launch_bounds__(256) void k_prep_gram(const float* __restrict__ hs,
      const float* __restrict__ rn, ushort* __restrict__ Ghi, ushort* __restrict__ Glo) {
  int t = threadIdx.x;
  int row = blockIdx.x * 8 + (t >> 5);
  int c = (t & 31) * 4;
  float r = rn[row];
  float4 v = *(const float4*)&hs[(size_t)row * H_ + c];
  float q[4] = {v.x * r, v.y * r, v.z * r, v.w * r};
  ushort hi[4], lo[4];
#pragma unroll
  for (int k = 0; k < 4; ++k) {
    hi[k] = f2bf(q[k]);
    float hf = __uint_as_float(((unsigned)hi[k]) << 16);
    lo[k] = f2bf(q[k] - hf);
  }
  *(ushort4*)&Ghi[(size_t)row * H_ + c] = *(ushort4*)hi;
  *(ushort4*)&Glo[(size_t)row * H_ + c] = *(ushort4*)lo;
}

// ---------------- N x N Gram: 4-wave blocks, 32 rows/wave, LDS j-tiles --------------
#define GSPLIT 8
__global__ __launch_bounds__(256) void k_gram_mfma(const ushort* __restrict__ Ghi,
      const ushort* __restrict__ Glo, int* __restrict__ Gip) {
  __shared__ ushort JH[64 * 136];
  __shared__ ushort JL[64 * 136];
  int t = threadIdx.x;
  int l = t & 63, w = t >> 6;
  int lo16 = l & 15, quad = l >> 4;
  int i0 = blockIdx.x * 128;
  int rbase = i0 + w * 32;
  int sp = blockIdx.y;
  const int jspan = N_ / GSPLIT;   // 1024

  bfrag ahi[2][4], alo[2][4];
#pragma unroll
  for (int mt = 0; mt < 2; ++mt)
#pragma unroll
    for (int kc = 0; kc < 4; ++kc) {
      size_t base = (size_t)(rbase + mt * 16 + lo16) * H_ + kc * 32 + quad * 8;
      ahi[mt][kc] = *(const bfrag*)&Ghi[base];
      alo[mt][kc] = *(const bfrag*)&Glo[base];
    }

  float tv[2][4][3]; int ti[2][4][3];
#pragma unroll
  for (int mt = 0; mt < 2; ++mt)
#pragma unroll
    for (int r = 0; r < 4; ++r)
#pragma unroll
      for (int s = 0; s < 3; ++s) { tv[mt][r][s] = -FLT_MAX; ti[mt][r][s] = 0x7fffffff; }

  int srow = t >> 2, scol = (t & 3) * 32;
  for (int jt = 0; jt < jspan / 64; ++jt) {
    int j0 = sp * jspan + jt * 64;
    __syncthreads();
    {
      const ushort* gh = &Ghi[(size_t)(j0 + srow) * H_ + scol];
      const ushort* gl = &Glo[(size_t)(j0 + srow) * H_ + scol];
      ushort* dh = &JH[srow * 136 + scol];
      ushort* dl = &JL[srow * 136 + scol];
#pragma unroll
      for (int u = 0; u < 32; u += 4) {
        *(ushort4*)&dh[u] = *(const ushort4*)&gh[u];
        *(ushort4*)&dl[u] = *(const ushort4*)&gl[u];
      }
    }
    __syncthreads();
#pragma unroll
    for (int js = 0; js < 4; ++js) {
      int jl_ = js * 16 + lo16;
      int j = j0 + jl_;
      bfrag bhi[4], blo[4];
#pragma unroll
      for (int kc = 0; kc < 4; ++kc) {
        int base = jl_ * 136 + kc * 32 + quad * 8;
        bhi[kc] = *(const bfrag*)&JH[base];
        blo[kc] = *(const bfrag*)&JL[base];
      }
#pragma unroll
      for (int mt = 0; mt < 2; ++mt) {
        f4 ahh = (f4){0.f, 0.f, 0.f, 0.f};
        f4 axx = (f4){0.f, 0.f, 0.f, 0.f};   // hl + lh chained
#pragma unroll
        for (int kc = 0; kc < 4; ++kc) {
          ahh = __builtin_amdgcn_mfma_f32_16x16x32_bf16(ahi[mt][kc], bhi[kc], ahh, 0, 0, 0);
          axx = __builtin_amdgcn_mfma_f32_16x16x32_bf16(ahi[mt][kc], blo[kc], axx, 0, 0, 0);
          axx = __builtin_amdgcn_mfma_f32_16x16x32_bf16(alo[mt][kc], bhi[kc], axx, 0, 0, 0);
        }
#pragma unroll
        for (int r = 0; r < 4; ++r) {
          int gi = rbase + mt * 16 + quad * 4 + r;
          float v = (j == gi) ? 0.f : (ahh[r] + axx[r]);
          top3_fast(tv[mt][r], ti[mt][r], v, j);
        }
      }
    }
  }
  // in-wave butterfly merge across the 16 lanes sharing each row
#pragma unroll
  for (int mt = 0; mt < 2; ++mt)
#pragma unroll
    for (int r = 0; r < 4; ++r) {
#pragma unroll
      for (int x = 1; x <= 8; x <<= 1) {
        float vv[3]; int ii[3];
#pragma unroll
        for (int s = 0; s < 3; ++s) {
          vv[s] = __shfl_xor(tv[mt][r][s], x, 16);
          ii[s] = __shfl_xor(ti[mt][r][s], x, 16);
        }
#pragma unroll
        for (int s = 0; s < 3; ++s) top3_ins(tv[mt][r], ti[mt][r], vv[s], ii[s]);
      }
    }
  if (lo16 == 0) {
#pragma unroll
    for (int mt = 0; mt < 2; ++mt)
#pragma unroll
      for (int r = 0; r < 4; ++r) {
        int row = rbase + mt * 16 + quad * 4 + r;
#pragma unroll
        for (int s = 0; s < 3; ++s)
          Gip[((size_t)sp * N_ + row) * 3 + s] = ti[mt][r][s];
      }
  }
}

// ---------------- exact fp32 rescore of 24 candidates/row -> final top-3 -------------
__global__ __launch_bounds__(256) void k_gram_rescore(const float* __restrict__ hs,
      const float* __restrict__ rn, const int* __restrict__ Gip,
      float* __restrict__ gvals, int* __restrict__ gidx) {
  int row = blockIdx.x * 4 + (threadIdx.x >> 6);
  int lane = threadIdx.x & 63;
  const float* qr = &hs[(size_t)row * H_];
  float q0 = qr[lane], q1 = qr[lane + 64];
  float rni = rn[row];
  float bv[3] = {-FLT_MAX, -FLT_MAX, -FLT_MAX};
  int bi[3] = {0x7fffffff, 0x7fffffff, 0x7fffffff};
  for (int s = 0; s < GSPLIT; ++s)
#pragma unroll
    for (int k = 0; k < 3; ++k) {
      int j = Gip[((size_t)s * N_ + row) * 3 + k];
      const float* jr = &hs[(size_t)j * H_];
      float d = q0 * jr[lane] + q1 * jr[lane + 64];
#pragma unroll
      for (int x = 1; x < 64; x <<= 1) d += __shfl_xor(d, x, 64);
      float v = (j == row) ? 0.f : d * rni * rn[j];
      top3_ins(bv, bi, v, j);
    }
  if (lane == 0) {
#pragma unroll
    for (int s = 0; s < 3; ++s) {
      gvals[(size_t)row * 3 + s] = bv[s];
      gidx[(size_t)row * 3 + s] = bi[s];
    }
  }
}

// ---------------- sparse scatter: hidden3 = hs2c^T @ h_shared ----------------
__global__ __launch_bounds__(128) void k_scatter(const float* __restrict__ hs,
      const float* __restrict__ gvals, const int* __restrict__ gidx,
      float* __restrict__ hidden3, float* __restrict__ colsum3) {
  int i = blockIdx.x, t = threadIdx.x;
  float xs = hs[(size_t)i * H_ + t];
#pragma unroll
  for (int k = 0; k < 3; ++k) {
    int j = gidx[i * 3 + k];
    float v = gvals[i * 3 + k];
    atomicAdd(&hidden3[(size_t)j * H_ + t], v * xs);
  }
  if (t == 0) {
#pragma unroll
    for (int k = 0; k < 3; ++k) atomicAdd(&colsum3[gidx[i * 3 + k]], gvals[i * 3 + k]);
  }
}

__global__ __launch_bounds__(128) void k_h3fin(float* __restrict__ hidden3,
      const float* __restrict__ hs, const float* __restrict__ colsum3,
      const float* __restrict__ diagv, float* __restrict__ rn3, int* __restrict__ keep2) {
  __shared__ float buf[128];
  int j = blockIdx.x, t = threadIdx.x;
  float v = hidden3[(size_t)j * H_ + t];
  if (colsum3[j] != 0.f) v += diagv[j] * hs[(size_t)j * H_ + t];
  hidden3[(size_t)j * H_ + t] = v;
  float ss = bred_sum128(v * v, buf);
  float sm = bred_sum128(v, buf);
  if (t == 0) {
    rn3[j] = (ss > 0.f) ? 1.f / sqrtf(ss) : 0.f;
    keep2[j] = (sm != 0.f) ? 1 : 0;
  }
}

// ---------------- attention prep: bf16 Qn/Kn, transposed V, keep as float ----------
__global__ __launch_bounds__(256) void k_prep_attn(const float* __restrict__ hs,
      const float* __restrict__ h3, const float* __restrict__ rqh,
      const float* __restrict__ rn3, const int* __restrict__ keep2,
      ushort* __restrict__ Qn, ushort* __restrict__ Kn, ushort* __restrict__ Vt,
      float* __restrict__ keepf) {
  __shared__ ushort T[H_][68];
  int t = threadIdx.x;
  int i0 = blockIdx.x * 64;
  int r = i0 + (t >> 2);
  int c0 = (t & 3) * 32;
  float rq = rqh[r], r3 = rn3[r];
  for (int c = c0; c < c0 + 32; c += 4) {
    float4 hv = *(const float4*)&hs[(size_t)r * H_ + c];
    float4 h3v = *(const float4*)&h3[(size_t)r * H_ + c];
    ushort q4[4] = {f2bf(hv.x * rq), f2bf(hv.y * rq), f2bf(hv.z * rq), f2bf(hv.w * rq)};
    ushort k4[4] = {f2bf(h3v.x * r3), f2bf(h3v.y * r3), f2bf(h3v.z * r3), f2bf(h3v.w * r3)};
    *(ushort4*)&Qn[(size_t)r * H_ + c] = *(ushort4*)q4;
    *(ushort4*)&Kn[(size_t)r * H_ + c] = *(ushort4*)k4;
    T[c + 0][r - i0] = f2bf(h3v.x);
    T[c + 1][r - i0] = f2bf(h3v.y);
    T[c + 2][r - i0] = f2bf(h3v.z);
    T[c + 3][r - i0] = f2bf(h3v.w);
  }
  if (t < 64) keepf[i0 + t] = (float)keep2[i0 + t];
  __syncthreads();
  int h = t >> 1, off = (t & 1) * 32;
  for (int u = 0; u < 32; u += 4) {
    ushort4 vv;
    vv.x = T[h][off + u]; vv.y = T[h][off + u + 1];
    vv.z = T[h][off + u + 2]; vv.w = T[h][off + u + 3];
    *(ushort4*)&Vt[(size_t)h * N_ + i0 + off + u] = vv;
  }
}

// ---------------- MFMA flash attention: 4-wave blocks, 32 rows/wave, LDS K/V --------
#define JSPLIT 8
__global__ __launch_bounds__(256) void k_attn_mfma(const ushort* __restrict__ Qn,
      const ushort* __restrict__ Kn, const ushort* __restrict__ Vt,
      const float* __restrict__ keepf, float* __restrict__ Opart,
      float* __restrict__ Lpart) {
  __shared__ ushort Ks[64 * 136];      // [j][k] stride 136
  __shared__ ushort Vs[128 * 72];      // [h][j] stride 72
  __shared__ ushort Ps[4][32 * 72];    // per-wave P tile (32 q-rows x 64 j)
  int t = threadIdx.x;
  int l = t & 63, w = t >> 6;
  int lo16 = l & 15, quad = l >> 4;
  int i0 = blockIdx.x * 128;
  int rbase = i0 + w * 32;
  int sp = blockIdx.y;
  const int jspan = N_ / JSPLIT;   // 1024

  bfrag aq[2][4];
#pragma unroll
  for (int mt = 0; mt < 2; ++mt)
#pragma unroll
    for (int kc = 0; kc < 4; ++kc)
      aq[mt][kc] = *(const bfrag*)&Qn[(size_t)(rbase + mt * 16 + lo16) * H_ + kc * 32 + quad * 8];

  f4 O[2][8];
#pragma unroll
  for (int mt = 0; mt < 2; ++mt)
#pragma unroll
    for (int ns = 0; ns < 8; ++ns) O[mt][ns] = (f4){0.f, 0.f, 0.f, 0.f};
  f4 lsum[2];
  lsum[0] = (f4){0.f, 0.f, 0.f, 0.f};
  lsum[1] = (f4){0.f, 0.f, 0.f, 0.f};

  int krow = t >> 2, kcol = (t & 3) * 32;
  int vrow = t >> 1, vcol = (t & 1) * 32;
  for (int jt = 0; jt < jspan / 64; ++jt) {
    int j0 = sp * jspan + jt * 64;
    __syncthreads();
    {
      const ushort* gk = &Kn[(size_t)(j0 + krow) * H_ + kcol];
      ushort* dk = &Ks[krow * 136 + kcol];
#pragma unroll
      for (int u = 0; u < 32; u += 4)
        *(ushort4*)&dk[u] = *(const ushort4*)&gk[u];
      const ushort* gv = &Vt[(size_t)vrow * N_ + j0 + vcol];
      ushort* dv = &Vs[vrow * 72 + vcol];
#pragma unroll
      for (int u = 0; u < 32; u += 4)
        *(ushort4*)&dv[u] = *(const ushort4*)&gv[u];
    }
    __syncthreads();
    float kp[4];
#pragma unroll
    for (int js = 0; js < 4; ++js) kp[js] = keepf[j0 + js * 16 + lo16];
#pragma unroll
    for (int js = 0; js < 4; ++js) {
      bfrag bk[4];
#pragma unroll
      for (int kc = 0; kc < 4; ++kc)
        bk[kc] = *(const bfrag*)&Ks[(js * 16 + lo16) * 136 + kc * 32 + quad * 8];
#pragma unroll
      for (int mt = 0; mt < 2; ++mt) {
        f4 acc = (f4){0.f, 0.f, 0.f, 0.f};
#pragma unroll
        for (int kc = 0; kc < 4; ++kc)
          acc = __builtin_amdgcn_mfma_f32_16x16x32_bf16(aq[mt][kc], bk[kc], acc, 0, 0, 0);
#pragma unroll
        for (int r = 0; r < 4; ++r) {
          float p = kp[js] * __expf(acc[r] - 1.f);   // cos-sim scores bounded: fixed max
          lsum[mt][r] += p;
          Ps[w][(mt * 16 + quad * 4 + r) * 72 + js * 16 + lo16] = f2bf(p);
        }
      }
    }
#pragma unroll
    for (int kc = 0; kc < 2; ++kc) {
      bfrag ap0 = *(const bfrag*)&Ps[w][lo16 * 72 + kc * 32 + quad * 8];
      bfrag ap1 = *(const bfrag*)&Ps[w][(16 + lo16) * 72 + kc * 32 + quad * 8];
#pragma unroll
      for (int ns = 0; ns < 8; ++ns) {
        bfrag bv = *(const bfrag*)&Vs[(ns * 16 + lo16) * 72 + kc * 32 + quad * 8];
        O[0][ns] = __builtin_amdgcn_mfma_f32_16x16x32_bf16(ap0, bv, O[0][ns], 0, 0, 0);
        O[1][ns] = __builtin_amdgcn_mfma_f32_16x16x32_bf16(ap1, bv, O[1][ns], 0, 0, 0);
      }
    }
  }
#pragma unroll
  for (int mt = 0; mt < 2; ++mt)
#pragma unroll
    for (int ns = 0; ns < 8; ++ns)
#pragma unroll
      for (int r = 0; r < 4; ++r) {
        int row = rbase + mt * 16 + quad * 4 + r;
        Opart[((size_t)sp * N_ + row) * H_ + ns * 16 + lo16] = O[mt][ns][r];
      }
#pragma unroll
  for (int x = 1; x <= 8; x <<= 1)
#pragma unroll
    for (int mt = 0; mt < 2; ++mt)
#pragma unroll
      for (int r = 0; r < 4; ++r) lsum[mt][r] += __shfl_xor(lsum[mt][r], x, 16);
  if (lo16 == 0) {
#pragma unroll
    for (int mt = 0; mt < 2; ++mt)
#pragma unroll
      for (int r = 0; r < 4; ++r)
        Lpart[(size_t)sp * N_ + rbase + mt * 16 + quad * 4 + r] = lsum[mt][r];
  }
}

__global__ __launch_bounds__(128) void k_attn_merge(const float* __restrict__ Opart,
      const float* __restrict__ Lpart, float* __restrict__ outp) {
  int i = blockIdx.x, t = threadIdx.x;
  float lg = 0.f;
#pragma unroll
  for (int s = 0; s < JSPLIT; ++s) lg += Lpart[(size_t)s * N_ + i];
  float inv = (lg > 0.f) ? 1.f / lg : 0.f;
  float acc = 0.f;
#pragma unroll
  for (int s = 0; s < JSPLIT; ++s)
    acc += Opart[((size_t)s * N_ + i) * H_ + t];
  outp[(size_t)i * H_ + t] = acc * inv;
}

// ---------------- elementwise ----------------
__global__ __launch_bounds__(256) void k_sub2(const float4* __restrict__ a,
      const float4* __restrict__ b, float4* __restrict__ o) {
  int i = blockIdx.x * 256 + threadIdx.x;
  float4 x = a[i], y = b[i], r;
  r.x = x.x - y.x; r.y = x.y - y.y; r.z = x.z - y.z; r.w = x.w - y.w;
  o[i] = r;
}

__global__ __launch_bounds__(256) void k_sub3(const float4* __restrict__ a,
      const float4* __restrict__ b, const float4* __restrict__ c, float4* __restrict__ o) {
  int i = blockIdx.x * 256 + threadIdx.x;
  float4 x = a[i], y = b[i], z = c[i], r;
  r.x = x.x - y.x - z.x; r.y = x.y - y.y - z.y; r.z = x.z - y.z - z.z; r.w = x.w - y.w - z.w;
  o[i] = r;
}

__global__ __launch_bounds__(128) void k_pred(const float* __restrict__ a,
      const float* __restrict__ b, const float* __restrict__ c,
      const float* __restrict__ wout, const float* __restrict__ bout,
      float* __restrict__ outp) {
  __shared__ float buf[128];
  int i = blockIdx.x, t = threadIdx.x;
  size_t idx = (size_t)i * H_ + t;
  float v = (a[idx] + b[idx] + c[idx]) * wout[t];
  float s = bred_sum128(v, buf);
  if (t == 0) outp[i] = s + bout[0];
}

// ---------------- host ----------------
extern "C" void kernel_launch(void* const* d_in, const int* in_sizes, int n_in,
                              void* d_out, int out_size, void* d_ws, size_t ws_size,
                              hipStream_t stream) {
  const float* x          = (const float*)d_in[0];
  const float* mv         = (const float*)d_in[1];
  const int*   cm         = (const int*)d_in[2];
  const float* W_ps       = (const float*)d_in[3];
  const float* b_ps       = (const float*)d_in[4];
  const float* W_hs       = (const float*)d_in[5];
  const float* b_hs       = (const float*)d_in[6];
  const float* W_ps_fore  = (const float*)d_in[7];
  const float* b_ps_fore  = (const float*)d_in[8];
  const float* W_hs_fore  = (const float*)d_in[9];
  const float* b_hs_fore  = (const float*)d_in[10];
  const float* W_ps_back  = (const float*)d_in[11];
  const float* b_ps_back  = (const float*)d_in[12];
  const float* W_hs_back  = (const float*)d_in[13];
  const float* b_hs_back  = (const float*)d_in[14];
  const float* W_indi     = (const float*)d_in[15];
  const float* b_indi     = (const float*)d_in[16];
  const float* W_out      = (const float*)d_in[23];
  const float* b_out      = (const float*)d_in[24];
  float* outp = (float*)d_out;

  float* W = (float*)d_ws;
  const size_t NC = (size_t)N_ * C_;   // NC = 4*NH
  const size_t NH = (size_t)N_ * H_;
  const size_t CH = (size_t)C_ * H_;
  float* Sbuf = W;
  float* pback   = Sbuf;
  float* outps   = Sbuf + NH;
  float* hback   = Sbuf + 2 * NH;
  float* outindi = Sbuf + 3 * NH;
  size_t off = NC;
  float* T1       = W + off; off += NH;
  float* p_shared = W + off; off += NH;
  float* h_shared = W + off; off += NH;
  float* hidden3  = W + off; off += NH;
  float* h_info   = W + off; off += NH;
  float* out_hs   = W + off; off += NH;
  float* hidden1  = W + off; off += CH;
  float* hidden2  = W + off; off += CH;
  float* colsum1   = W + off; off += C_;
  float* colmax    = W + off; off += C_;
  float* colsumexp = W + off; off += C_;
  float* rny2      = W + off; off += C_;
  float* partb     = W + off; off += (size_t)CPB * C_;
  float* rnx     = W + off; off += N_;
  float* rqh     = W + off; off += N_;
  float* diagv   = W + off; off += N_;
  float* colsum3 = W + off; off += N_;
  float* rn3     = W + off; off += N_;
  float* gvals   = W + off; off += 3 * N_;
  float* Lpart   = W + off; off += (size_t)JSPLIT * N_;
  float* keepf   = W + off; off += N_;
  int* keep1 = (int*)(W + off); off += C_;
  int* keep2 = (int*)(W + off); off += N_;
  int* gidx  = (int*)(W + off); off += 3 * N_;
  ushort* Qn = (ushort*)(W + off); off += NH / 2;
  ushort* Kn = (ushort*)(W + off); off += NH / 2;
  ushort* Vt = (ushort*)(W + off); off += NH / 2;
  float* Opart = W + off; off += (size_t)JSPLIT * NH;   // stage-5 only
  // Gram scratch ALIASES Opart (stage-4 only; disjoint in time from attention):
  ushort* Ghi = (ushort*)Opart;
  ushort* Glo = Ghi + NH;
  int*    Gip = (int*)(Opart + NH);

  hipMemsetAsync(colsum1, 0, C_ * sizeof(float), stream);
  hipMemsetAsync(hidden1, 0, CH * sizeof(float), stream);
  hipMemsetAsync(hidden2, 0, CH * sizeof(float), stream);
  hipMemsetAsync(hidden3, 0, NH * sizeof(float), stream);
  hipMemsetAsync(colsum3, 0, N_ * sizeof(float), stream);

  // stage 1: market-value aggregation
  k_colsum1<<<dim3(2, 128), 256, 0, stream>>>(cm, mv, colsum1);
  k_agg<0><<<dim3(16, 64), 256, 0, stream>>>(x, cm, mv, nullptr, nullptr, hidden1);
  k_fin_hidden1<<<C_, 128, 0, stream>>>(hidden1, colsum1, keep1);
  k_rowstats<<<N_, 128, 0, stream>>>(x, rnx, nullptr, nullptr);

  // stage 2: softmax over stocks, hidden2 (S via MFMA hi/lo GEMM)
  k_mgemm<1, 0><<<dim3(C_ / 64, N_ / 64), 256, 0, stream>>>(
      x, H_, hidden1, H_, Sbuf, C_, H_, nullptr, nullptr, nullptr);
  k_colmax_part<<<CPB, 256, 0, stream>>>(Sbuf, partb);
  k_colfin_max<<<1, 512, 0, stream>>>(partb, colmax);
  k_colsum_part<<<CPB, 256, 0, stream>>>(Sbuf, colmax, partb);
  k_colfin_sum<<<1, 512, 0, stream>>>(partb, colsumexp);
  k_agg<1><<<dim3(16, 64), 256, 0, stream>>>(x, nullptr, nullptr, Sbuf, colmax, hidden2);
  k_fin_hidden2<<<C_, 128, 0, stream>>>(hidden2, colsumexp, rny2);

  // stage 3: c2s softmax + p branch (all GEMMs via MFMA hi/lo)
  k_mgemm<1, 0><<<dim3(C_ / 64, N_ / 64), 256, 0, stream>>>(
      x, H_, hidden2, H_, Sbuf, C_, H_, nullptr, rnx, rny2);
  k_rowsoftmax<<<N_, 256, 0, stream>>>(Sbuf, keep1);
  k_mgemm<0, 0><<<dim3(H_ / 64, N_ / 64), 256, 0, stream>>>(
      Sbuf, C_, hidden2, H_, T1, H_, C_, nullptr, nullptr, nullptr);
  k_mgemm<0, 0><<<dim3(H_ / 64, N_ / 64), 256, 0, stream>>>(
      T1, H_, W_ps, H_, p_shared, H_, H_, b_ps, nullptr, nullptr);
  k_mgemm<0, 0><<<dim3(H_ / 64, N_ / 64), 256, 0, stream>>>(
      p_shared, H_, W_ps_back, H_, pback, H_, H_, b_ps_back, nullptr, nullptr);
  k_mgemm<0, 1><<<dim3(H_ / 64, N_ / 64), 256, 0, stream>>>(
      p_shared, H_, W_ps_fore, H_, outps, H_, H_, b_ps_fore, nullptr, nullptr);

  // stage 4: h_shared, N x N top-3 graph (MFMA candidates + exact rescore)
  k_sub2<<<NH / 4 / 256, 256, 0, stream>>>((const float4*)x, (const float4*)pback,
                                           (float4*)h_shared);
  k_rowstats<<<N_, 128, 0, stream>>>(h_shared, rqh, diagv, nullptr);
  k_prep_gram<<<N_ / 8, 256, 0, stream>>>(h_shared, rqh, Ghi, Glo);
  k_gram_mfma<<<dim3(N_ / 128, GSPLIT), 256, 0, stream>>>(Ghi, Glo, Gip);
  k_gram_rescore<<<N_ / 4, 256, 0, stream>>>(h_shared, rqh, Gip, gvals, gidx);
  k_scatter<<<N_, 128, 0, stream>>>(h_shared, gvals, gidx, hidden3, colsum3);
  k_h3fin<<<N_, 128, 0, stream>>>(hidden3, h_shared, colsum3, diagv, rn3, keep2);

  // stage 5: MFMA flash attention (fixed-max, LDS-staged K/V), h branch
  k_prep_attn<<<N_ / 64, 256, 0, stream>>>(h_shared, hidden3, rqh, rn3, keep2,
                                           Qn, Kn, Vt, keepf);
  k_attn_mfma<<<dim3(N_ / 128, JSPLIT), 256, 0, stream>>>(Qn, Kn, Vt, keepf,
                                                          Opart, Lpart);
  k_attn_merge<<<N_, 128, 0, stream>>>(Opart, Lpart, T1);
  k_mgemm<0, 0><<<dim3(H_ / 64, N_ / 64), 256, 0, stream>>>(
      T1, H_, W_hs, H_, h_info, H_, H_, b_hs, nullptr, nullptr);
  k_mgemm<0, 0><<<dim3(H_ / 64, N_ / 64), 256, 0, stream>>>(
      h_info, H_, W_hs_back, H_, hback, H_, H_, b_hs_back, nullptr, nullptr);
  k_mgemm<0, 1><<<dim3(H_ / 64, N_ / 64), 256, 0, stream>>>(
      h_info, H_, W_hs_fore, H_, out_hs, H_, H_, b_hs_fore, nullptr, nullptr);

  // stage 6: individual branch + final projection
  k_sub3<<<NH / 4 / 256, 256, 0, stream>>>((const float4*)x, (const float4*)pback,
                                           (const float4*)hback, (float4*)h_shared);
  k_mgemm<0, 1><<<dim3(H_ / 64, N_ / 64), 256, 0, stream>>>(
      h_shared, H_, W_indi, H_, outindi, H_, H_, b_indi, nullptr, nullptr);
  k_pred<<<N_, 128, 0, stream>>>(outps, out_hs, outindi, W_out, b_out, outp);
}

// Round 10
// 613.545 us; speedup vs baseline: 2.0600x; 1.0063x over previous
//
#include <hip/hip_runtime.h>
#include <float.h>
#include <math.h>

#define N_ 8192
#define C_ 512
#define H_ 128

typedef __attribute__((ext_vector_type(8))) short bfrag;
typedef __attribute__((ext_vector_type(4))) float f4;

__device__ __forceinline__ ushort f2bf(float f) {
  unsigned u = __float_as_uint(f);
  unsigned r = (u + 0x7fffu + ((u >> 16) & 1u)) >> 16;
  return (ushort)r;
}

// split 8 consecutive fp32 into bf16 hi/lo
__device__ __forceinline__ void split8_contig(const float* __restrict__ src,
      ushort* __restrict__ dh, ushort* __restrict__ dl) {
  float4 v0 = *(const float4*)src;
  float4 v1 = *(const float4*)(src + 4);
  float a[8] = {v0.x, v0.y, v0.z, v0.w, v1.x, v1.y, v1.z, v1.w};
  ushort hh[8], ll[8];
#pragma unroll
  for (int i = 0; i < 8; ++i) {
    hh[i] = f2bf(a[i]);
    float hf = __uint_as_float(((unsigned)hh[i]) << 16);
    ll[i] = f2bf(a[i] - hf);
  }
  *(ushort4*)&dh[0] = *(ushort4*)&hh[0];
  *(ushort4*)&dh[4] = *(ushort4*)&hh[4];
  *(ushort4*)&dl[0] = *(ushort4*)&ll[0];
  *(ushort4*)&dl[4] = *(ushort4*)&ll[4];
}

// ---------------- helpers ----------------
__device__ __forceinline__ float bred_sum128(float v, float* buf) {
  int t = threadIdx.x;
  buf[t] = v; __syncthreads();
  for (int s = 64; s > 0; s >>= 1) {
    if (t < s) buf[t] += buf[t + s];
    __syncthreads();
  }
  float r = buf[0]; __syncthreads();
  return r;
}

__device__ __forceinline__ void top3_ins(float (&tv)[3], int (&ti)[3], float v, int j) {
  bool b2 = (v > tv[2]) || (v == tv[2] && j < ti[2]);
  if (!b2) return;
  bool b1 = (v > tv[1]) || (v == tv[1] && j < ti[1]);
  if (b1) {
    tv[2] = tv[1]; ti[2] = ti[1];
    bool b0 = (v > tv[0]) || (v == tv[0] && j < ti[0]);
    if (b0) { tv[1] = tv[0]; ti[1] = ti[0]; tv[0] = v; ti[0] = j; }
    else    { tv[1] = v;     ti[1] = j; }
  } else { tv[2] = v; ti[2] = j; }
}

// fast insert: per-lane stream is j-ascending, strict > keeps lowest j on ties
__device__ __forceinline__ void top3_fast(float (&tv)[3], int (&ti)[3], float v, int j) {
  if (v <= tv[2]) return;
  if (v > tv[1]) {
    tv[2] = tv[1]; ti[2] = ti[1];
    if (v > tv[0]) { tv[1] = tv[0]; ti[1] = ti[0]; tv[0] = v; ti[0] = j; }
    else           { tv[1] = v;     ti[1] = j; }
  } else { tv[2] = v; ti[2] = j; }
}

// ---------------- stage 1: concept aggregation ----------------
__global__ __launch_bounds__(256) void k_colsum1(const int* __restrict__ cm,
      const float* __restrict__ mv, float* __restrict__ colsum1) {
  int t = threadIdx.x;
  int c = blockIdx.x * 256 + t;
  int r0 = blockIdx.y * 64;
  float acc = 0.f;
  for (int r = 0; r < 64; ++r) {
    int i = r0 + r;
    acc += (float)cm[(size_t)i * C_ + c] * mv[i];
  }
  atomicAdd(&colsum1[c], acc);
}

template<int MODE>
__global__ __launch_bounds__(256) void k_agg(const float* __restrict__ x,
      const int* __restrict__ cm, const float* __restrict__ mv,
      const float* __restrict__ S, const float* __restrict__ colmax,
      float* __restrict__ outCH) {
  __shared__ float ws[8][32];
  int t = threadIdx.x;
  int cbase = blockIdx.x * 32;
  int h = t & 127, half = t >> 7;
  float acc[16];
#pragma unroll
  for (int k = 0; k < 16; ++k) acc[k] = 0.f;
  int sr = t >> 5, sc = t & 31;
  for (int sub = 0; sub < 16; ++sub) {
    int ibase = blockIdx.y * 128 + sub * 8;
    {
      int i = ibase + sr, c = cbase + sc;
      float w;
      if (MODE == 0) w = cm[(size_t)i * C_ + c] ? mv[i] : 0.f;
      else           w = __expf(S[(size_t)i * C_ + c] - colmax[c]);
      ws[sr][sc] = w;
    }
    __syncthreads();
#pragma unroll
    for (int r = 0; r < 8; ++r) {
      float xv = x[(size_t)(ibase + r) * H_ + h];
      const float* wr = &ws[r][half * 16];
#pragma unroll
      for (int k = 0; k < 16; ++k) acc[k] += wr[k] * xv;
    }
    __syncthreads();
  }
#pragma unroll
  for (int k = 0; k < 16; ++k)
    atomicAdd(&outCH[(size_t)(cbase + half * 16 + k) * H_ + h], acc[k]);
}

__global__ __launch_bounds__(128) void k_fin_hidden1(float* __restrict__ h1,
      const float* __restrict__ colsum1, int* __restrict__ keep1) {
  __shared__ float buf[128];
  int c = blockIdx.x, t = threadIdx.x;
  float v = h1[(size_t)c * H_ + t] / (colsum1[c] + 1.f);
  h1[(size_t)c * H_ + t] = v;
  float sm = bred_sum128(v, buf);
  if (t == 0) keep1[c] = (sm != 0.f) ? 1 : 0;
}

__global__ __launch_bounds__(128) void k_fin_hidden2(float* __restrict__ h2,
      const float* __restrict__ colsumexp, float* __restrict__ rny) {
  __shared__ float buf[128];
  int c = blockIdx.x, t = threadIdx.x;
  float v = h2[(size_t)c * H_ + t] / colsumexp[c];
  h2[(size_t)c * H_ + t] = v;
  float ss = bred_sum128(v * v, buf);
  if (t == 0) rny[c] = (ss > 0.f) ? 1.f / sqrtf(ss) : 0.f;
}

__global__ __launch_bounds__(128) void k_rowstats(const float* __restrict__ A,
      float* __restrict__ rinv, float* __restrict__ diag, int* __restrict__ keep) {
  __shared__ float buf[128];
  int i = blockIdx.x, t = threadIdx.x;
  float v = A[(size_t)i * H_ + t];
  float ss = bred_sum128(v * v, buf);
  float sm = bred_sum128(v, buf);
  if (t == 0) {
    float nr = sqrtf(ss);
    if (rinv) rinv[i] = (ss > 0.f) ? 1.f / nr : 0.f;
    if (diag) diag[i] = (ss > 0.f) ? ss / (nr * nr) : 0.f;
    if (keep) keep[i] = (sm != 0.f) ? 1 : 0;
  }
}

// ---------------- MFMA GEMM, hi/lo-compensated bf16, fused split ----------------
template<int TRANSB, int ACT>
__global__ __launch_bounds__(256) void k_mgemm(const float* __restrict__ A, int lda,
      const float* __restrict__ B, int ldb, float* __restrict__ Cc, int ldc, int Kk,
      const float* __restrict__ bias, const float* __restrict__ rowscale,
      const float* __restrict__ colscale) {
  __shared__ ushort Ah[64 * 40], Al[64 * 40], Bh[64 * 40], Bl[64 * 40];
  int t = threadIdx.x;
  int l = t & 63, w = t >> 6;
  int lo16 = l & 15, quad = l >> 4;
  int n0 = blockIdx.x * 64, m0 = blockIdx.y * 64;
  int mt0 = (w & 1) * 2, nt0 = (w >> 1) * 2;
  f4 acc[2][2];
#pragma unroll
  for (int mt = 0; mt < 2; ++mt)
#pragma unroll
    for (int nt = 0; nt < 2; ++nt) acc[mt][nt] = (f4){0.f, 0.f, 0.f, 0.f};

  int ar = t >> 2, ac = (t & 3) * 8;
  int kr = t >> 3, nc = (t & 7) * 8;
  for (int k0 = 0; k0 < Kk; k0 += 32) {
    __syncthreads();
    split8_contig(&A[(size_t)(m0 + ar) * lda + k0 + ac], &Ah[ar * 40 + ac], &Al[ar * 40 + ac]);
    if (TRANSB) {
      split8_contig(&B[(size_t)(n0 + ar) * ldb + k0 + ac], &Bh[ar * 40 + ac], &Bl[ar * 40 + ac]);
    } else {
      const float* src = &B[(size_t)(k0 + kr) * ldb + n0 + nc];
      float4 v0 = *(const float4*)src;
      float4 v1 = *(const float4*)(src + 4);
      float a[8] = {v0.x, v0.y, v0.z, v0.w, v1.x, v1.y, v1.z, v1.w};
#pragma unroll
      for (int i = 0; i < 8; ++i) {
        ushort hh = f2bf(a[i]);
        float hf = __uint_as_float(((unsigned)hh) << 16);
        Bh[(nc + i) * 40 + kr] = hh;
        Bl[(nc + i) * 40 + kr] = f2bf(a[i] - hf);
      }
    }
    __syncthreads();
    bfrag ah[2], al_[2], bh[2], bl[2];
#pragma unroll
    for (int mt = 0; mt < 2; ++mt) {
      int row = (mt0 + mt) * 16 + lo16;
      ah[mt]  = *(const bfrag*)&Ah[row * 40 + quad * 8];
      al_[mt] = *(const bfrag*)&Al[row * 40 + quad * 8];
    }
#pragma unroll
    for (int nt = 0; nt < 2; ++nt) {
      int col = (nt0 + nt) * 16 + lo16;
      bh[nt] = *(const bfrag*)&Bh[col * 40 + quad * 8];
      bl[nt] = *(const bfrag*)&Bl[col * 40 + quad * 8];
    }
#pragma unroll
    for (int mt = 0; mt < 2; ++mt)
#pragma unroll
      for (int nt = 0; nt < 2; ++nt) {
        f4 a0 = __builtin_amdgcn_mfma_f32_16x16x32_bf16(al_[mt], bh[nt], acc[mt][nt], 0, 0, 0);
        a0 = __builtin_amdgcn_mfma_f32_16x16x32_bf16(ah[mt], bl[nt], a0, 0, 0, 0);
        acc[mt][nt] = __builtin_amdgcn_mfma_f32_16x16x32_bf16(ah[mt], bh[nt], a0, 0, 0, 0);
      }
  }
#pragma unroll
  for (int mt = 0; mt < 2; ++mt)
#pragma unroll
    for (int r = 0; r < 4; ++r) {
      int row = m0 + (mt0 + mt) * 16 + quad * 4 + r;
      float rs = rowscale ? rowscale[row] : 1.f;
#pragma unroll
      for (int nt = 0; nt < 2; ++nt) {
        int col = n0 + (nt0 + nt) * 16 + lo16;
        float v = acc[mt][nt][r] * rs;
        if (colscale) v *= colscale[col];
        if (bias) v += bias[col];
        if (ACT) v = (v > 0.f) ? v : 0.01f * v;
        Cc[(size_t)row * ldc + col] = v;
      }
    }
}

// ---------------- fused dual-B MFMA GEMM: C1 = A@B1 + b1; C2 = act(A@B2 + b2) --------
// TRANSB=0 only (B [K,Nn] row-major). Stages A once for both outputs.
__global__ __launch_bounds__(256) void k_mgemm2(const float* __restrict__ A, int lda,
      const float* __restrict__ B1, const float* __restrict__ B2, int ldb,
      float* __restrict__ C1, float* __restrict__ C2, int ldc, int Kk,
      const float* __restrict__ bias1, const float* __restrict__ bias2) {
  __shared__ ushort Ah[64 * 40], Al[64 * 40];
  __shared__ ushort B1h[64 * 40], B1l[64 * 40], B2h[64 * 40], B2l[64 * 40];
  int t = threadIdx.x;
  int l = t & 63, w = t >> 6;
  int lo16 = l & 15, quad = l >> 4;
  int n0 = blockIdx.x * 64, m0 = blockIdx.y * 64;
  int mt0 = (w & 1) * 2, nt0 = (w >> 1) * 2;
  f4 acc1[2][2], acc2[2][2];
#pragma unroll
  for (int mt = 0; mt < 2; ++mt)
#pragma unroll
    for (int nt = 0; nt < 2; ++nt) {
      acc1[mt][nt] = (f4){0.f, 0.f, 0.f, 0.f};
      acc2[mt][nt] = (f4){0.f, 0.f, 0.f, 0.f};
    }
  int ar = t >> 2, ac = (t & 3) * 8;
  int kr = t >> 3, nc = (t & 7) * 8;
  for (int k0 = 0; k0 < Kk; k0 += 32) {
    __syncthreads();
    split8_contig(&A[(size_t)(m0 + ar) * lda + k0 + ac], &Ah[ar * 40 + ac], &Al[ar * 40 + ac]);
#pragma unroll
    for (int bsel = 0; bsel < 2; ++bsel) {
      const float* src = (bsel ? &B2[(size_t)(k0 + kr) * ldb + n0 + nc]
                               : &B1[(size_t)(k0 + kr) * ldb + n0 + nc]);
      ushort* dh = bsel ? B2h : B1h;
      ushort* dl = bsel ? B2l : B1l;
      float4 v0 = *(const float4*)src;
      float4 v1 = *(const float4*)(src + 4);
      float a[8] = {v0.x, v0.y, v0.z, v0.w, v1.x, v1.y, v1.z, v1.w};
#pragma unroll
      for (int i = 0; i < 8; ++i) {
        ushort hh = f2bf(a[i]);
        float hf = __uint_as_float(((unsigned)hh) << 16);
        dh[(nc + i) * 40 + kr] = hh;
        dl[(nc + i) * 40 + kr] = f2bf(a[i] - hf);
      }
    }
    __syncthreads();
    bfrag ah[2], al_[2];
#pragma unroll
    for (int mt = 0; mt < 2; ++mt) {
      int row = (mt0 + mt) * 16 + lo16;
      ah[mt]  = *(const bfrag*)&Ah[row * 40 + quad * 8];
      al_[mt] = *(const bfrag*)&Al[row * 40 + quad * 8];
    }
#pragma unroll
    for (int nt = 0; nt < 2; ++nt) {
      int col = (nt0 + nt) * 16 + lo16;
      bfrag b1h = *(const bfrag*)&B1h[col * 40 + quad * 8];
      bfrag b1l = *(const bfrag*)&B1l[col * 40 + quad * 8];
      bfrag b2h = *(const bfrag*)&B2h[col * 40 + quad * 8];
      bfrag b2l = *(const bfrag*)&B2l[col * 40 + quad * 8];
#pragma unroll
      for (int mt = 0; mt < 2; ++mt) {
        f4 a0 = __builtin_amdgcn_mfma_f32_16x16x32_bf16(al_[mt], b1h, acc1[mt][nt], 0, 0, 0);
        a0 = __builtin_amdgcn_mfma_f32_16x16x32_bf16(ah[mt], b1l, a0, 0, 0, 0);
        acc1[mt][nt] = __builtin_amdgcn_mfma_f32_16x16x32_bf16(ah[mt], b1h, a0, 0, 0, 0);
        f4 a1 = __builtin_amdgcn_mfma_f32_16x16x32_bf16(al_[mt], b2h, acc2[mt][nt], 0, 0, 0);
        a1 = __builtin_amdgcn_mfma_f32_16x16x32_bf16(ah[mt], b2l, a1, 0, 0, 0);
        acc2[mt][nt] = __builtin_amdgcn_mfma_f32_16x16x32_bf16(ah[mt], b2h, a1, 0, 0, 0);
      }
    }
  }
#pragma unroll
  for (int mt = 0; mt < 2; ++mt)
#pragma unroll
    for (int r = 0; r < 4; ++r) {
      int row = m0 + (mt0 + mt) * 16 + quad * 4 + r;
#pragma unroll
      for (int nt = 0; nt < 2; ++nt) {
        int col = n0 + (nt0 + nt) * 16 + lo16;
        C1[(size_t)row * ldc + col] = acc1[mt][nt][r] + bias1[col];
        float v = acc2[mt][nt][r] + bias2[col];
        C2[(size_t)row * ldc + col] = (v > 0.f) ? v : 0.01f * v;
      }
    }
}

// ---------------- column softmax over S[N,C] ----------------
#define CPB 128
__global__ __launch_bounds__(256) void k_colmax_part(const float* __restrict__ S,
      float* __restrict__ part) {
  int t = threadIdx.x, b = blockIdx.x;
  int r0 = b * (N_ / CPB);
  float m0 = -FLT_MAX, m1 = -FLT_MAX;
  for (int r = 0; r < N_ / CPB; ++r) {
    const float* row = S + (size_t)(r0 + r) * C_;
    m0 = fmaxf(m0, row[t]);
    m1 = fmaxf(m1, row[t + 256]);
  }
  part[(size_t)b * C_ + t] = m0;
  part[(size_t)b * C_ + t + 256] = m1;
}

__global__ __launch_bounds__(256) void k_colsum_part(const float* __restrict__ S,
      const float* __restrict__ colmax, float* __restrict__ part) {
  int t = threadIdx.x, b = blockIdx.x;
  int r0 = b * (N_ / CPB);
  float cm0 = colmax[t], cm1 = colmax[t + 256];
  float s0 = 0.f, s1 = 0.f;
  for (int r = 0; r < N_ / CPB; ++r) {
    const float* row = S + (size_t)(r0 + r) * C_;
    s0 += __expf(row[t] - cm0);
    s1 += __expf(row[t + 256] - cm1);
  }
  part[(size_t)b * C_ + t] = s0;
  part[(size_t)b * C_ + t + 256] = s1;
}

__global__ __launch_bounds__(512) void k_colfin_max(const float* __restrict__ part,
      float* __restrict__ outv) {
  int c = threadIdx.x;
  float m = -FLT_MAX;
  for (int b = 0; b < CPB; ++b) m = fmaxf(m, part[(size_t)b * C_ + c]);
  outv[c] = m;
}

__global__ __launch_bounds__(512) void k_colfin_sum(const float* __restrict__ part,
      float* __restrict__ outv) {
  int c = threadIdx.x;
  float s = 0.f;
  for (int b = 0; b < CPB; ++b) s += part[(size_t)b * C_ + c];
  outv[c] = s;
}

// ---------------- row softmax (512 cols) with keep mask ----------------
__global__ __launch_bounds__(256) void k_rowsoftmax(float* __restrict__ Sm,
      const int* __restrict__ keep1) {
  __shared__ float buf[256];
  int i = blockIdx.x, t = threadIdx.x;
  float* row = Sm + (size_t)i * C_;
  int k0 = keep1[t], k1 = keep1[t + 256];
  float v0 = k0 ? row[t] : -FLT_MAX;
  float v1 = k1 ? row[t + 256] : -FLT_MAX;
  buf[t] = fmaxf(v0, v1); __syncthreads();
  for (int s = 128; s > 0; s >>= 1) {
    if (t < s) buf[t] = fmaxf(buf[t], buf[t + s]);
    __syncthreads();
  }
  float m = buf[0]; __syncthreads();
  float e0 = k0 ? expf(v0 - m) : 0.f;
  float e1 = k1 ? expf(v1 - m) : 0.f;
  buf[t] = e0 + e1; __syncthreads();
  for (int s = 128; s > 0; s >>= 1) {
    if (t < s) buf[t] += buf[t + s];
    __syncthreads();
  }
  float inv = 1.f / buf[0];
  row[t] = e0 * inv;
  row[t + 256] = e1 * inv;
}

// ---------------- gram prep: normalized rows split into bf16 hi + lo ----------------
__global__ __launch_bounds__(256) void k_prep_gram(const float* __restrict__ hs,
      const float* __restrict__ rn, ushort* __restrict__ Ghi, ushort* __restrict__ Glo) {
  int t = threadIdx.x;
  int row = blockIdx.x * 8 + (t >> 5);
  int c = (t & 31) * 4;
  float r = rn[row];
  float4 v = *(const float4*)&hs[(size_t)row * H_ + c];
  float q[4] = {v.x * r, v.y * r, v.z * r, v.w * r};
  ushort hi[4], lo[4];
#pragma unroll
  for (int k = 0; k < 4; ++k) {
    hi[k] = f2bf(q[k]);
    float hf = __uint_as_float(((unsigned)hi[k]) << 16);
    lo[k] = f2bf(q[k] - hf);
  }
  *(ushort4*)&Ghi[(size_t)row * H_ + c] = *(ushort4*)hi;
  *(ushort4*)&Glo[(size_t)row * H_ + c] = *(ushort4*)lo;
}

// ---------------- N x N Gram: 4-wave blocks, 32 rows/wave, LDS j-tiles --------------
// 3 INDEPENDENT 4-deep MFMA chains per (mt,js) (R8 structure: 8-deep chain regressed).
#define GSPLIT 16
__global__ __launch_bounds__(256) void k_gram_mfma(const ushort* __restrict__ Ghi,
      const ushort* __restrict__ Glo, int* __restrict__ Gip) {
  __shared__ ushort JH[64 * 136];
  __shared__ ushort JL[64 * 136];
  int t = threadIdx.x;
  int l = t & 63, w = t >> 6;
  int lo16 = l & 15, quad = l >> 4;
  int i0 = blockIdx.x * 128;
  int rbase = i0 + w * 32;
  int sp = blockIdx.y;
  const int jspan = N_ / GSPLIT;   // 512

  bfrag ahi[2][4], alo[2][4];
#pragma unroll
  for (int mt = 0; mt < 2; ++mt)
#pragma unroll
    for (int kc = 0; kc < 4; ++kc) {
      size_t base = (size_t)(rbase + mt * 16 + lo16) * H_ + kc * 32 + quad * 8;
      ahi[mt][kc] = *(const bfrag*)&Ghi[base];
      alo[mt][kc] = *(const bfrag*)&Glo[base];
    }

  float tv[2][4][3]; int ti[2][4][3];
#pragma unroll
  for (int mt = 0; mt < 2; ++mt)
#pragma unroll
    for (int r = 0; r < 4; ++r)
#pragma unroll
      for (int s = 0; s < 3; ++s) { tv[mt][r][s] = -FLT_MAX; ti[mt][r][s] = 0x7fffffff; }

  int srow = t >> 2, scol = (t & 3) * 32;
  for (int jt = 0; jt < jspan / 64; ++jt) {
    int j0 = sp * jspan + jt * 64;
    __syncthreads();
    {
      const ushort* gh = &Ghi[(size_t)(j0 + srow) * H_ + scol];
      const ushort* gl = &Glo[(size_t)(j0 + srow) * H_ + scol];
      ushort* dh = &JH[srow * 136 + scol];
      ushort* dl = &JL[srow * 136 + scol];
#pragma unroll
      for (int u = 0; u < 32; u += 4) {
        *(ushort4*)&dh[u] = *(const ushort4*)&gh[u];
        *(ushort4*)&dl[u] = *(const ushort4*)&gl[u];
      }
    }
    __syncthreads();
#pragma unroll
    for (int js = 0; js < 4; ++js) {
      int jl_ = js * 16 + lo16;
      int j = j0 + jl_;
      bfrag bhi[4], blo[4];
#pragma unroll
      for (int kc = 0; kc < 4; ++kc) {
        int base = jl_ * 136 + kc * 32 + quad * 8;
        bhi[kc] = *(const bfrag*)&JH[base];
        blo[kc] = *(const bfrag*)&JL[base];
      }
#pragma unroll
      for (int mt = 0; mt < 2; ++mt) {
        f4 ahh = (f4){0.f, 0.f, 0.f, 0.f};
        f4 ahl = (f4){0.f, 0.f, 0.f, 0.f};
        f4 alh = (f4){0.f, 0.f, 0.f, 0.f};
#pragma unroll
        for (int kc = 0; kc < 4; ++kc) {
          ahh = __builtin_amdgcn_mfma_f32_16x16x32_bf16(ahi[mt][kc], bhi[kc], ahh, 0, 0, 0);
          ahl = __builtin_amdgcn_mfma_f32_16x16x32_bf16(ahi[mt][kc], blo[kc], ahl, 0, 0, 0);
          alh = __builtin_amdgcn_mfma_f32_16x16x32_bf16(alo[mt][kc], bhi[kc], alh, 0, 0, 0);
        }
#pragma unroll
        for (int r = 0; r < 4; ++r) {
          int gi = rbase + mt * 16 + quad * 4 + r;
          float v = (j == gi) ? 0.f : (ahh[r] + ahl[r] + alh[r]);
          top3_fast(tv[mt][r], ti[mt][r], v, j);
        }
      }
    }
  }
  // in-wave butterfly merge across the 16 lanes sharing each row
#pragma unroll
  for (int mt = 0; mt < 2; ++mt)
#pragma unroll
    for (int r = 0; r < 4; ++r) {
#pragma unroll
      for (int x = 1; x <= 8; x <<= 1) {
        float vv[3]; int ii[3];
#pragma unroll
        for (int s = 0; s < 3; ++s) {
          vv[s] = __shfl_xor(tv[mt][r][s], x, 16);
          ii[s] = __shfl_xor(ti[mt][r][s], x, 16);
        }
#pragma unroll
        for (int s = 0; s < 3; ++s) top3_ins(tv[mt][r], ti[mt][r], vv[s], ii[s]);
      }
    }
  if (lo16 == 0) {
#pragma unroll
    for (int mt = 0; mt < 2; ++mt)
#pragma unroll
      for (int r = 0; r < 4; ++r) {
        int row = rbase + mt * 16 + quad * 4 + r;
#pragma unroll
        for (int s = 0; s < 3; ++s)
          Gip[((size_t)sp * N_ + row) * 3 + s] = ti[mt][r][s];
      }
  }
}

// ---------------- exact fp32 rescore of 48 candidates/row -> final top-3 -------------
__global__ __launch_bounds__(256) void k_gram_rescore(const float* __restrict__ hs,
      const float* __restrict__ rn, const int* __restrict__ Gip,
      float* __restrict__ gvals, int* __restrict__ gidx) {
  int row = blockIdx.x * 4 + (threadIdx.x >> 6);
  int lane = threadIdx.x & 63;
  const float* qr = &hs[(size_t)row * H_];
  float q0 = qr[lane], q1 = qr[lane + 64];
  float rni = rn[row];
  float bv[3] = {-FLT_MAX, -FLT_MAX, -FLT_MAX};
  int bi[3] = {0x7fffffff, 0x7fffffff, 0x7fffffff};
  for (int s = 0; s < GSPLIT; ++s)
#pragma unroll
    for (int k = 0; k < 3; ++k) {
      int j = Gip[((size_t)s * N_ + row) * 3 + k];
      const float* jr = &hs[(size_t)j * H_];
      float d = q0 * jr[lane] + q1 * jr[lane + 64];
#pragma unroll
      for (int x = 1; x < 64; x <<= 1) d += __shfl_xor(d, x, 64);
      float v = (j == row) ? 0.f : d * rni * rn[j];
      top3_ins(bv, bi, v, j);
    }
  if (lane == 0) {
#pragma unroll
    for (int s = 0; s < 3; ++s) {
      gvals[(size_t)row * 3 + s] = bv[s];
      gidx[(size_t)row * 3 + s] = bi[s];
    }
  }
}

// ---------------- sparse scatter: hidden3 = hs2c^T @ h_shared ----------------
__global__ __launch_bounds__(128) void k_scatter(const float* __restrict__ hs,
      const float* __restrict__ gvals, const int* __restrict__ gidx,
      float* __restrict__ hidden3, float* __restrict__ colsum3) {
  int i = blockIdx.x, t = threadIdx.x;
  float xs = hs[(size_t)i * H_ + t];
#pragma unroll
  for (int k = 0; k < 3; ++k) {
    int j = gidx[i * 3 + k];
    float v = gvals[i * 3 + k];
    atomicAdd(&hidden3[(size_t)j * H_ + t], v * xs);
  }
  if (t == 0) {
#pragma unroll
    for (int k = 0; k < 3; ++k) atomicAdd(&colsum3[gidx[i * 3 + k]], gvals[i * 3 + k]);
  }
}

__global__ __launch_bounds__(128) void k_h3fin(float* __restrict__ hidden3,
      const float* __restrict__ hs, const float* __restrict__ colsum3,
      const float* __restrict__ diagv, float* __restrict__ rn3, int* __restrict__ keep2) {
  __shared__ float buf[128];
  int j = blockIdx.x, t = threadIdx.x;
  float v = hidden3[(size_t)j * H_ + t];
  if (colsum3[j] != 0.f) v += diagv[j] * hs[(size_t)j * H_ + t];
  hidden3[(size_t)j * H_ + t] = v;
  float ss = bred_sum128(v * v, buf);
  float sm = bred_sum128(v, buf);
  if (t == 0) {
    rn3[j] = (ss > 0.f) ? 1.f / sqrtf(ss) : 0.f;
    keep2[j] = (sm != 0.f) ? 1 : 0;
  }
}

// ---------------- attention prep: bf16 Qn/Kn, transposed V, keep as float ----------
__global__ __launch_bounds__(256) void k_prep_attn(const float* __restrict__ hs,
      const float* __restrict__ h3, const float* __restrict__ rqh,
      const float* __restrict__ rn3, const int* __restrict__ keep2,
      ushort* __restrict__ Qn, ushort* __restrict__ Kn, ushort* __restrict__ Vt,
      float* __restrict__ keepf) {
  __shared__ ushort T[H_][68];
  int t = threadIdx.x;
  int i0 = blockIdx.x * 64;
  int r = i0 + (t >> 2);
  int c0 = (t & 3) * 32;
  float rq = rqh[r], r3 = rn3[r];
  for (int c = c0; c < c0 + 32; c += 4) {
    float4 hv = *(const float4*)&hs[(size_t)r * H_ + c];
    float4 h3v = *(const float4*)&h3[(size_t)r * H_ + c];
    ushort q4[4] = {f2bf(hv.x * rq), f2bf(hv.y * rq), f2bf(hv.z * rq), f2bf(hv.w * rq)};
    ushort k4[4] = {f2bf(h3v.x * r3), f2bf(h3v.y * r3), f2bf(h3v.z * r3), f2bf(h3v.w * r3)};
    *(ushort4*)&Qn[(size_t)r * H_ + c] = *(ushort4*)q4;
    *(ushort4*)&Kn[(size_t)r * H_ + c] = *(ushort4*)k4;
    T[c + 0][r - i0] = f2bf(h3v.x);
    T[c + 1][r - i0] = f2bf(h3v.y);
    T[c + 2][r - i0] = f2bf(h3v.z);
    T[c + 3][r - i0] = f2bf(h3v.w);
  }
  if (t < 64) keepf[i0 + t] = (float)keep2[i0 + t];
  __syncthreads();
  int h = t >> 1, off = (t & 1) * 32;
  for (int u = 0; u < 32; u += 4) {
    ushort4 vv;
    vv.x = T[h][off + u]; vv.y = T[h][off + u + 1];
    vv.z = T[h][off + u + 2]; vv.w = T[h][off + u + 3];
    *(ushort4*)&Vt[(size_t)h * N_ + i0 + off + u] = vv;
  }
}

// ---------------- MFMA flash attention: 4-wave blocks, 32 rows/wave, LDS K/V --------
#define JSPLIT 8
__global__ __launch_bounds__(256) void k_attn_mfma(const ushort* __restrict__ Qn,
      const ushort* __restrict__ Kn, const ushort* __restrict__ Vt,
      const float* __restrict__ keepf, float* __restrict__ Opart,
      float* __restrict__ Lpart) {
  __shared__ ushort Ks[64 * 136];
  __shared__ ushort Vs[128 * 72];
  __shared__ ushort Ps[4][32 * 72];
  int t = threadIdx.x;
  int l = t & 63, w = t >> 6;
  int lo16 = l & 15, quad = l >> 4;
  int i0 = blockIdx.x * 128;
  int rbase = i0 + w * 32;
  int sp = blockIdx.y;
  const int jspan = N_ / JSPLIT;   // 1024

  bfrag aq[2][4];
#pragma unroll
  for (int mt = 0; mt < 2; ++mt)
#pragma unroll
    for (int kc = 0; kc < 4; ++kc)
      aq[mt][kc] = *(const bfrag*)&Qn[(size_t)(rbase + mt * 16 + lo16) * H_ + kc * 32 + quad * 8];

  f4 O[2][8];
#pragma unroll
  for (int mt = 0; mt < 2; ++mt)
#pragma unroll
    for (int ns = 0; ns < 8; ++ns) O[mt][ns] = (f4){0.f, 0.f, 0.f, 0.f};
  f4 lsum[2];
  lsum[0] = (f4){0.f, 0.f, 0.f, 0.f};
  lsum[1] = (f4){0.f, 0.f, 0.f, 0.f};

  int krow = t >> 2, kcol = (t & 3) * 32;
  int vrow = t >> 1, vcol = (t & 1) * 32;
  for (int jt = 0; jt < jspan / 64; ++jt) {
    int j0 = sp * jspan + jt * 64;
    __syncthreads();
    {
      const ushort* gk = &Kn[(size_t)(j0 + krow) * H_ + kcol];
      ushort* dk = &Ks[krow * 136 + kcol];
#pragma unroll
      for (int u = 0; u < 32; u += 4)
        *(ushort4*)&dk[u] = *(const ushort4*)&gk[u];
      const ushort* gv = &Vt[(size_t)vrow * N_ + j0 + vcol];
      ushort* dv = &Vs[vrow * 72 + vcol];
#pragma unroll
      for (int u = 0; u < 32; u += 4)
        *(ushort4*)&dv[u] = *(const ushort4*)&gv[u];
    }
    __syncthreads();
    float kp[4];
#pragma unroll
    for (int js = 0; js < 4; ++js) kp[js] = keepf[j0 + js * 16 + lo16];
#pragma unroll
    for (int js = 0; js < 4; ++js) {
      bfrag bk[4];
#pragma unroll
      for (int kc = 0; kc < 4; ++kc)
        bk[kc] = *(const bfrag*)&Ks[(js * 16 + lo16) * 136 + kc * 32 + quad * 8];
#pragma unroll
      for (int mt = 0; mt < 2; ++mt) {
        f4 acc = (f4){0.f, 0.f, 0.f, 0.f};
#pragma unroll
        for (int kc = 0; kc < 4; ++kc)
          acc = __builtin_amdgcn_mfma_f32_16x16x32_bf16(aq[mt][kc], bk[kc], acc, 0, 0, 0);
#pragma unroll
        for (int r = 0; r < 4; ++r) {
          float p = kp[js] * __expf(acc[r] - 1.f);
          lsum[mt][r] += p;
          Ps[w][(mt * 16 + quad * 4 + r) * 72 + js * 16 + lo16] = f2bf(p);
        }
      }
    }
#pragma unroll
    for (int kc = 0; kc < 2; ++kc) {
      bfrag ap0 = *(const bfrag*)&Ps[w][lo16 * 72 + kc * 32 + quad * 8];
      bfrag ap1 = *(const bfrag*)&Ps[w][(16 + lo16) * 72 + kc * 32 + quad * 8];
#pragma unroll
      for (int ns = 0; ns < 8; ++ns) {
        bfrag bv = *(const bfrag*)&Vs[(ns * 16 + lo16) * 72 + kc * 32 + quad * 8];
        O[0][ns] = __builtin_amdgcn_mfma_f32_16x16x32_bf16(ap0, bv, O[0][ns], 0, 0, 0);
        O[1][ns] = __builtin_amdgcn_mfma_f32_16x16x32_bf16(ap1, bv, O[1][ns], 0, 0, 0);
      }
    }
  }
#pragma unroll
  for (int mt = 0; mt < 2; ++mt)
#pragma unroll
    for (int ns = 0; ns < 8; ++ns)
#pragma unroll
      for (int r = 0; r < 4; ++r) {
        int row = rbase + mt * 16 + quad * 4 + r;
        Opart[((size_t)sp * N_ + row) * H_ + ns * 16 + lo16] = O[mt][ns][r];
      }
#pragma unroll
  for (int x = 1; x <= 8; x <<= 1)
#pragma unroll
    for (int mt = 0; mt < 2; ++mt)
#pragma unroll
      for (int r = 0; r < 4; ++r) lsum[mt][r] += __shfl_xor(lsum[mt][r], x, 16);
  if (lo16 == 0) {
#pragma unroll
    for (int mt = 0; mt < 2; ++mt)
#pragma unroll
      for (int r = 0; r < 4; ++r)
        Lpart[(size_t)sp * N_ + rbase + mt * 16 + quad * 4 + r] = lsum[mt][r];
  }
}

__global__ __launch_bounds__(128) void k_attn_merge(const float* __restrict__ Opart,
      const float* __restrict__ Lpart, float* __restrict__ outp) {
  int i = blockIdx.x, t = threadIdx.x;
  float lg = 0.f;
#pragma unroll
  for (int s = 0; s < JSPLIT; ++s) lg += Lpart[(size_t)s * N_ + i];
  float inv = (lg > 0.f) ? 1.f / lg : 0.f;
  float acc = 0.f;
#pragma unroll
  for (int s = 0; s < JSPLIT; ++s)
    acc += Opart[((size_t)s * N_ + i) * H_ + t];
  outp[(size_t)i * H_ + t] = acc * inv;
}

// ---------------- elementwise ----------------
__global__ __launch_bounds__(256) void k_sub2(const float4* __restrict__ a,
      const float4* __restrict__ b, float4* __restrict__ o) {
  int i = blockIdx.x * 256 + threadIdx.x;
  float4 x = a[i], y = b[i], r;
  r.x = x.x - y.x; r.y = x.y - y.y; r.z = x.z - y.z; r.w = x.w - y.w;
  o[i] = r;
}

__global__ __launch_bounds__(256) void k_sub3(const float4* __restrict__ a,
      const float4* __restrict__ b, const float4* __restrict__ c, float4* __restrict__ o) {
  int i = blockIdx.x * 256 + threadIdx.x;
  float4 x = a[i], y = b[i], z = c[i], r;
  r.x = x.x - y.x - z.x; r.y = x.y - y.y - z.y; r.z = x.z - y.z - z.z; r.w = x.w - y.w - z.w;
  o[i] = r;
}

__global__ __launch_bounds__(128) void k_pred(const float* __restrict__ a,
      const float* __restrict__ b, const float* __restrict__ c,
      const float* __restrict__ wout, const float* __restrict__ bout,
      float* __restrict__ outp) {
  __shared__ float buf[128];
  int i = blockIdx.x, t = threadIdx.x;
  size_t idx = (size_t)i * H_ + t;
  float v = (a[idx] + b[idx] + c[idx]) * wout[t];
  float s = bred_sum128(v, buf);
  if (t == 0) outp[i] = s + bout[0];
}

// ---------------- host ----------------
extern "C" void kernel_launch(void* const* d_in, const int* in_sizes, int n_in,
                              void* d_out, int out_size, void* d_ws, size_t ws_size,
                              hipStream_t stream) {
  const float* x          = (const float*)d_in[0];
  const float* mv         = (const float*)d_in[1];
  const int*   cm         = (const int*)d_in[2];
  const float* W_ps       = (const float*)d_in[3];
  const float* b_ps       = (const float*)d_in[4];
  const float* W_hs       = (const float*)d_in[5];
  const float* b_hs       = (const float*)d_in[6];
  const float* W_ps_fore  = (const float*)d_in[7];
  const float* b_ps_fore  = (const float*)d_in[8];
  const float* W_hs_fore  = (const float*)d_in[9];
  const float* b_hs_fore  = (const float*)d_in[10];
  const float* W_ps_back  = (const float*)d_in[11];
  const float* b_ps_back  = (const float*)d_in[12];
  const float* W_hs_back  = (const float*)d_in[13];
  const float* b_hs_back  = (const float*)d_in[14];
  const float* W_indi     = (const float*)d_in[15];
  const float* b_indi     = (const float*)d_in[16];
  const float* W_out      = (const float*)d_in[23];
  const float* b_out      = (const float*)d_in[24];
  float* outp = (float*)d_out;

  float* W = (float*)d_ws;
  const size_t NC = (size_t)N_ * C_;   // NC = 4*NH
  const size_t NH = (size_t)N_ * H_;
  const size_t CH = (size_t)C_ * H_;
  float* Sbuf = W;
  float* pback   = Sbuf;
  float* outps   = Sbuf + NH;
  float* hback   = Sbuf + 2 * NH;
  float* outindi = Sbuf + 3 * NH;
  size_t off = NC;
  float* T1       = W + off; off += NH;
  float* p_shared = W + off; off += NH;
  float* h_shared = W + off; off += NH;
  float* hidden3  = W + off; off += NH;
  float* h_info   = W + off; off += NH;
  float* out_hs   = W + off; off += NH;
  float* hidden1  = W + off; off += CH;
  float* hidden2  = W + off; off += CH;
  float* colsum1   = W + off; off += C_;
  float* colmax    = W + off; off += C_;
  float* colsumexp = W + off; off += C_;
  float* rny2      = W + off; off += C_;
  float* partb     = W + off; off += (size_t)CPB * C_;
  float* rnx     = W + off; off += N_;
  float* rqh     = W + off; off += N_;
  float* diagv   = W + off; off += N_;
  float* colsum3 = W + off; off += N_;
  float* rn3     = W + off; off += N_;
  float* gvals   = W + off; off += 3 * N_;
  float* Lpart   = W + off; off += (size_t)JSPLIT * N_;
  float* keepf   = W + off; off += N_;
  int* keep1 = (int*)(W + off); off += C_;
  int* keep2 = (int*)(W + off); off += N_;
  int* gidx  = (int*)(W + off); off += 3 * N_;
  ushort* Qn = (ushort*)(W + off); off += NH / 2;
  ushort* Kn = (ushort*)(W + off); off += NH / 2;
  ushort* Vt = (ushort*)(W + off); off += NH / 2;
  float* Opart = W + off; off += (size_t)JSPLIT * NH;   // stage-5 only
  // Gram scratch ALIASES Opart (stage-4 only; disjoint in time from attention):
  ushort* Ghi = (ushort*)Opart;
  ushort* Glo = Ghi + NH;
  int*    Gip = (int*)(Opart + NH);   // GSPLIT*N*3 ints = 1.5 MB << Opart size

  hipMemsetAsync(colsum1, 0, C_ * sizeof(float), stream);
  hipMemsetAsync(hidden1, 0, CH * sizeof(float), stream);
  hipMemsetAsync(hidden2, 0, CH * sizeof(float), stream);
  hipMemsetAsync(hidden3, 0, NH * sizeof(float), stream);
  hipMemsetAsync(colsum3, 0, N_ * sizeof(float), stream);

  // stage 1: market-value aggregation
  k_colsum1<<<dim3(2, 128), 256, 0, stream>>>(cm, mv, colsum1);
  k_agg<0><<<dim3(16, 64), 256, 0, stream>>>(x, cm, mv, nullptr, nullptr, hidden1);
  k_fin_hidden1<<<C_, 128, 0, stream>>>(hidden1, colsum1, keep1);
  k_rowstats<<<N_, 128, 0, stream>>>(x, rnx, nullptr, nullptr);

  // stage 2: softmax over stocks, hidden2
  k_mgemm<1, 0><<<dim3(C_ / 64, N_ / 64), 256, 0, stream>>>(
      x, H_, hidden1, H_, Sbuf, C_, H_, nullptr, nullptr, nullptr);
  k_colmax_part<<<CPB, 256, 0, stream>>>(Sbuf, partb);
  k_colfin_max<<<1, 512, 0, stream>>>(partb, colmax);
  k_colsum_part<<<CPB, 256, 0, stream>>>(Sbuf, colmax, partb);
  k_colfin_sum<<<1, 512, 0, stream>>>(partb, colsumexp);
  k_agg<1><<<dim3(16, 64), 256, 0, stream>>>(x, nullptr, nullptr, Sbuf, colmax, hidden2);
  k_fin_hidden2<<<C_, 128, 0, stream>>>(hidden2, colsumexp, rny2);

  // stage 3: c2s softmax + p branch
  k_mgemm<1, 0><<<dim3(C_ / 64, N_ / 64), 256, 0, stream>>>(
      x, H_, hidden2, H_, Sbuf, C_, H_, nullptr, rnx, rny2);
  k_rowsoftmax<<<N_, 256, 0, stream>>>(Sbuf, keep1);
  k_mgemm<0, 0><<<dim3(H_ / 64, N_ / 64), 256, 0, stream>>>(
      Sbuf, C_, hidden2, H_, T1, H_, C_, nullptr, nullptr, nullptr);
  k_mgemm<0, 0><<<dim3(H_ / 64, N_ / 64), 256, 0, stream>>>(
      T1, H_, W_ps, H_, p_shared, H_, H_, b_ps, nullptr, nullptr);
  k_mgemm2<<<dim3(H_ / 64, N_ / 64), 256, 0, stream>>>(
      p_shared, H_, W_ps_back, W_ps_fore, H_, pback, outps, H_, H_, b_ps_back, b_ps_fore);

  // stage 4: h_shared, N x N top-3 graph (MFMA candidates + exact rescore)
  k_sub2<<<NH / 4 / 256, 256, 0, stream>>>((const float4*)x, (const float4*)pback,
                                           (float4*)h_shared);
  k_rowstats<<<N_, 128, 0, stream>>>(h_shared, rqh, diagv, nullptr);
  k_prep_gram<<<N_ / 8, 256, 0, stream>>>(h_shared, rqh, Ghi, Glo);
  k_gram_mfma<<<dim3(N_ / 128, GSPLIT), 256, 0, stream>>>(Ghi, Glo, Gip);
  k_gram_rescore<<<N_ / 4, 256, 0, stream>>>(h_shared, rqh, Gip, gvals, gidx);
  k_scatter<<<N_, 128, 0, stream>>>(h_shared, gvals, gidx, hidden3, colsum3);
  k_h3fin<<<N_, 128, 0, stream>>>(hidden3, h_shared, colsum3, diagv, rn3, keep2);

  // stage 5: MFMA flash attention (fixed-max, LDS-staged K/V), h branch
  k_prep_attn<<<N_ / 64, 256, 0, stream>>>(h_shared, hidden3, rqh, rn3, keep2,
                                           Qn, Kn, Vt, keepf);
  k_attn_mfma<<<dim3(N_ / 128, JSPLIT), 256, 0, stream>>>(Qn, Kn, Vt, keepf,
                                                          Opart, Lpart);
  k_attn_merge<<<N_, 128, 0, stream>>>(Opart, Lpart, T1);
  k_mgemm<0, 0><<<dim3(H_ / 64, N_ / 64), 256, 0, stream>>>(
      T1, H_, W_hs, H_, h_info, H_, H_, b_hs, nullptr, nullptr);
  k_mgemm2<<<dim3(H_ / 64, N_ / 64), 256, 0, stream>>>(
      h_info, H_, W_hs_back, W_hs_fore, H_, hback, out_hs, H_, H_, b_hs_back, b_hs_fore);

  // stage 6: individual branch + final projection
  k_sub3<<<NH / 4 / 256, 256, 0, stream>>>((const float4*)x, (const float4*)pback,
                                           (const float4*)hback, (float4*)h_shared);
  k_mgemm<0, 1><<<dim3(H_ / 64, N_ / 64), 256, 0, stream>>>(
      h_shared, H_, W_indi, H_, outindi, H_, H_, b_indi, nullptr, nullptr);
  k_pred<<<N_, 128, 0, stream>>>(outps, out_hs, outindi, W_out, b_out, outp);
}

// Round 11
// 582.094 us; speedup vs baseline: 2.1713x; 1.0540x over previous
//
#include <hip/hip_runtime.h>
#include <float.h>
#include <math.h>

#define N_ 8192
#define C_ 512
#define H_ 128

typedef __attribute__((ext_vector_type(8))) short bfrag;
typedef __attribute__((ext_vector_type(4))) float f4;

__device__ __forceinline__ ushort f2bf(float f) {
  unsigned u = __float_as_uint(f);
  unsigned r = (u + 0x7fffu + ((u >> 16) & 1u)) >> 16;
  return (ushort)r;
}

// split 8 consecutive fp32 into bf16 hi/lo
__device__ __forceinline__ void split8_contig(const float* __restrict__ src,
      ushort* __restrict__ dh, ushort* __restrict__ dl) {
  float4 v0 = *(const float4*)src;
  float4 v1 = *(const float4*)(src + 4);
  float a[8] = {v0.x, v0.y, v0.z, v0.w, v1.x, v1.y, v1.z, v1.w};
  ushort hh[8], ll[8];
#pragma unroll
  for (int i = 0; i < 8; ++i) {
    hh[i] = f2bf(a[i]);
    float hf = __uint_as_float(((unsigned)hh[i]) << 16);
    ll[i] = f2bf(a[i] - hf);
  }
  *(ushort4*)&dh[0] = *(ushort4*)&hh[0];
  *(ushort4*)&dh[4] = *(ushort4*)&hh[4];
  *(ushort4*)&dl[0] = *(ushort4*)&ll[0];
  *(ushort4*)&dl[4] = *(ushort4*)&ll[4];
}

// ---------------- helpers ----------------
__device__ __forceinline__ float bred_sum128(float v, float* buf) {
  int t = threadIdx.x;
  buf[t] = v; __syncthreads();
  for (int s = 64; s > 0; s >>= 1) {
    if (t < s) buf[t] += buf[t + s];
    __syncthreads();
  }
  float r = buf[0]; __syncthreads();
  return r;
}

__device__ __forceinline__ void top3_ins(float (&tv)[3], int (&ti)[3], float v, int j) {
  bool b2 = (v > tv[2]) || (v == tv[2] && j < ti[2]);
  if (!b2) return;
  bool b1 = (v > tv[1]) || (v == tv[1] && j < ti[1]);
  if (b1) {
    tv[2] = tv[1]; ti[2] = ti[1];
    bool b0 = (v > tv[0]) || (v == tv[0] && j < ti[0]);
    if (b0) { tv[1] = tv[0]; ti[1] = ti[0]; tv[0] = v; ti[0] = j; }
    else    { tv[1] = v;     ti[1] = j; }
  } else { tv[2] = v; ti[2] = j; }
}

// fast insert: per-lane stream is j-ascending, strict > keeps lowest j on ties
__device__ __forceinline__ void top3_fast(float (&tv)[3], int (&ti)[3], float v, int j) {
  if (v <= tv[2]) return;
  if (v > tv[1]) {
    tv[2] = tv[1]; ti[2] = ti[1];
    if (v > tv[0]) { tv[1] = tv[0]; ti[1] = ti[0]; tv[0] = v; ti[0] = j; }
    else           { tv[1] = v;     ti[1] = j; }
  } else { tv[2] = v; ti[2] = j; }
}

// ---------------- stage 1: concept aggregation ----------------
__global__ __launch_bounds__(256) void k_colsum1(const int* __restrict__ cm,
      const float* __restrict__ mv, float* __restrict__ colsum1) {
  int t = threadIdx.x;
  int c = blockIdx.x * 256 + t;
  int r0 = blockIdx.y * 64;
  float acc = 0.f;
  for (int r = 0; r < 64; ++r) {
    int i = r0 + r;
    acc += (float)cm[(size_t)i * C_ + c] * mv[i];
  }
  atomicAdd(&colsum1[c], acc);
}

template<int MODE>
__global__ __launch_bounds__(256) void k_agg(const float* __restrict__ x,
      const int* __restrict__ cm, const float* __restrict__ mv,
      const float* __restrict__ S, const float* __restrict__ colmax,
      float* __restrict__ outCH) {
  __shared__ float ws[8][32];
  int t = threadIdx.x;
  int cbase = blockIdx.x * 32;
  int h = t & 127, half = t >> 7;
  float acc[16];
#pragma unroll
  for (int k = 0; k < 16; ++k) acc[k] = 0.f;
  int sr = t >> 5, sc = t & 31;
  for (int sub = 0; sub < 16; ++sub) {
    int ibase = blockIdx.y * 128 + sub * 8;
    {
      int i = ibase + sr, c = cbase + sc;
      float w;
      if (MODE == 0) w = cm[(size_t)i * C_ + c] ? mv[i] : 0.f;
      else           w = __expf(S[(size_t)i * C_ + c] - colmax[c]);
      ws[sr][sc] = w;
    }
    __syncthreads();
#pragma unroll
    for (int r = 0; r < 8; ++r) {
      float xv = x[(size_t)(ibase + r) * H_ + h];
      const float* wr = &ws[r][half * 16];
#pragma unroll
      for (int k = 0; k < 16; ++k) acc[k] += wr[k] * xv;
    }
    __syncthreads();
  }
#pragma unroll
  for (int k = 0; k < 16; ++k)
    atomicAdd(&outCH[(size_t)(cbase + half * 16 + k) * H_ + h], acc[k]);
}

__global__ __launch_bounds__(128) void k_fin_hidden1(float* __restrict__ h1,
      const float* __restrict__ colsum1, int* __restrict__ keep1) {
  __shared__ float buf[128];
  int c = blockIdx.x, t = threadIdx.x;
  float v = h1[(size_t)c * H_ + t] / (colsum1[c] + 1.f);
  h1[(size_t)c * H_ + t] = v;
  float sm = bred_sum128(v, buf);
  if (t == 0) keep1[c] = (sm != 0.f) ? 1 : 0;
}

__global__ __launch_bounds__(128) void k_fin_hidden2(float* __restrict__ h2,
      const float* __restrict__ colsumexp, float* __restrict__ rny) {
  __shared__ float buf[128];
  int c = blockIdx.x, t = threadIdx.x;
  float v = h2[(size_t)c * H_ + t] / colsumexp[c];
  h2[(size_t)c * H_ + t] = v;
  float ss = bred_sum128(v * v, buf);
  if (t == 0) rny[c] = (ss > 0.f) ? 1.f / sqrtf(ss) : 0.f;
}

__global__ __launch_bounds__(128) void k_rowstats(const float* __restrict__ A,
      float* __restrict__ rinv, float* __restrict__ diag, int* __restrict__ keep) {
  __shared__ float buf[128];
  int i = blockIdx.x, t = threadIdx.x;
  float v = A[(size_t)i * H_ + t];
  float ss = bred_sum128(v * v, buf);
  float sm = bred_sum128(v, buf);
  if (t == 0) {
    float nr = sqrtf(ss);
    if (rinv) rinv[i] = (ss > 0.f) ? 1.f / nr : 0.f;
    if (diag) diag[i] = (ss > 0.f) ? ss / (nr * nr) : 0.f;
    if (keep) keep[i] = (sm != 0.f) ? 1 : 0;
  }
}

// ---------------- MFMA GEMM, hi/lo-compensated bf16, fused split ----------------
template<int TRANSB, int ACT>
__global__ __launch_bounds__(256) void k_mgemm(const float* __restrict__ A, int lda,
      const float* __restrict__ B, int ldb, float* __restrict__ Cc, int ldc, int Kk,
      const float* __restrict__ bias, const float* __restrict__ rowscale,
      const float* __restrict__ colscale) {
  __shared__ ushort Ah[64 * 40], Al[64 * 40], Bh[64 * 40], Bl[64 * 40];
  int t = threadIdx.x;
  int l = t & 63, w = t >> 6;
  int lo16 = l & 15, quad = l >> 4;
  int n0 = blockIdx.x * 64, m0 = blockIdx.y * 64;
  int mt0 = (w & 1) * 2, nt0 = (w >> 1) * 2;
  f4 acc[2][2];
#pragma unroll
  for (int mt = 0; mt < 2; ++mt)
#pragma unroll
    for (int nt = 0; nt < 2; ++nt) acc[mt][nt] = (f4){0.f, 0.f, 0.f, 0.f};

  int ar = t >> 2, ac = (t & 3) * 8;
  int kr = t >> 3, nc = (t & 7) * 8;
  for (int k0 = 0; k0 < Kk; k0 += 32) {
    __syncthreads();
    split8_contig(&A[(size_t)(m0 + ar) * lda + k0 + ac], &Ah[ar * 40 + ac], &Al[ar * 40 + ac]);
    if (TRANSB) {
      split8_contig(&B[(size_t)(n0 + ar) * ldb + k0 + ac], &Bh[ar * 40 + ac], &Bl[ar * 40 + ac]);
    } else {
      const float* src = &B[(size_t)(k0 + kr) * ldb + n0 + nc];
      float4 v0 = *(const float4*)src;
      float4 v1 = *(const float4*)(src + 4);
      float a[8] = {v0.x, v0.y, v0.z, v0.w, v1.x, v1.y, v1.z, v1.w};
#pragma unroll
      for (int i = 0; i < 8; ++i) {
        ushort hh = f2bf(a[i]);
        float hf = __uint_as_float(((unsigned)hh) << 16);
        Bh[(nc + i) * 40 + kr] = hh;
        Bl[(nc + i) * 40 + kr] = f2bf(a[i] - hf);
      }
    }
    __syncthreads();
    bfrag ah[2], al_[2], bh[2], bl[2];
#pragma unroll
    for (int mt = 0; mt < 2; ++mt) {
      int row = (mt0 + mt) * 16 + lo16;
      ah[mt]  = *(const bfrag*)&Ah[row * 40 + quad * 8];
      al_[mt] = *(const bfrag*)&Al[row * 40 + quad * 8];
    }
#pragma unroll
    for (int nt = 0; nt < 2; ++nt) {
      int col = (nt0 + nt) * 16 + lo16;
      bh[nt] = *(const bfrag*)&Bh[col * 40 + quad * 8];
      bl[nt] = *(const bfrag*)&Bl[col * 40 + quad * 8];
    }
#pragma unroll
    for (int mt = 0; mt < 2; ++mt)
#pragma unroll
      for (int nt = 0; nt < 2; ++nt) {
        f4 a0 = __builtin_amdgcn_mfma_f32_16x16x32_bf16(al_[mt], bh[nt], acc[mt][nt], 0, 0, 0);
        a0 = __builtin_amdgcn_mfma_f32_16x16x32_bf16(ah[mt], bl[nt], a0, 0, 0, 0);
        acc[mt][nt] = __builtin_amdgcn_mfma_f32_16x16x32_bf16(ah[mt], bh[nt], a0, 0, 0, 0);
      }
  }
#pragma unroll
  for (int mt = 0; mt < 2; ++mt)
#pragma unroll
    for (int r = 0; r < 4; ++r) {
      int row = m0 + (mt0 + mt) * 16 + quad * 4 + r;
      float rs = rowscale ? rowscale[row] : 1.f;
#pragma unroll
      for (int nt = 0; nt < 2; ++nt) {
        int col = n0 + (nt0 + nt) * 16 + lo16;
        float v = acc[mt][nt][r] * rs;
        if (colscale) v *= colscale[col];
        if (bias) v += bias[col];
        if (ACT) v = (v > 0.f) ? v : 0.01f * v;
        Cc[(size_t)row * ldc + col] = v;
      }
    }
}

// ---------------- fused dual-B MFMA GEMM: C1 = A@B1 + b1; C2 = act(A@B2 + b2) --------
__global__ __launch_bounds__(256) void k_mgemm2(const float* __restrict__ A, int lda,
      const float* __restrict__ B1, const float* __restrict__ B2, int ldb,
      float* __restrict__ C1, float* __restrict__ C2, int ldc, int Kk,
      const float* __restrict__ bias1, const float* __restrict__ bias2) {
  __shared__ ushort Ah[64 * 40], Al[64 * 40];
  __shared__ ushort B1h[64 * 40], B1l[64 * 40], B2h[64 * 40], B2l[64 * 40];
  int t = threadIdx.x;
  int l = t & 63, w = t >> 6;
  int lo16 = l & 15, quad = l >> 4;
  int n0 = blockIdx.x * 64, m0 = blockIdx.y * 64;
  int mt0 = (w & 1) * 2, nt0 = (w >> 1) * 2;
  f4 acc1[2][2], acc2[2][2];
#pragma unroll
  for (int mt = 0; mt < 2; ++mt)
#pragma unroll
    for (int nt = 0; nt < 2; ++nt) {
      acc1[mt][nt] = (f4){0.f, 0.f, 0.f, 0.f};
      acc2[mt][nt] = (f4){0.f, 0.f, 0.f, 0.f};
    }
  int ar = t >> 2, ac = (t & 3) * 8;
  int kr = t >> 3, nc = (t & 7) * 8;
  for (int k0 = 0; k0 < Kk; k0 += 32) {
    __syncthreads();
    split8_contig(&A[(size_t)(m0 + ar) * lda + k0 + ac], &Ah[ar * 40 + ac], &Al[ar * 40 + ac]);
#pragma unroll
    for (int bsel = 0; bsel < 2; ++bsel) {
      const float* src = (bsel ? &B2[(size_t)(k0 + kr) * ldb + n0 + nc]
                               : &B1[(size_t)(k0 + kr) * ldb + n0 + nc]);
      ushort* dh = bsel ? B2h : B1h;
      ushort* dl = bsel ? B2l : B1l;
      float4 v0 = *(const float4*)src;
      float4 v1 = *(const float4*)(src + 4);
      float a[8] = {v0.x, v0.y, v0.z, v0.w, v1.x, v1.y, v1.z, v1.w};
#pragma unroll
      for (int i = 0; i < 8; ++i) {
        ushort hh = f2bf(a[i]);
        float hf = __uint_as_float(((unsigned)hh) << 16);
        dh[(nc + i) * 40 + kr] = hh;
        dl[(nc + i) * 40 + kr] = f2bf(a[i] - hf);
      }
    }
    __syncthreads();
    bfrag ah[2], al_[2];
#pragma unroll
    for (int mt = 0; mt < 2; ++mt) {
      int row = (mt0 + mt) * 16 + lo16;
      ah[mt]  = *(const bfrag*)&Ah[row * 40 + quad * 8];
      al_[mt] = *(const bfrag*)&Al[row * 40 + quad * 8];
    }
#pragma unroll
    for (int nt = 0; nt < 2; ++nt) {
      int col = (nt0 + nt) * 16 + lo16;
      bfrag b1h = *(const bfrag*)&B1h[col * 40 + quad * 8];
      bfrag b1l = *(const bfrag*)&B1l[col * 40 + quad * 8];
      bfrag b2h = *(const bfrag*)&B2h[col * 40 + quad * 8];
      bfrag b2l = *(const bfrag*)&B2l[col * 40 + quad * 8];
#pragma unroll
      for (int mt = 0; mt < 2; ++mt) {
        f4 a0 = __builtin_amdgcn_mfma_f32_16x16x32_bf16(al_[mt], b1h, acc1[mt][nt], 0, 0, 0);
        a0 = __builtin_amdgcn_mfma_f32_16x16x32_bf16(ah[mt], b1l, a0, 0, 0, 0);
        acc1[mt][nt] = __builtin_amdgcn_mfma_f32_16x16x32_bf16(ah[mt], b1h, a0, 0, 0, 0);
        f4 a1 = __builtin_amdgcn_mfma_f32_16x16x32_bf16(al_[mt], b2h, acc2[mt][nt], 0, 0, 0);
        a1 = __builtin_amdgcn_mfma_f32_16x16x32_bf16(ah[mt], b2l, a1, 0, 0, 0);
        acc2[mt][nt] = __builtin_amdgcn_mfma_f32_16x16x32_bf16(ah[mt], b2h, a1, 0, 0, 0);
      }
    }
  }
#pragma unroll
  for (int mt = 0; mt < 2; ++mt)
#pragma unroll
    for (int r = 0; r < 4; ++r) {
      int row = m0 + (mt0 + mt) * 16 + quad * 4 + r;
#pragma unroll
      for (int nt = 0; nt < 2; ++nt) {
        int col = n0 + (nt0 + nt) * 16 + lo16;
        C1[(size_t)row * ldc + col] = acc1[mt][nt][r] + bias1[col];
        float v = acc2[mt][nt][r] + bias2[col];
        C2[(size_t)row * ldc + col] = (v > 0.f) ? v : 0.01f * v;
      }
    }
}

// ---------------- column softmax stats over S[N,C]: fused max+sumexp ----------------
#define CPB 128
__global__ __launch_bounds__(256) void k_colms_part(const float* __restrict__ S,
      float* __restrict__ partm, float* __restrict__ parts) {
  int t = threadIdx.x, b = blockIdx.x;
  int r0 = b * (N_ / CPB);
  float m0 = -FLT_MAX, m1 = -FLT_MAX;
  for (int r = 0; r < N_ / CPB; ++r) {
    const float* row = S + (size_t)(r0 + r) * C_;
    m0 = fmaxf(m0, row[t]);
    m1 = fmaxf(m1, row[t + 256]);
  }
  float s0 = 0.f, s1 = 0.f;
  for (int r = 0; r < N_ / CPB; ++r) {   // slice is L2-resident after pass 1
    const float* row = S + (size_t)(r0 + r) * C_;
    s0 += __expf(row[t] - m0);
    s1 += __expf(row[t + 256] - m1);
  }
  partm[(size_t)b * C_ + t] = m0;
  partm[(size_t)b * C_ + t + 256] = m1;
  parts[(size_t)b * C_ + t] = s0;
  parts[(size_t)b * C_ + t + 256] = s1;
}

__global__ __launch_bounds__(512) void k_colfin(const float* __restrict__ partm,
      const float* __restrict__ parts, float* __restrict__ colmax,
      float* __restrict__ colsumexp) {
  int c = threadIdx.x;
  float m = -FLT_MAX;
  for (int b = 0; b < CPB; ++b) m = fmaxf(m, partm[(size_t)b * C_ + c]);
  float s = 0.f;
  for (int b = 0; b < CPB; ++b)
    s += parts[(size_t)b * C_ + c] * __expf(partm[(size_t)b * C_ + c] - m);
  colmax[c] = m;
  colsumexp[c] = s;
}

// ---------------- row softmax (512 cols) with keep mask ----------------
__global__ __launch_bounds__(256) void k_rowsoftmax(float* __restrict__ Sm,
      const int* __restrict__ keep1) {
  __shared__ float buf[256];
  int i = blockIdx.x, t = threadIdx.x;
  float* row = Sm + (size_t)i * C_;
  int k0 = keep1[t], k1 = keep1[t + 256];
  float v0 = k0 ? row[t] : -FLT_MAX;
  float v1 = k1 ? row[t + 256] : -FLT_MAX;
  buf[t] = fmaxf(v0, v1); __syncthreads();
  for (int s = 128; s > 0; s >>= 1) {
    if (t < s) buf[t] = fmaxf(buf[t], buf[t + s]);
    __syncthreads();
  }
  float m = buf[0]; __syncthreads();
  float e0 = k0 ? __expf(v0 - m) : 0.f;
  float e1 = k1 ? __expf(v1 - m) : 0.f;
  buf[t] = e0 + e1; __syncthreads();
  for (int s = 128; s > 0; s >>= 1) {
    if (t < s) buf[t] += buf[t + s];
    __syncthreads();
  }
  float inv = 1.f / buf[0];
  row[t] = e0 * inv;
  row[t + 256] = e1 * inv;
}

// ---------------- gram prep: normalized rows split into bf16 hi + lo ----------------
__global__ __launch_bounds__(256) void k_prep_gram(const float* __restrict__ hs,
      const float* __restrict__ rn, ushort* __restrict__ Ghi, ushort* __restrict__ Glo) {
  int t = threadIdx.x;
  int row = blockIdx.x * 8 + (t >> 5);
  int c = (t & 31) * 4;
  float r = rn[row];
  float4 v = *(const float4*)&hs[(size_t)row * H_ + c];
  float q[4] = {v.x * r, v.y * r, v.z * r, v.w * r};
  ushort hi[4], lo[4];
#pragma unroll
  for (int k = 0; k < 4; ++k) {
    hi[k] = f2bf(q[k]);
    float hf = __uint_as_float(((unsigned)hi[k]) << 16);
    lo[k] = f2bf(q[k] - hf);
  }
  *(ushort4*)&Ghi[(size_t)row * H_ + c] = *(ushort4*)hi;
  *(ushort4*)&Glo[(size_t)row * H_ + c] = *(ushort4*)lo;
}

// gram tile body: DIAG variant carries the j==gi check, non-DIAG path skips it
template<bool DIAG>
__device__ __forceinline__ void gram_tile(const ushort* __restrict__ JH,
      const ushort* __restrict__ JL, const bfrag (&ahi)[2][4], const bfrag (&alo)[2][4],
      float (&tv)[2][4][3], int (&ti)[2][4][3], int j0, int lo16, int quad, int rbase) {
#pragma unroll
  for (int js = 0; js < 4; ++js) {
    int jl_ = js * 16 + lo16;
    int j = j0 + jl_;
    bfrag bhi[4], blo[4];
#pragma unroll
    for (int kc = 0; kc < 4; ++kc) {
      int base = jl_ * 136 + kc * 32 + quad * 8;
      bhi[kc] = *(const bfrag*)&JH[base];
      blo[kc] = *(const bfrag*)&JL[base];
    }
#pragma unroll
    for (int mt = 0; mt < 2; ++mt) {
      f4 ahh = (f4){0.f, 0.f, 0.f, 0.f};
      f4 ahl = (f4){0.f, 0.f, 0.f, 0.f};
      f4 alh = (f4){0.f, 0.f, 0.f, 0.f};
#pragma unroll
      for (int kc = 0; kc < 4; ++kc) {
        ahh = __builtin_amdgcn_mfma_f32_16x16x32_bf16(ahi[mt][kc], bhi[kc], ahh, 0, 0, 0);
        ahl = __builtin_amdgcn_mfma_f32_16x16x32_bf16(ahi[mt][kc], blo[kc], ahl, 0, 0, 0);
        alh = __builtin_amdgcn_mfma_f32_16x16x32_bf16(alo[mt][kc], bhi[kc], alh, 0, 0, 0);
      }
#pragma unroll
      for (int r = 0; r < 4; ++r) {
        float v = ahh[r] + ahl[r] + alh[r];
        if (DIAG) {
          int gi = rbase + mt * 16 + quad * 4 + r;
          if (j == gi) v = 0.f;
        }
        top3_fast(tv[mt][r], ti[mt][r], v, j);
      }
    }
  }
}

// ---------------- N x N Gram: 4-wave blocks, 32 rows/wave, LDS j-tiles --------------
#define GSPLIT 8
__global__ __launch_bounds__(256) void k_gram_mfma(const ushort* __restrict__ Ghi,
      const ushort* __restrict__ Glo, int* __restrict__ Gip) {
  __shared__ ushort JH[64 * 136];
  __shared__ ushort JL[64 * 136];
  int t = threadIdx.x;
  int l = t & 63, w = t >> 6;
  int lo16 = l & 15, quad = l >> 4;
  int i0 = blockIdx.x * 128;
  int rbase = i0 + w * 32;
  int sp = blockIdx.y;
  const int jspan = N_ / GSPLIT;   // 1024

  bfrag ahi[2][4], alo[2][4];
#pragma unroll
  for (int mt = 0; mt < 2; ++mt)
#pragma unroll
    for (int kc = 0; kc < 4; ++kc) {
      size_t base = (size_t)(rbase + mt * 16 + lo16) * H_ + kc * 32 + quad * 8;
      ahi[mt][kc] = *(const bfrag*)&Ghi[base];
      alo[mt][kc] = *(const bfrag*)&Glo[base];
    }

  float tv[2][4][3]; int ti[2][4][3];
#pragma unroll
  for (int mt = 0; mt < 2; ++mt)
#pragma unroll
    for (int r = 0; r < 4; ++r)
#pragma unroll
      for (int s = 0; s < 3; ++s) { tv[mt][r][s] = -FLT_MAX; ti[mt][r][s] = 0x7fffffff; }

  int srow = t >> 2, scol = (t & 3) * 32;
  for (int jt = 0; jt < jspan / 64; ++jt) {
    int j0 = sp * jspan + jt * 64;
    __syncthreads();
    {
      const ushort* gh = &Ghi[(size_t)(j0 + srow) * H_ + scol];
      const ushort* gl = &Glo[(size_t)(j0 + srow) * H_ + scol];
      ushort* dh = &JH[srow * 136 + scol];
      ushort* dl = &JL[srow * 136 + scol];
#pragma unroll
      for (int u = 0; u < 32; u += 4) {
        *(ushort4*)&dh[u] = *(const ushort4*)&gh[u];
        *(ushort4*)&dl[u] = *(const ushort4*)&gl[u];
      }
    }
    __syncthreads();
    // diagonal can only appear when [j0,j0+63] intersects [rbase,rbase+31] (wave-uniform)
    if (rbase <= j0 + 63 && j0 <= rbase + 31)
      gram_tile<true>(JH, JL, ahi, alo, tv, ti, j0, lo16, quad, rbase);
    else
      gram_tile<false>(JH, JL, ahi, alo, tv, ti, j0, lo16, quad, rbase);
  }
  // in-wave butterfly merge across the 16 lanes sharing each row
#pragma unroll
  for (int mt = 0; mt < 2; ++mt)
#pragma unroll
    for (int r = 0; r < 4; ++r) {
#pragma unroll
      for (int x = 1; x <= 8; x <<= 1) {
        float vv[3]; int ii[3];
#pragma unroll
        for (int s = 0; s < 3; ++s) {
          vv[s] = __shfl_xor(tv[mt][r][s], x, 16);
          ii[s] = __shfl_xor(ti[mt][r][s], x, 16);
        }
#pragma unroll
        for (int s = 0; s < 3; ++s) top3_ins(tv[mt][r], ti[mt][r], vv[s], ii[s]);
      }
    }
  if (lo16 == 0) {
#pragma unroll
    for (int mt = 0; mt < 2; ++mt)
#pragma unroll
      for (int r = 0; r < 4; ++r) {
        int row = rbase + mt * 16 + quad * 4 + r;
#pragma unroll
        for (int s = 0; s < 3; ++s)
          Gip[((size_t)sp * N_ + row) * 3 + s] = ti[mt][r][s];
      }
  }
}

// ---------------- exact fp32 rescore of 24 candidates/row -> final top-3 -------------
__global__ __launch_bounds__(256) void k_gram_rescore(const float* __restrict__ hs,
      const float* __restrict__ rn, const int* __restrict__ Gip,
      float* __restrict__ gvals, int* __restrict__ gidx) {
  int row = blockIdx.x * 4 + (threadIdx.x >> 6);
  int lane = threadIdx.x & 63;
  const float* qr = &hs[(size_t)row * H_];
  float q0 = qr[lane], q1 = qr[lane + 64];
  float rni = rn[row];
  float bv[3] = {-FLT_MAX, -FLT_MAX, -FLT_MAX};
  int bi[3] = {0x7fffffff, 0x7fffffff, 0x7fffffff};
  for (int s = 0; s < GSPLIT; ++s)
#pragma unroll
    for (int k = 0; k < 3; ++k) {
      int j = Gip[((size_t)s * N_ + row) * 3 + k];
      const float* jr = &hs[(size_t)j * H_];
      float d = q0 * jr[lane] + q1 * jr[lane + 64];
#pragma unroll
      for (int x = 1; x < 64; x <<= 1) d += __shfl_xor(d, x, 64);
      float v = (j == row) ? 0.f : d * rni * rn[j];
      top3_ins(bv, bi, v, j);
    }
  if (lane == 0) {
#pragma unroll
    for (int s = 0; s < 3; ++s) {
      gvals[(size_t)row * 3 + s] = bv[s];
      gidx[(size_t)row * 3 + s] = bi[s];
    }
  }
}

// ---------------- sparse scatter: hidden3 = hs2c^T @ h_shared ----------------
__global__ __launch_bounds__(128) void k_scatter(const float* __restrict__ hs,
      const float* __restrict__ gvals, const int* __restrict__ gidx,
      float* __restrict__ hidden3, float* __restrict__ colsum3) {
  int i = blockIdx.x, t = threadIdx.x;
  float xs = hs[(size_t)i * H_ + t];
#pragma unroll
  for (int k = 0; k < 3; ++k) {
    int j = gidx[i * 3 + k];
    float v = gvals[i * 3 + k];
    atomicAdd(&hidden3[(size_t)j * H_ + t], v * xs);
  }
  if (t == 0) {
#pragma unroll
    for (int k = 0; k < 3; ++k) atomicAdd(&colsum3[gidx[i * 3 + k]], gvals[i * 3 + k]);
  }
}

__global__ __launch_bounds__(128) void k_h3fin(float* __restrict__ hidden3,
      const float* __restrict__ hs, const float* __restrict__ colsum3,
      const float* __restrict__ diagv, float* __restrict__ rn3, int* __restrict__ keep2) {
  __shared__ float buf[128];
  int j = blockIdx.x, t = threadIdx.x;
  float v = hidden3[(size_t)j * H_ + t];
  if (colsum3[j] != 0.f) v += diagv[j] * hs[(size_t)j * H_ + t];
  hidden3[(size_t)j * H_ + t] = v;
  float ss = bred_sum128(v * v, buf);
  float sm = bred_sum128(v, buf);
  if (t == 0) {
    rn3[j] = (ss > 0.f) ? 1.f / sqrtf(ss) : 0.f;
    keep2[j] = (sm != 0.f) ? 1 : 0;
  }
}

// ---------------- attention prep: bf16 Qn/Kn, transposed V, keep as float ----------
__global__ __launch_bounds__(256) void k_prep_attn(const float* __restrict__ hs,
      const float* __restrict__ h3, const float* __restrict__ rqh,
      const float* __restrict__ rn3, const int* __restrict__ keep2,
      ushort* __restrict__ Qn, ushort* __restrict__ Kn, ushort* __restrict__ Vt,
      float* __restrict__ keepf) {
  __shared__ ushort T[H_][68];
  int t = threadIdx.x;
  int i0 = blockIdx.x * 64;
  int r = i0 + (t >> 2);
  int c0 = (t & 3) * 32;
  float rq = rqh[r], r3 = rn3[r];
  for (int c = c0; c < c0 + 32; c += 4) {
    float4 hv = *(const float4*)&hs[(size_t)r * H_ + c];
    float4 h3v = *(const float4*)&h3[(size_t)r * H_ + c];
    ushort q4[4] = {f2bf(hv.x * rq), f2bf(hv.y * rq), f2bf(hv.z * rq), f2bf(hv.w * rq)};
    ushort k4[4] = {f2bf(h3v.x * r3), f2bf(h3v.y * r3), f2bf(h3v.z * r3), f2bf(h3v.w * r3)};
    *(ushort4*)&Qn[(size_t)r * H_ + c] = *(ushort4*)q4;
    *(ushort4*)&Kn[(size_t)r * H_ + c] = *(ushort4*)k4;
    T[c + 0][r - i0] = f2bf(h3v.x);
    T[c + 1][r - i0] = f2bf(h3v.y);
    T[c + 2][r - i0] = f2bf(h3v.z);
    T[c + 3][r - i0] = f2bf(h3v.w);
  }
  if (t < 64) keepf[i0 + t] = (float)keep2[i0 + t];
  __syncthreads();
  int h = t >> 1, off = (t & 1) * 32;
  for (int u = 0; u < 32; u += 4) {
    ushort4 vv;
    vv.x = T[h][off + u]; vv.y = T[h][off + u + 1];
    vv.z = T[h][off + u + 2]; vv.w = T[h][off + u + 3];
    *(ushort4*)&Vt[(size_t)h * N_ + i0 + off + u] = vv;
  }
}

// ---------------- MFMA flash attention: 4-wave blocks, 32 rows/wave, LDS K/V --------
#define JSPLIT 8
__global__ __launch_bounds__(256) void k_attn_mfma(const ushort* __restrict__ Qn,
      const ushort* __restrict__ Kn, const ushort* __restrict__ Vt,
      const float* __restrict__ keepf, float* __restrict__ Opart,
      float* __restrict__ Lpart) {
  __shared__ ushort Ks[64 * 136];
  __shared__ ushort Vs[128 * 72];
  __shared__ ushort Ps[4][32 * 72];
  int t = threadIdx.x;
  int l = t & 63, w = t >> 6;
  int lo16 = l & 15, quad = l >> 4;
  int i0 = blockIdx.x * 128;
  int rbase = i0 + w * 32;
  int sp = blockIdx.y;
  const int jspan = N_ / JSPLIT;   // 1024

  bfrag aq[2][4];
#pragma unroll
  for (int mt = 0; mt < 2; ++mt)
#pragma unroll
    for (int kc = 0; kc < 4; ++kc)
      aq[mt][kc] = *(const bfrag*)&Qn[(size_t)(rbase + mt * 16 + lo16) * H_ + kc * 32 + quad * 8];

  f4 O[2][8];
#pragma unroll
  for (int mt = 0; mt < 2; ++mt)
#pragma unroll
    for (int ns = 0; ns < 8; ++ns) O[mt][ns] = (f4){0.f, 0.f, 0.f, 0.f};
  f4 lsum[2];
  lsum[0] = (f4){0.f, 0.f, 0.f, 0.f};
  lsum[1] = (f4){0.f, 0.f, 0.f, 0.f};

  int krow = t >> 2, kcol = (t & 3) * 32;
  int vrow = t >> 1, vcol = (t & 1) * 32;
  for (int jt = 0; jt < jspan / 64; ++jt) {
    int j0 = sp * jspan + jt * 64;
    __syncthreads();
    {
      const ushort* gk = &Kn[(size_t)(j0 + krow) * H_ + kcol];
      ushort* dk = &Ks[krow * 136 + kcol];
#pragma unroll
      for (int u = 0; u < 32; u += 4)
        *(ushort4*)&dk[u] = *(const ushort4*)&gk[u];
      const ushort* gv = &Vt[(size_t)vrow * N_ + j0 + vcol];
      ushort* dv = &Vs[vrow * 72 + vcol];
#pragma unroll
      for (int u = 0; u < 32; u += 4)
        *(ushort4*)&dv[u] = *(const ushort4*)&gv[u];
    }
    __syncthreads();
    float kp[4];
#pragma unroll
    for (int js = 0; js < 4; ++js) kp[js] = keepf[j0 + js * 16 + lo16];
#pragma unroll
    for (int js = 0; js < 4; ++js) {
      bfrag bk[4];
#pragma unroll
      for (int kc = 0; kc < 4; ++kc)
        bk[kc] = *(const bfrag*)&Ks[(js * 16 + lo16) * 136 + kc * 32 + quad * 8];
#pragma unroll
      for (int mt = 0; mt < 2; ++mt) {
        f4 acc = (f4){0.f, 0.f, 0.f, 0.f};
#pragma unroll
        for (int kc = 0; kc < 4; ++kc)
          acc = __builtin_amdgcn_mfma_f32_16x16x32_bf16(aq[mt][kc], bk[kc], acc, 0, 0, 0);
#pragma unroll
        for (int r = 0; r < 4; ++r) {
          float p = kp[js] * __expf(acc[r] - 1.f);
          lsum[mt][r] += p;
          Ps[w][(mt * 16 + quad * 4 + r) * 72 + js * 16 + lo16] = f2bf(p);
        }
      }
    }
#pragma unroll
    for (int kc = 0; kc < 2; ++kc) {
      bfrag ap0 = *(const bfrag*)&Ps[w][lo16 * 72 + kc * 32 + quad * 8];
      bfrag ap1 = *(const bfrag*)&Ps[w][(16 + lo16) * 72 + kc * 32 + quad * 8];
#pragma unroll
      for (int ns = 0; ns < 8; ++ns) {
        bfrag bv = *(const bfrag*)&Vs[(ns * 16 + lo16) * 72 + kc * 32 + quad * 8];
        O[0][ns] = __builtin_amdgcn_mfma_f32_16x16x32_bf16(ap0, bv, O[0][ns], 0, 0, 0);
        O[1][ns] = __builtin_amdgcn_mfma_f32_16x16x32_bf16(ap1, bv, O[1][ns], 0, 0, 0);
      }
    }
  }
#pragma unroll
  for (int mt = 0; mt < 2; ++mt)
#pragma unroll
    for (int ns = 0; ns < 8; ++ns)
#pragma unroll
      for (int r = 0; r < 4; ++r) {
        int row = rbase + mt * 16 + quad * 4 + r;
        Opart[((size_t)sp * N_ + row) * H_ + ns * 16 + lo16] = O[mt][ns][r];
      }
#pragma unroll
  for (int x = 1; x <= 8; x <<= 1)
#pragma unroll
    for (int mt = 0; mt < 2; ++mt)
#pragma unroll
      for (int r = 0; r < 4; ++r) lsum[mt][r] += __shfl_xor(lsum[mt][r], x, 16);
  if (lo16 == 0) {
#pragma unroll
    for (int mt = 0; mt < 2; ++mt)
#pragma unroll
      for (int r = 0; r < 4; ++r)
        Lpart[(size_t)sp * N_ + rbase + mt * 16 + quad * 4 + r] = lsum[mt][r];
  }
}

__global__ __launch_bounds__(128) void k_attn_merge(const float* __restrict__ Opart,
      const float* __restrict__ Lpart, float* __restrict__ outp) {
  int i = blockIdx.x, t = threadIdx.x;
  float lg = 0.f;
#pragma unroll
  for (int s = 0; s < JSPLIT; ++s) lg += Lpart[(size_t)s * N_ + i];
  float inv = (lg > 0.f) ? 1.f / lg : 0.f;
  float acc = 0.f;
#pragma unroll
  for (int s = 0; s < JSPLIT; ++s)
    acc += Opart[((size_t)s * N_ + i) * H_ + t];
  outp[(size_t)i * H_ + t] = acc * inv;
}

// ---------------- elementwise ----------------
__global__ __launch_bounds__(256) void k_sub2(const float4* __restrict__ a,
      const float4* __restrict__ b, float4* __restrict__ o) {
  int i = blockIdx.x * 256 + threadIdx.x;
  float4 x = a[i], y = b[i], r;
  r.x = x.x - y.x; r.y = x.y - y.y; r.z = x.z - y.z; r.w = x.w - y.w;
  o[i] = r;
}

__global__ __launch_bounds__(256) void k_sub3(const float4* __restrict__ a,
      const float4* __restrict__ b, const float4* __restrict__ c, float4* __restrict__ o) {
  int i = blockIdx.x * 256 + threadIdx.x;
  float4 x = a[i], y = b[i], z = c[i], r;
  r.x = x.x - y.x - z.x; r.y = x.y - y.y - z.y; r.z = x.z - y.z - z.z; r.w = x.w - y.w - z.w;
  o[i] = r;
}

__global__ __launch_bounds__(128) void k_pred(const float* __restrict__ a,
      const float* __restrict__ b, const float* __restrict__ c,
      const float* __restrict__ wout, const float* __restrict__ bout,
      float* __restrict__ outp) {
  __shared__ float buf[128];
  int i = blockIdx.x, t = threadIdx.x;
  size_t idx = (size_t)i * H_ + t;
  float v = (a[idx] + b[idx] + c[idx]) * wout[t];
  float s = bred_sum128(v, buf);
  if (t == 0) outp[i] = s + bout[0];
}

// ---------------- host ----------------
extern "C" void kernel_launch(void* const* d_in, const int* in_sizes, int n_in,
                              void* d_out, int out_size, void* d_ws, size_t ws_size,
                              hipStream_t stream) {
  const float* x          = (const float*)d_in[0];
  const float* mv         = (const float*)d_in[1];
  const int*   cm         = (const int*)d_in[2];
  const float* W_ps       = (const float*)d_in[3];
  const float* b_ps       = (const float*)d_in[4];
  const float* W_hs       = (const float*)d_in[5];
  const float* b_hs       = (const float*)d_in[6];
  const float* W_ps_fore  = (const float*)d_in[7];
  const float* b_ps_fore  = (const float*)d_in[8];
  const float* W_hs_fore  = (const float*)d_in[9];
  const float* b_hs_fore  = (const float*)d_in[10];
  const float* W_ps_back  = (const float*)d_in[11];
  const float* b_ps_back  = (const float*)d_in[12];
  const float* W_hs_back  = (const float*)d_in[13];
  const float* b_hs_back  = (const float*)d_in[14];
  const float* W_indi     = (const float*)d_in[15];
  const float* b_indi     = (const float*)d_in[16];
  const float* W_out      = (const float*)d_in[23];
  const float* b_out      = (const float*)d_in[24];
  float* outp = (float*)d_out;

  float* W = (float*)d_ws;
  const size_t NC = (size_t)N_ * C_;   // NC = 4*NH
  const size_t NH = (size_t)N_ * H_;
  const size_t CH = (size_t)C_ * H_;
  float* Sbuf = W;
  float* pback   = Sbuf;
  float* outps   = Sbuf + NH;
  float* hback   = Sbuf + 2 * NH;
  float* outindi = Sbuf + 3 * NH;
  size_t off = NC;
  float* T1       = W + off; off += NH;
  float* p_shared = W + off; off += NH;
  float* h_shared = W + off; off += NH;
  float* hidden3  = W + off; off += NH;
  float* h_info   = W + off; off += NH;
  float* out_hs   = W + off; off += NH;
  float* hidden1  = W + off; off += CH;
  float* hidden2  = W + off; off += CH;
  float* colsum1   = W + off; off += C_;
  float* colmax    = W + off; off += C_;
  float* colsumexp = W + off; off += C_;
  float* rny2      = W + off; off += C_;
  float* partm     = W + off; off += (size_t)CPB * C_;
  float* parts     = W + off; off += (size_t)CPB * C_;
  float* rnx     = W + off; off += N_;
  float* rqh     = W + off; off += N_;
  float* diagv   = W + off; off += N_;
  float* colsum3 = W + off; off += N_;
  float* rn3     = W + off; off += N_;
  float* gvals   = W + off; off += 3 * N_;
  float* Lpart   = W + off; off += (size_t)JSPLIT * N_;
  float* keepf   = W + off; off += N_;
  int* keep1 = (int*)(W + off); off += C_;
  int* keep2 = (int*)(W + off); off += N_;
  int* gidx  = (int*)(W + off); off += 3 * N_;
  ushort* Qn = (ushort*)(W + off); off += NH / 2;
  ushort* Kn = (ushort*)(W + off); off += NH / 2;
  ushort* Vt = (ushort*)(W + off); off += NH / 2;
  float* Opart = W + off; off += (size_t)JSPLIT * NH;   // stage-5 only
  // Gram scratch ALIASES Opart (stage-4 only; disjoint in time from attention):
  ushort* Ghi = (ushort*)Opart;
  ushort* Glo = Ghi + NH;
  int*    Gip = (int*)(Opart + NH);

  hipMemsetAsync(colsum1, 0, C_ * sizeof(float), stream);
  hipMemsetAsync(hidden1, 0, CH * sizeof(float), stream);
  hipMemsetAsync(hidden2, 0, CH * sizeof(float), stream);
  hipMemsetAsync(hidden3, 0, NH * sizeof(float), stream);
  hipMemsetAsync(colsum3, 0, N_ * sizeof(float), stream);

  // stage 1: market-value aggregation
  k_colsum1<<<dim3(2, 128), 256, 0, stream>>>(cm, mv, colsum1);
  k_agg<0><<<dim3(16, 64), 256, 0, stream>>>(x, cm, mv, nullptr, nullptr, hidden1);
  k_fin_hidden1<<<C_, 128, 0, stream>>>(hidden1, colsum1, keep1);
  k_rowstats<<<N_, 128, 0, stream>>>(x, rnx, nullptr, nullptr);

  // stage 2: softmax over stocks, hidden2
  k_mgemm<1, 0><<<dim3(C_ / 64, N_ / 64), 256, 0, stream>>>(
      x, H_, hidden1, H_, Sbuf, C_, H_, nullptr, nullptr, nullptr);
  k_colms_part<<<CPB, 256, 0, stream>>>(Sbuf, partm, parts);
  k_colfin<<<1, 512, 0, stream>>>(partm, parts, colmax, colsumexp);
  k_agg<1><<<dim3(16, 64), 256, 0, stream>>>(x, nullptr, nullptr, Sbuf, colmax, hidden2);
  k_fin_hidden2<<<C_, 128, 0, stream>>>(hidden2, colsumexp, rny2);

  // stage 3: c2s softmax + p branch
  k_mgemm<1, 0><<<dim3(C_ / 64, N_ / 64), 256, 0, stream>>>(
      x, H_, hidden2, H_, Sbuf, C_, H_, nullptr, rnx, rny2);
  k_rowsoftmax<<<N_, 256, 0, stream>>>(Sbuf, keep1);
  k_mgemm<0, 0><<<dim3(H_ / 64, N_ / 64), 256, 0, stream>>>(
      Sbuf, C_, hidden2, H_, T1, H_, C_, nullptr, nullptr, nullptr);
  k_mgemm<0, 0><<<dim3(H_ / 64, N_ / 64), 256, 0, stream>>>(
      T1, H_, W_ps, H_, p_shared, H_, H_, b_ps, nullptr, nullptr);
  k_mgemm2<<<dim3(H_ / 64, N_ / 64), 256, 0, stream>>>(
      p_shared, H_, W_ps_back, W_ps_fore, H_, pback, outps, H_, H_, b_ps_back, b_ps_fore);

  // stage 4: h_shared, N x N top-3 graph (MFMA candidates + exact rescore)
  k_sub2<<<NH / 4 / 256, 256, 0, stream>>>((const float4*)x, (const float4*)pback,
                                           (float4*)h_shared);
  k_rowstats<<<N_, 128, 0, stream>>>(h_shared, rqh, diagv, nullptr);
  k_prep_gram<<<N_ / 8, 256, 0, stream>>>(h_shared, rqh, Ghi, Glo);
  k_gram_mfma<<<dim3(N_ / 128, GSPLIT), 256, 0, stream>>>(Ghi, Glo, Gip);
  k_gram_rescore<<<N_ / 4, 256, 0, stream>>>(h_shared, rqh, Gip, gvals, gidx);
  k_scatter<<<N_, 128, 0, stream>>>(h_shared, gvals, gidx, hidden3, colsum3);
  k_h3fin<<<N_, 128, 0, stream>>>(hidden3, h_shared, colsum3, diagv, rn3, keep2);

  // stage 5: MFMA flash attention (fixed-max, LDS-staged K/V), h branch
  k_prep_attn<<<N_ / 64, 256, 0, stream>>>(h_shared, hidden3, rqh, rn3, keep2,
                                           Qn, Kn, Vt, keepf);
  k_attn_mfma<<<dim3(N_ / 128, JSPLIT), 256, 0, stream>>>(Qn, Kn, Vt, keepf,
                                                          Opart, Lpart);
  k_attn_merge<<<N_, 128, 0, stream>>>(Opart, Lpart, T1);
  k_mgemm<0, 0><<<dim3(H_ / 64, N_ / 64), 256, 0, stream>>>(
      T1, H_, W_hs, H_, h_info, H_, H_, b_hs, nullptr, nullptr);
  k_mgemm2<<<dim3(H_ / 64, N_ / 64), 256, 0, stream>>>(
      h_info, H_, W_hs_back, W_hs_fore, H_, hback, out_hs, H_, H_, b_hs_back, b_hs_fore);

  // stage 6: individual branch + final projection
  k_sub3<<<NH / 4 / 256, 256, 0, stream>>>((const float4*)x, (const float4*)pback,
                                           (const float4*)hback, (float4*)h_shared);
  k_mgemm<0, 1><<<dim3(H_ / 64, N_ / 64), 256, 0, stream>>>(
      h_shared, H_, W_indi, H_, outindi, H_, H_, b_indi, nullptr, nullptr);
  k_pred<<<N_, 128, 0, stream>>>(outps, out_hs, outindi, W_out, b_out, outp);
}

// Round 12
// 578.736 us; speedup vs baseline: 2.1839x; 1.0058x over previous
//
#include <hip/hip_runtime.h>
#include <float.h>
#include <math.h>

#define N_ 8192
#define C_ 512
#define H_ 128

typedef __attribute__((ext_vector_type(8))) short bfrag;
typedef __attribute__((ext_vector_type(8))) _Float16 hfrag;
typedef __attribute__((ext_vector_type(4))) float f4;

__device__ __forceinline__ ushort f2bf(float f) {
  unsigned u = __float_as_uint(f);
  unsigned r = (u + 0x7fffu + ((u >> 16) & 1u)) >> 16;
  return (ushort)r;
}

__device__ __forceinline__ ushort f2h(float f) {
  _Float16 h = (_Float16)f;   // v_cvt_f16_f32, RTN
  return *(ushort*)&h;
}

// split 8 consecutive fp32 into bf16 hi/lo
__device__ __forceinline__ void split8_contig(const float* __restrict__ src,
      ushort* __restrict__ dh, ushort* __restrict__ dl) {
  float4 v0 = *(const float4*)src;
  float4 v1 = *(const float4*)(src + 4);
  float a[8] = {v0.x, v0.y, v0.z, v0.w, v1.x, v1.y, v1.z, v1.w};
  ushort hh[8], ll[8];
#pragma unroll
  for (int i = 0; i < 8; ++i) {
    hh[i] = f2bf(a[i]);
    float hf = __uint_as_float(((unsigned)hh[i]) << 16);
    ll[i] = f2bf(a[i] - hf);
  }
  *(ushort4*)&dh[0] = *(ushort4*)&hh[0];
  *(ushort4*)&dh[4] = *(ushort4*)&hh[4];
  *(ushort4*)&dl[0] = *(ushort4*)&ll[0];
  *(ushort4*)&dl[4] = *(ushort4*)&ll[4];
}

// ---------------- helpers ----------------
__device__ __forceinline__ float bred_sum128(float v, float* buf) {
  int t = threadIdx.x;
  buf[t] = v; __syncthreads();
  for (int s = 64; s > 0; s >>= 1) {
    if (t < s) buf[t] += buf[t + s];
    __syncthreads();
  }
  float r = buf[0]; __syncthreads();
  return r;
}

__device__ __forceinline__ void top3_ins(float (&tv)[3], int (&ti)[3], float v, int j) {
  bool b2 = (v > tv[2]) || (v == tv[2] && j < ti[2]);
  if (!b2) return;
  bool b1 = (v > tv[1]) || (v == tv[1] && j < ti[1]);
  if (b1) {
    tv[2] = tv[1]; ti[2] = ti[1];
    bool b0 = (v > tv[0]) || (v == tv[0] && j < ti[0]);
    if (b0) { tv[1] = tv[0]; ti[1] = ti[0]; tv[0] = v; ti[0] = j; }
    else    { tv[1] = v;     ti[1] = j; }
  } else { tv[2] = v; ti[2] = j; }
}

// fast insert: per-lane stream is j-ascending, strict > keeps lowest j on ties
__device__ __forceinline__ void top3_fast(float (&tv)[3], int (&ti)[3], float v, int j) {
  if (v <= tv[2]) return;
  if (v > tv[1]) {
    tv[2] = tv[1]; ti[2] = ti[1];
    if (v > tv[0]) { tv[1] = tv[0]; ti[1] = ti[0]; tv[0] = v; ti[0] = j; }
    else           { tv[1] = v;     ti[1] = j; }
  } else { tv[2] = v; ti[2] = j; }
}

// ---------------- stage 1: concept aggregation ----------------
// MODE 0 also accumulates colsum1[c] = sum_i w (w already computed for the tile)
template<int MODE>
__global__ __launch_bounds__(256) void k_agg(const float* __restrict__ x,
      const int* __restrict__ cm, const float* __restrict__ mv,
      const float* __restrict__ S, const float* __restrict__ colmax,
      float* __restrict__ outCH, float* __restrict__ colsum1) {
  __shared__ float ws[8][32];
  int t = threadIdx.x;
  int cbase = blockIdx.x * 32;
  int h = t & 127, half = t >> 7;
  float acc[16];
#pragma unroll
  for (int k = 0; k < 16; ++k) acc[k] = 0.f;
  int sr = t >> 5, sc = t & 31;
  float csum = 0.f;
  for (int sub = 0; sub < 16; ++sub) {
    int ibase = blockIdx.y * 128 + sub * 8;
    {
      int i = ibase + sr, c = cbase + sc;
      float w;
      if (MODE == 0) w = cm[(size_t)i * C_ + c] ? mv[i] : 0.f;
      else           w = __expf(S[(size_t)i * C_ + c] - colmax[c]);
      ws[sr][sc] = w;
      if (MODE == 0) csum += w;
    }
    __syncthreads();
#pragma unroll
    for (int r = 0; r < 8; ++r) {
      float xv = x[(size_t)(ibase + r) * H_ + h];
      const float* wr = &ws[r][half * 16];
#pragma unroll
      for (int k = 0; k < 16; ++k) acc[k] += wr[k] * xv;
    }
    __syncthreads();
  }
#pragma unroll
  for (int k = 0; k < 16; ++k)
    atomicAdd(&outCH[(size_t)(cbase + half * 16 + k) * H_ + h], acc[k]);
  if (MODE == 0) atomicAdd(&colsum1[cbase + sc], csum);
}

__global__ __launch_bounds__(128) void k_fin_hidden1(float* __restrict__ h1,
      const float* __restrict__ colsum1, int* __restrict__ keep1) {
  __shared__ float buf[128];
  int c = blockIdx.x, t = threadIdx.x;
  float v = h1[(size_t)c * H_ + t] / (colsum1[c] + 1.f);
  h1[(size_t)c * H_ + t] = v;
  float sm = bred_sum128(v, buf);
  if (t == 0) keep1[c] = (sm != 0.f) ? 1 : 0;
}

__global__ __launch_bounds__(128) void k_fin_hidden2(float* __restrict__ h2,
      const float* __restrict__ colsumexp, float* __restrict__ rny) {
  __shared__ float buf[128];
  int c = blockIdx.x, t = threadIdx.x;
  float v = h2[(size_t)c * H_ + t] / colsumexp[c];
  h2[(size_t)c * H_ + t] = v;
  float ss = bred_sum128(v * v, buf);
  if (t == 0) rny[c] = (ss > 0.f) ? 1.f / sqrtf(ss) : 0.f;
}

__global__ __launch_bounds__(128) void k_rowstats(const float* __restrict__ A,
      float* __restrict__ rinv, float* __restrict__ diag, int* __restrict__ keep) {
  __shared__ float buf[128];
  int i = blockIdx.x, t = threadIdx.x;
  float v = A[(size_t)i * H_ + t];
  float ss = bred_sum128(v * v, buf);
  float sm = bred_sum128(v, buf);
  if (t == 0) {
    float nr = sqrtf(ss);
    if (rinv) rinv[i] = (ss > 0.f) ? 1.f / nr : 0.f;
    if (diag) diag[i] = (ss > 0.f) ? ss / (nr * nr) : 0.f;
    if (keep) keep[i] = (sm != 0.f) ? 1 : 0;
  }
}

// ---------------- MFMA GEMM, hi/lo-compensated bf16, fused split ----------------
template<int TRANSB, int ACT>
__global__ __launch_bounds__(256) void k_mgemm(const float* __restrict__ A, int lda,
      const float* __restrict__ B, int ldb, float* __restrict__ Cc, int ldc, int Kk,
      const float* __restrict__ bias, const float* __restrict__ rowscale,
      const float* __restrict__ colscale) {
  __shared__ ushort Ah[64 * 40], Al[64 * 40], Bh[64 * 40], Bl[64 * 40];
  int t = threadIdx.x;
  int l = t & 63, w = t >> 6;
  int lo16 = l & 15, quad = l >> 4;
  int n0 = blockIdx.x * 64, m0 = blockIdx.y * 64;
  int mt0 = (w & 1) * 2, nt0 = (w >> 1) * 2;
  f4 acc[2][2];
#pragma unroll
  for (int mt = 0; mt < 2; ++mt)
#pragma unroll
    for (int nt = 0; nt < 2; ++nt) acc[mt][nt] = (f4){0.f, 0.f, 0.f, 0.f};

  int ar = t >> 2, ac = (t & 3) * 8;
  int kr = t >> 3, nc = (t & 7) * 8;
  for (int k0 = 0; k0 < Kk; k0 += 32) {
    __syncthreads();
    split8_contig(&A[(size_t)(m0 + ar) * lda + k0 + ac], &Ah[ar * 40 + ac], &Al[ar * 40 + ac]);
    if (TRANSB) {
      split8_contig(&B[(size_t)(n0 + ar) * ldb + k0 + ac], &Bh[ar * 40 + ac], &Bl[ar * 40 + ac]);
    } else {
      const float* src = &B[(size_t)(k0 + kr) * ldb + n0 + nc];
      float4 v0 = *(const float4*)src;
      float4 v1 = *(const float4*)(src + 4);
      float a[8] = {v0.x, v0.y, v0.z, v0.w, v1.x, v1.y, v1.z, v1.w};
#pragma unroll
      for (int i = 0; i < 8; ++i) {
        ushort hh = f2bf(a[i]);
        float hf = __uint_as_float(((unsigned)hh) << 16);
        Bh[(nc + i) * 40 + kr] = hh;
        Bl[(nc + i) * 40 + kr] = f2bf(a[i] - hf);
      }
    }
    __syncthreads();
    bfrag ah[2], al_[2], bh[2], bl[2];
#pragma unroll
    for (int mt = 0; mt < 2; ++mt) {
      int row = (mt0 + mt) * 16 + lo16;
      ah[mt]  = *(const bfrag*)&Ah[row * 40 + quad * 8];
      al_[mt] = *(const bfrag*)&Al[row * 40 + quad * 8];
    }
#pragma unroll
    for (int nt = 0; nt < 2; ++nt) {
      int col = (nt0 + nt) * 16 + lo16;
      bh[nt] = *(const bfrag*)&Bh[col * 40 + quad * 8];
      bl[nt] = *(const bfrag*)&Bl[col * 40 + quad * 8];
    }
#pragma unroll
    for (int mt = 0; mt < 2; ++mt)
#pragma unroll
      for (int nt = 0; nt < 2; ++nt) {
        f4 a0 = __builtin_amdgcn_mfma_f32_16x16x32_bf16(al_[mt], bh[nt], acc[mt][nt], 0, 0, 0);
        a0 = __builtin_amdgcn_mfma_f32_16x16x32_bf16(ah[mt], bl[nt], a0, 0, 0, 0);
        acc[mt][nt] = __builtin_amdgcn_mfma_f32_16x16x32_bf16(ah[mt], bh[nt], a0, 0, 0, 0);
      }
  }
#pragma unroll
  for (int mt = 0; mt < 2; ++mt)
#pragma unroll
    for (int r = 0; r < 4; ++r) {
      int row = m0 + (mt0 + mt) * 16 + quad * 4 + r;
      float rs = rowscale ? rowscale[row] : 1.f;
#pragma unroll
      for (int nt = 0; nt < 2; ++nt) {
        int col = n0 + (nt0 + nt) * 16 + lo16;
        float v = acc[mt][nt][r] * rs;
        if (colscale) v *= colscale[col];
        if (bias) v += bias[col];
        if (ACT) v = (v > 0.f) ? v : 0.01f * v;
        Cc[(size_t)row * ldc + col] = v;
      }
    }
}

// ---------------- fused dual-B MFMA GEMM: C1 = A@B1 + b1; C2 = act(A@B2 + b2) --------
__global__ __launch_bounds__(256) void k_mgemm2(const float* __restrict__ A, int lda,
      const float* __restrict__ B1, const float* __restrict__ B2, int ldb,
      float* __restrict__ C1, float* __restrict__ C2, int ldc, int Kk,
      const float* __restrict__ bias1, const float* __restrict__ bias2) {
  __shared__ ushort Ah[64 * 40], Al[64 * 40];
  __shared__ ushort B1h[64 * 40], B1l[64 * 40], B2h[64 * 40], B2l[64 * 40];
  int t = threadIdx.x;
  int l = t & 63, w = t >> 6;
  int lo16 = l & 15, quad = l >> 4;
  int n0 = blockIdx.x * 64, m0 = blockIdx.y * 64;
  int mt0 = (w & 1) * 2, nt0 = (w >> 1) * 2;
  f4 acc1[2][2], acc2[2][2];
#pragma unroll
  for (int mt = 0; mt < 2; ++mt)
#pragma unroll
    for (int nt = 0; nt < 2; ++nt) {
      acc1[mt][nt] = (f4){0.f, 0.f, 0.f, 0.f};
      acc2[mt][nt] = (f4){0.f, 0.f, 0.f, 0.f};
    }
  int ar = t >> 2, ac = (t & 3) * 8;
  int kr = t >> 3, nc = (t & 7) * 8;
  for (int k0 = 0; k0 < Kk; k0 += 32) {
    __syncthreads();
    split8_contig(&A[(size_t)(m0 + ar) * lda + k0 + ac], &Ah[ar * 40 + ac], &Al[ar * 40 + ac]);
#pragma unroll
    for (int bsel = 0; bsel < 2; ++bsel) {
      const float* src = (bsel ? &B2[(size_t)(k0 + kr) * ldb + n0 + nc]
                               : &B1[(size_t)(k0 + kr) * ldb + n0 + nc]);
      ushort* dh = bsel ? B2h : B1h;
      ushort* dl = bsel ? B2l : B1l;
      float4 v0 = *(const float4*)src;
      float4 v1 = *(const float4*)(src + 4);
      float a[8] = {v0.x, v0.y, v0.z, v0.w, v1.x, v1.y, v1.z, v1.w};
#pragma unroll
      for (int i = 0; i < 8; ++i) {
        ushort hh = f2bf(a[i]);
        float hf = __uint_as_float(((unsigned)hh) << 16);
        dh[(nc + i) * 40 + kr] = hh;
        dl[(nc + i) * 40 + kr] = f2bf(a[i] - hf);
      }
    }
    __syncthreads();
    bfrag ah[2], al_[2];
#pragma unroll
    for (int mt = 0; mt < 2; ++mt) {
      int row = (mt0 + mt) * 16 + lo16;
      ah[mt]  = *(const bfrag*)&Ah[row * 40 + quad * 8];
      al_[mt] = *(const bfrag*)&Al[row * 40 + quad * 8];
    }
#pragma unroll
    for (int nt = 0; nt < 2; ++nt) {
      int col = (nt0 + nt) * 16 + lo16;
      bfrag b1h = *(const bfrag*)&B1h[col * 40 + quad * 8];
      bfrag b1l = *(const bfrag*)&B1l[col * 40 + quad * 8];
      bfrag b2h = *(const bfrag*)&B2h[col * 40 + quad * 8];
      bfrag b2l = *(const bfrag*)&B2l[col * 40 + quad * 8];
#pragma unroll
      for (int mt = 0; mt < 2; ++mt) {
        f4 a0 = __builtin_amdgcn_mfma_f32_16x16x32_bf16(al_[mt], b1h, acc1[mt][nt], 0, 0, 0);
        a0 = __builtin_amdgcn_mfma_f32_16x16x32_bf16(ah[mt], b1l, a0, 0, 0, 0);
        acc1[mt][nt] = __builtin_amdgcn_mfma_f32_16x16x32_bf16(ah[mt], b1h, a0, 0, 0, 0);
        f4 a1 = __builtin_amdgcn_mfma_f32_16x16x32_bf16(al_[mt], b2h, acc2[mt][nt], 0, 0, 0);
        a1 = __builtin_amdgcn_mfma_f32_16x16x32_bf16(ah[mt], b2l, a1, 0, 0, 0);
        acc2[mt][nt] = __builtin_amdgcn_mfma_f32_16x16x32_bf16(ah[mt], b2h, a1, 0, 0, 0);
      }
    }
  }
#pragma unroll
  for (int mt = 0; mt < 2; ++mt)
#pragma unroll
    for (int r = 0; r < 4; ++r) {
      int row = m0 + (mt0 + mt) * 16 + quad * 4 + r;
#pragma unroll
      for (int nt = 0; nt < 2; ++nt) {
        int col = n0 + (nt0 + nt) * 16 + lo16;
        C1[(size_t)row * ldc + col] = acc1[mt][nt][r] + bias1[col];
        float v = acc2[mt][nt][r] + bias2[col];
        C2[(size_t)row * ldc + col] = (v > 0.f) ? v : 0.01f * v;
      }
    }
}

// ---------------- column softmax stats over S[N,C]: fused max+sumexp ----------------
#define CPB 128
__global__ __launch_bounds__(256) void k_colms_part(const float* __restrict__ S,
      float* __restrict__ partm, float* __restrict__ parts) {
  int t = threadIdx.x, b = blockIdx.x;
  int r0 = b * (N_ / CPB);
  float m0 = -FLT_MAX, m1 = -FLT_MAX;
  for (int r = 0; r < N_ / CPB; ++r) {
    const float* row = S + (size_t)(r0 + r) * C_;
    m0 = fmaxf(m0, row[t]);
    m1 = fmaxf(m1, row[t + 256]);
  }
  float s0 = 0.f, s1 = 0.f;
  for (int r = 0; r < N_ / CPB; ++r) {
    const float* row = S + (size_t)(r0 + r) * C_;
    s0 += __expf(row[t] - m0);
    s1 += __expf(row[t + 256] - m1);
  }
  partm[(size_t)b * C_ + t] = m0;
  partm[(size_t)b * C_ + t + 256] = m1;
  parts[(size_t)b * C_ + t] = s0;
  parts[(size_t)b * C_ + t + 256] = s1;
}

__global__ __launch_bounds__(512) void k_colfin(const float* __restrict__ partm,
      const float* __restrict__ parts, float* __restrict__ colmax,
      float* __restrict__ colsumexp) {
  int c = threadIdx.x;
  float m = -FLT_MAX;
  for (int b = 0; b < CPB; ++b) m = fmaxf(m, partm[(size_t)b * C_ + c]);
  float s = 0.f;
  for (int b = 0; b < CPB; ++b)
    s += parts[(size_t)b * C_ + c] * __expf(partm[(size_t)b * C_ + c] - m);
  colmax[c] = m;
  colsumexp[c] = s;
}

// ---------------- row softmax (512 cols) with keep mask ----------------
__global__ __launch_bounds__(256) void k_rowsoftmax(float* __restrict__ Sm,
      const int* __restrict__ keep1) {
  __shared__ float buf[256];
  int i = blockIdx.x, t = threadIdx.x;
  float* row = Sm + (size_t)i * C_;
  int k0 = keep1[t], k1 = keep1[t + 256];
  float v0 = k0 ? row[t] : -FLT_MAX;
  float v1 = k1 ? row[t + 256] : -FLT_MAX;
  buf[t] = fmaxf(v0, v1); __syncthreads();
  for (int s = 128; s > 0; s >>= 1) {
    if (t < s) buf[t] = fmaxf(buf[t], buf[t + s]);
    __syncthreads();
  }
  float m = buf[0]; __syncthreads();
  float e0 = k0 ? __expf(v0 - m) : 0.f;
  float e1 = k1 ? __expf(v1 - m) : 0.f;
  buf[t] = e0 + e1; __syncthreads();
  for (int s = 128; s > 0; s >>= 1) {
    if (t < s) buf[t] += buf[t + s];
    __syncthreads();
  }
  float inv = 1.f / buf[0];
  row[t] = e0 * inv;
  row[t + 256] = e1 * inv;
}

// ---------------- gram prep: normalized rows -> fp16 (single array) ----------------
__global__ __launch_bounds__(256) void k_prep_gram(const float* __restrict__ hs,
      const float* __restrict__ rn, ushort* __restrict__ Gh) {
  int t = threadIdx.x;
  int row = blockIdx.x * 8 + (t >> 5);
  int c = (t & 31) * 4;
  float r = rn[row];
  float4 v = *(const float4*)&hs[(size_t)row * H_ + c];
  ushort h4[4] = {f2h(v.x * r), f2h(v.y * r), f2h(v.z * r), f2h(v.w * r)};
  *(ushort4*)&Gh[(size_t)row * H_ + c] = *(ushort4*)h4;
}

// gram tile body (fp16 single-chain scores; exact rescore downstream fixes values)
template<bool DIAG>
__device__ __forceinline__ void gram_tile(const ushort* __restrict__ JH,
      const hfrag (&ah)[2][4], float (&tv)[2][4][3], int (&ti)[2][4][3],
      int j0, int lo16, int quad, int rbase) {
#pragma unroll
  for (int js = 0; js < 4; ++js) {
    int jl_ = js * 16 + lo16;
    int j = j0 + jl_;
    hfrag bh[4];
#pragma unroll
    for (int kc = 0; kc < 4; ++kc)
      bh[kc] = *(const hfrag*)&JH[jl_ * 136 + kc * 32 + quad * 8];
#pragma unroll
    for (int mt = 0; mt < 2; ++mt) {
      f4 acc = (f4){0.f, 0.f, 0.f, 0.f};
#pragma unroll
      for (int kc = 0; kc < 4; ++kc)
        acc = __builtin_amdgcn_mfma_f32_16x16x32_f16(ah[mt][kc], bh[kc], acc, 0, 0, 0);
#pragma unroll
      for (int r = 0; r < 4; ++r) {
        float v = acc[r];
        if (DIAG) {
          int gi = rbase + mt * 16 + quad * 4 + r;
          if (j == gi) v = 0.f;
        }
        top3_fast(tv[mt][r], ti[mt][r], v, j);
      }
    }
  }
}

// ---------------- N x N Gram: 4-wave blocks, 32 rows/wave, LDS j-tiles (fp16) -------
#define GSPLIT 8
__global__ __launch_bounds__(256) void k_gram_mfma(const ushort* __restrict__ Gh,
      int* __restrict__ Gip) {
  __shared__ ushort JH[64 * 136];
  int t = threadIdx.x;
  int l = t & 63, w = t >> 6;
  int lo16 = l & 15, quad = l >> 4;
  int i0 = blockIdx.x * 128;
  int rbase = i0 + w * 32;
  int sp = blockIdx.y;
  const int jspan = N_ / GSPLIT;   // 1024

  hfrag ah[2][4];
#pragma unroll
  for (int mt = 0; mt < 2; ++mt)
#pragma unroll
    for (int kc = 0; kc < 4; ++kc)
      ah[mt][kc] = *(const hfrag*)&Gh[(size_t)(rbase + mt * 16 + lo16) * H_ + kc * 32 + quad * 8];

  float tv[2][4][3]; int ti[2][4][3];
#pragma unroll
  for (int mt = 0; mt < 2; ++mt)
#pragma unroll
    for (int r = 0; r < 4; ++r)
#pragma unroll
      for (int s = 0; s < 3; ++s) { tv[mt][r][s] = -FLT_MAX; ti[mt][r][s] = 0x7fffffff; }

  int srow = t >> 2, scol = (t & 3) * 32;
  for (int jt = 0; jt < jspan / 64; ++jt) {
    int j0 = sp * jspan + jt * 64;
    __syncthreads();
    {
      const ushort* gh = &Gh[(size_t)(j0 + srow) * H_ + scol];
      ushort* dh = &JH[srow * 136 + scol];
#pragma unroll
      for (int u = 0; u < 32; u += 4)
        *(ushort4*)&dh[u] = *(const ushort4*)&gh[u];
    }
    __syncthreads();
    if (rbase <= j0 + 63 && j0 <= rbase + 31)
      gram_tile<true>(JH, ah, tv, ti, j0, lo16, quad, rbase);
    else
      gram_tile<false>(JH, ah, tv, ti, j0, lo16, quad, rbase);
  }
  // in-wave butterfly merge across the 16 lanes sharing each row
#pragma unroll
  for (int mt = 0; mt < 2; ++mt)
#pragma unroll
    for (int r = 0; r < 4; ++r) {
#pragma unroll
      for (int x = 1; x <= 8; x <<= 1) {
        float vv[3]; int ii[3];
#pragma unroll
        for (int s = 0; s < 3; ++s) {
          vv[s] = __shfl_xor(tv[mt][r][s], x, 16);
          ii[s] = __shfl_xor(ti[mt][r][s], x, 16);
        }
#pragma unroll
        for (int s = 0; s < 3; ++s) top3_ins(tv[mt][r], ti[mt][r], vv[s], ii[s]);
      }
    }
  if (lo16 == 0) {
#pragma unroll
    for (int mt = 0; mt < 2; ++mt)
#pragma unroll
      for (int r = 0; r < 4; ++r) {
        int row = rbase + mt * 16 + quad * 4 + r;
#pragma unroll
        for (int s = 0; s < 3; ++s)
          Gip[((size_t)sp * N_ + row) * 3 + s] = ti[mt][r][s];
      }
  }
}

// ---------------- exact fp32 rescore of 24 candidates/row -> final top-3 -------------
__global__ __launch_bounds__(256) void k_gram_rescore(const float* __restrict__ hs,
      const float* __restrict__ rn, const int* __restrict__ Gip,
      float* __restrict__ gvals, int* __restrict__ gidx) {
  int row = blockIdx.x * 4 + (threadIdx.x >> 6);
  int lane = threadIdx.x & 63;
  const float* qr = &hs[(size_t)row * H_];
  float q0 = qr[lane], q1 = qr[lane + 64];
  float rni = rn[row];
  float bv[3] = {-FLT_MAX, -FLT_MAX, -FLT_MAX};
  int bi[3] = {0x7fffffff, 0x7fffffff, 0x7fffffff};
  for (int s = 0; s < GSPLIT; ++s)
#pragma unroll
    for (int k = 0; k < 3; ++k) {
      int j = Gip[((size_t)s * N_ + row) * 3 + k];
      const float* jr = &hs[(size_t)j * H_];
      float d = q0 * jr[lane] + q1 * jr[lane + 64];
#pragma unroll
      for (int x = 1; x < 64; x <<= 1) d += __shfl_xor(d, x, 64);
      float v = (j == row) ? 0.f : d * rni * rn[j];
      top3_ins(bv, bi, v, j);
    }
  if (lane == 0) {
#pragma unroll
    for (int s = 0; s < 3; ++s) {
      gvals[(size_t)row * 3 + s] = bv[s];
      gidx[(size_t)row * 3 + s] = bi[s];
    }
  }
}

// ---------------- sparse scatter: hidden3 = hs2c^T @ h_shared ----------------
__global__ __launch_bounds__(128) void k_scatter(const float* __restrict__ hs,
      const float* __restrict__ gvals, const int* __restrict__ gidx,
      float* __restrict__ hidden3, float* __restrict__ colsum3) {
  int i = blockIdx.x, t = threadIdx.x;
  float xs = hs[(size_t)i * H_ + t];
#pragma unroll
  for (int k = 0; k < 3; ++k) {
    int j = gidx[i * 3 + k];
    float v = gvals[i * 3 + k];
    atomicAdd(&hidden3[(size_t)j * H_ + t], v * xs);
  }
  if (t == 0) {
#pragma unroll
    for (int k = 0; k < 3; ++k) atomicAdd(&colsum3[gidx[i * 3 + k]], gvals[i * 3 + k]);
  }
}

__global__ __launch_bounds__(128) void k_h3fin(float* __restrict__ hidden3,
      const float* __restrict__ hs, const float* __restrict__ colsum3,
      const float* __restrict__ diagv, float* __restrict__ rn3, int* __restrict__ keep2) {
  __shared__ float buf[128];
  int j = blockIdx.x, t = threadIdx.x;
  float v = hidden3[(size_t)j * H_ + t];
  if (colsum3[j] != 0.f) v += diagv[j] * hs[(size_t)j * H_ + t];
  hidden3[(size_t)j * H_ + t] = v;
  float ss = bred_sum128(v * v, buf);
  float sm = bred_sum128(v, buf);
  if (t == 0) {
    rn3[j] = (ss > 0.f) ? 1.f / sqrtf(ss) : 0.f;
    keep2[j] = (sm != 0.f) ? 1 : 0;
  }
}

// ---------------- attention prep: bf16 Qn/Kn, transposed V, keep as float ----------
__global__ __launch_bounds__(256) void k_prep_attn(const float* __restrict__ hs,
      const float* __restrict__ h3, const float* __restrict__ rqh,
      const float* __restrict__ rn3, const int* __restrict__ keep2,
      ushort* __restrict__ Qn, ushort* __restrict__ Kn, ushort* __restrict__ Vt,
      float* __restrict__ keepf) {
  __shared__ ushort T[H_][68];
  int t = threadIdx.x;
  int i0 = blockIdx.x * 64;
  int r = i0 + (t >> 2);
  int c0 = (t & 3) * 32;
  float rq = rqh[r], r3 = rn3[r];
  for (int c = c0; c < c0 + 32; c += 4) {
    float4 hv = *(const float4*)&hs[(size_t)r * H_ + c];
    float4 h3v = *(const float4*)&h3[(size_t)r * H_ + c];
    ushort q4[4] = {f2bf(hv.x * rq), f2bf(hv.y * rq), f2bf(hv.z * rq), f2bf(hv.w * rq)};
    ushort k4[4] = {f2bf(h3v.x * r3), f2bf(h3v.y * r3), f2bf(h3v.z * r3), f2bf(h3v.w * r3)};
    *(ushort4*)&Qn[(size_t)r * H_ + c] = *(ushort4*)q4;
    *(ushort4*)&Kn[(size_t)r * H_ + c] = *(ushort4*)k4;
    T[c + 0][r - i0] = f2bf(h3v.x);
    T[c + 1][r - i0] = f2bf(h3v.y);
    T[c + 2][r - i0] = f2bf(h3v.z);
    T[c + 3][r - i0] = f2bf(h3v.w);
  }
  if (t < 64) keepf[i0 + t] = (float)keep2[i0 + t];
  __syncthreads();
  int h = t >> 1, off = (t & 1) * 32;
  for (int u = 0; u < 32; u += 4) {
    ushort4 vv;
    vv.x = T[h][off + u]; vv.y = T[h][off + u + 1];
    vv.z = T[h][off + u + 2]; vv.w = T[h][off + u + 3];
    *(ushort4*)&Vt[(size_t)h * N_ + i0 + off + u] = vv;
  }
}

// ---------------- MFMA flash attention: 4-wave blocks, 32 rows/wave, LDS K/V --------
#define JSPLIT 8
__global__ __launch_bounds__(256) void k_attn_mfma(const ushort* __restrict__ Qn,
      const ushort* __restrict__ Kn, const ushort* __restrict__ Vt,
      const float* __restrict__ keepf, float* __restrict__ Opart,
      float* __restrict__ Lpart) {
  __shared__ ushort Ks[64 * 136];
  __shared__ ushort Vs[128 * 72];
  __shared__ ushort Ps[4][32 * 72];
  int t = threadIdx.x;
  int l = t & 63, w = t >> 6;
  int lo16 = l & 15, quad = l >> 4;
  int i0 = blockIdx.x * 128;
  int rbase = i0 + w * 32;
  int sp = blockIdx.y;
  const int jspan = N_ / JSPLIT;   // 1024

  bfrag aq[2][4];
#pragma unroll
  for (int mt = 0; mt < 2; ++mt)
#pragma unroll
    for (int kc = 0; kc < 4; ++kc)
      aq[mt][kc] = *(const bfrag*)&Qn[(size_t)(rbase + mt * 16 + lo16) * H_ + kc * 32 + quad * 8];

  f4 O[2][8];
#pragma unroll
  for (int mt = 0; mt < 2; ++mt)
#pragma unroll
    for (int ns = 0; ns < 8; ++ns) O[mt][ns] = (f4){0.f, 0.f, 0.f, 0.f};
  f4 lsum[2];
  lsum[0] = (f4){0.f, 0.f, 0.f, 0.f};
  lsum[1] = (f4){0.f, 0.f, 0.f, 0.f};

  int krow = t >> 2, kcol = (t & 3) * 32;
  int vrow = t >> 1, vcol = (t & 1) * 32;
  for (int jt = 0; jt < jspan / 64; ++jt) {
    int j0 = sp * jspan + jt * 64;
    __syncthreads();
    {
      const ushort* gk = &Kn[(size_t)(j0 + krow) * H_ + kcol];
      ushort* dk = &Ks[krow * 136 + kcol];
#pragma unroll
      for (int u = 0; u < 32; u += 4)
        *(ushort4*)&dk[u] = *(const ushort4*)&gk[u];
      const ushort* gv = &Vt[(size_t)vrow * N_ + j0 + vcol];
      ushort* dv = &Vs[vrow * 72 + vcol];
#pragma unroll
      for (int u = 0; u < 32; u += 4)
        *(ushort4*)&dv[u] = *(const ushort4*)&gv[u];
    }
    __syncthreads();
    float kp[4];
#pragma unroll
    for (int js = 0; js < 4; ++js) kp[js] = keepf[j0 + js * 16 + lo16];
#pragma unroll
    for (int js = 0; js < 4; ++js) {
      bfrag bk[4];
#pragma unroll
      for (int kc = 0; kc < 4; ++kc)
        bk[kc] = *(const bfrag*)&Ks[(js * 16 + lo16) * 136 + kc * 32 + quad * 8];
#pragma unroll
      for (int mt = 0; mt < 2; ++mt) {
        f4 acc = (f4){0.f, 0.f, 0.f, 0.f};
#pragma unroll
        for (int kc = 0; kc < 4; ++kc)
          acc = __builtin_amdgcn_mfma_f32_16x16x32_bf16(aq[mt][kc], bk[kc], acc, 0, 0, 0);
#pragma unroll
        for (int r = 0; r < 4; ++r) {
          float p = kp[js] * __expf(acc[r] - 1.f);
          lsum[mt][r] += p;
          Ps[w][(mt * 16 + quad * 4 + r) * 72 + js * 16 + lo16] = f2bf(p);
        }
      }
    }
#pragma unroll
    for (int kc = 0; kc < 2; ++kc) {
      bfrag ap0 = *(const bfrag*)&Ps[w][lo16 * 72 + kc * 32 + quad * 8];
      bfrag ap1 = *(const bfrag*)&Ps[w][(16 + lo16) * 72 + kc * 32 + quad * 8];
#pragma unroll
      for (int ns = 0; ns < 8; ++ns) {
        bfrag bv = *(const bfrag*)&Vs[(ns * 16 + lo16) * 72 + kc * 32 + quad * 8];
        O[0][ns] = __builtin_amdgcn_mfma_f32_16x16x32_bf16(ap0, bv, O[0][ns], 0, 0, 0);
        O[1][ns] = __builtin_amdgcn_mfma_f32_16x16x32_bf16(ap1, bv, O[1][ns], 0, 0, 0);
      }
    }
  }
#pragma unroll
  for (int mt = 0; mt < 2; ++mt)
#pragma unroll
    for (int ns = 0; ns < 8; ++ns)
#pragma unroll
      for (int r = 0; r < 4; ++r) {
        int row = rbase + mt * 16 + quad * 4 + r;
        Opart[((size_t)sp * N_ + row) * H_ + ns * 16 + lo16] = O[mt][ns][r];
      }
#pragma unroll
  for (int x = 1; x <= 8; x <<= 1)
#pragma unroll
    for (int mt = 0; mt < 2; ++mt)
#pragma unroll
      for (int r = 0; r < 4; ++r) lsum[mt][r] += __shfl_xor(lsum[mt][r], x, 16);
  if (lo16 == 0) {
#pragma unroll
    for (int mt = 0; mt < 2; ++mt)
#pragma unroll
      for (int r = 0; r < 4; ++r)
        Lpart[(size_t)sp * N_ + rbase + mt * 16 + quad * 4 + r] = lsum[mt][r];
  }
}

__global__ __launch_bounds__(128) void k_attn_merge(const float* __restrict__ Opart,
      const float* __restrict__ Lpart, float* __restrict__ outp) {
  int i = blockIdx.x, t = threadIdx.x;
  float lg = 0.f;
#pragma unroll
  for (int s = 0; s < JSPLIT; ++s) lg += Lpart[(size_t)s * N_ + i];
  float inv = (lg > 0.f) ? 1.f / lg : 0.f;
  float acc = 0.f;
#pragma unroll
  for (int s = 0; s < JSPLIT; ++s)
    acc += Opart[((size_t)s * N_ + i) * H_ + t];
  outp[(size_t)i * H_ + t] = acc * inv;
}

// ---------------- elementwise ----------------
__global__ __launch_bounds__(256) void k_sub2(const float4* __restrict__ a,
      const float4* __restrict__ b, float4* __restrict__ o) {
  int i = blockIdx.x * 256 + threadIdx.x;
  float4 x = a[i], y = b[i], r;
  r.x = x.x - y.x; r.y = x.y - y.y; r.z = x.z - y.z; r.w = x.w - y.w;
  o[i] = r;
}

__global__ __launch_bounds__(256) void k_sub3(const float4* __restrict__ a,
      const float4* __restrict__ b, const float4* __restrict__ c, float4* __restrict__ o) {
  int i = blockIdx.x * 256 + threadIdx.x;
  float4 x = a[i], y = b[i], z = c[i], r;
  r.x = x.x - y.x - z.x; r.y = x.y - y.y - z.y; r.z = x.z - y.z - z.z; r.w = x.w - y.w - z.w;
  o[i] = r;
}

__global__ __launch_bounds__(128) void k_pred(const float* __restrict__ a,
      const float* __restrict__ b, const float* __restrict__ c,
      const float* __restrict__ wout, const float* __restrict__ bout,
      float* __restrict__ outp) {
  __shared__ float buf[128];
  int i = blockIdx.x, t = threadIdx.x;
  size_t idx = (size_t)i * H_ + t;
  float v = (a[idx] + b[idx] + c[idx]) * wout[t];
  float s = bred_sum128(v, buf);
  if (t == 0) outp[i] = s + bout[0];
}

// ---------------- host ----------------
extern "C" void kernel_launch(void* const* d_in, const int* in_sizes, int n_in,
                              void* d_out, int out_size, void* d_ws, size_t ws_size,
                              hipStream_t stream) {
  const float* x          = (const float*)d_in[0];
  const float* mv         = (const float*)d_in[1];
  const int*   cm         = (const int*)d_in[2];
  const float* W_ps       = (const float*)d_in[3];
  const float* b_ps       = (const float*)d_in[4];
  const float* W_hs       = (const float*)d_in[5];
  const float* b_hs       = (const float*)d_in[6];
  const float* W_ps_fore  = (const float*)d_in[7];
  const float* b_ps_fore  = (const float*)d_in[8];
  const float* W_hs_fore  = (const float*)d_in[9];
  const float* b_hs_fore  = (const float*)d_in[10];
  const float* W_ps_back  = (const float*)d_in[11];
  const float* b_ps_back  = (const float*)d_in[12];
  const float* W_hs_back  = (const float*)d_in[13];
  const float* b_hs_back  = (const float*)d_in[14];
  const float* W_indi     = (const float*)d_in[15];
  const float* b_indi     = (const float*)d_in[16];
  const float* W_out      = (const float*)d_in[23];
  const float* b_out      = (const float*)d_in[24];
  float* outp = (float*)d_out;

  float* W = (float*)d_ws;
  const size_t NC = (size_t)N_ * C_;   // NC = 4*NH
  const size_t NH = (size_t)N_ * H_;
  const size_t CH = (size_t)C_ * H_;
  float* Sbuf = W;
  float* pback   = Sbuf;
  float* outps   = Sbuf + NH;
  float* hback   = Sbuf + 2 * NH;
  float* outindi = Sbuf + 3 * NH;
  size_t off = NC;
  float* T1       = W + off; off += NH;
  float* p_shared = W + off; off += NH;
  float* h_shared = W + off; off += NH;
  float* hidden3  = W + off; off += NH;
  float* h_info   = W + off; off += NH;
  float* out_hs   = W + off; off += NH;
  float* hidden1  = W + off; off += CH;
  float* hidden2  = W + off; off += CH;
  float* colsum1   = W + off; off += C_;
  float* colmax    = W + off; off += C_;
  float* colsumexp = W + off; off += C_;
  float* rny2      = W + off; off += C_;
  float* partm     = W + off; off += (size_t)CPB * C_;
  float* parts     = W + off; off += (size_t)CPB * C_;
  float* rnx     = W + off; off += N_;
  float* rqh     = W + off; off += N_;
  float* diagv   = W + off; off += N_;
  float* colsum3 = W + off; off += N_;
  float* rn3     = W + off; off += N_;
  float* gvals   = W + off; off += 3 * N_;
  float* Lpart   = W + off; off += (size_t)JSPLIT * N_;
  float* keepf   = W + off; off += N_;
  int* keep1 = (int*)(W + off); off += C_;
  int* keep2 = (int*)(W + off); off += N_;
  int* gidx  = (int*)(W + off); off += 3 * N_;
  ushort* Qn = (ushort*)(W + off); off += NH / 2;
  ushort* Kn = (ushort*)(W + off); off += NH / 2;
  ushort* Vt = (ushort*)(W + off); off += NH / 2;
  float* Opart = W + off; off += (size_t)JSPLIT * NH;   // stage-5 only
  // Gram scratch ALIASES Opart (stage-4 only; disjoint in time from attention):
  ushort* Gh  = (ushort*)Opart;
  int*    Gip = (int*)(Opart + NH);

  hipMemsetAsync(colsum1, 0, C_ * sizeof(float), stream);
  hipMemsetAsync(hidden1, 0, CH * sizeof(float), stream);
  hipMemsetAsync(hidden2, 0, CH * sizeof(float), stream);
  hipMemsetAsync(hidden3, 0, NH * sizeof(float), stream);
  hipMemsetAsync(colsum3, 0, N_ * sizeof(float), stream);

  // stage 1: market-value aggregation (colsum1 fused into k_agg<0>)
  k_agg<0><<<dim3(16, 64), 256, 0, stream>>>(x, cm, mv, nullptr, nullptr, hidden1, colsum1);
  k_fin_hidden1<<<C_, 128, 0, stream>>>(hidden1, colsum1, keep1);
  k_rowstats<<<N_, 128, 0, stream>>>(x, rnx, nullptr, nullptr);

  // stage 2: softmax over stocks, hidden2
  k_mgemm<1, 0><<<dim3(C_ / 64, N_ / 64), 256, 0, stream>>>(
      x, H_, hidden1, H_, Sbuf, C_, H_, nullptr, nullptr, nullptr);
  k_colms_part<<<CPB, 256, 0, stream>>>(Sbuf, partm, parts);
  k_colfin<<<1, 512, 0, stream>>>(partm, parts, colmax, colsumexp);
  k_agg<1><<<dim3(16, 64), 256, 0, stream>>>(x, nullptr, nullptr, Sbuf, colmax, hidden2,
                                             nullptr);
  k_fin_hidden2<<<C_, 128, 0, stream>>>(hidden2, colsumexp, rny2);

  // stage 3: c2s softmax + p branch
  k_mgemm<1, 0><<<dim3(C_ / 64, N_ / 64), 256, 0, stream>>>(
      x, H_, hidden2, H_, Sbuf, C_, H_, nullptr, rnx, rny2);
  k_rowsoftmax<<<N_, 256, 0, stream>>>(Sbuf, keep1);
  k_mgemm<0, 0><<<dim3(H_ / 64, N_ / 64), 256, 0, stream>>>(
      Sbuf, C_, hidden2, H_, T1, H_, C_, nullptr, nullptr, nullptr);
  k_mgemm<0, 0><<<dim3(H_ / 64, N_ / 64), 256, 0, stream>>>(
      T1, H_, W_ps, H_, p_shared, H_, H_, b_ps, nullptr, nullptr);
  k_mgemm2<<<dim3(H_ / 64, N_ / 64), 256, 0, stream>>>(
      p_shared, H_, W_ps_back, W_ps_fore, H_, pback, outps, H_, H_, b_ps_back, b_ps_fore);

  // stage 4: h_shared, N x N top-3 graph (fp16 MFMA candidates + exact rescore)
  k_sub2<<<NH / 4 / 256, 256, 0, stream>>>((const float4*)x, (const float4*)pback,
                                           (float4*)h_shared);
  k_rowstats<<<N_, 128, 0, stream>>>(h_shared, rqh, diagv, nullptr);
  k_prep_gram<<<N_ / 8, 256, 0, stream>>>(h_shared, rqh, Gh);
  k_gram_mfma<<<dim3(N_ / 128, GSPLIT), 256, 0, stream>>>(Gh, Gip);
  k_gram_rescore<<<N_ / 4, 256, 0, stream>>>(h_shared, rqh, Gip, gvals, gidx);
  k_scatter<<<N_, 128, 0, stream>>>(h_shared, gvals, gidx, hidden3, colsum3);
  k_h3fin<<<N_, 128, 0, stream>>>(hidden3, h_shared, colsum3, diagv, rn3, keep2);

  // stage 5: MFMA flash attention (fixed-max, LDS-staged K/V), h branch
  k_prep_attn<<<N_ / 64, 256, 0, stream>>>(h_shared, hidden3, rqh, rn3, keep2,
                                           Qn, Kn, Vt, keepf);
  k_attn_mfma<<<dim3(N_ / 128, JSPLIT), 256, 0, stream>>>(Qn, Kn, Vt, keepf,
                                                          Opart, Lpart);
  k_attn_merge<<<N_, 128, 0, stream>>>(Opart, Lpart, T1);
  k_mgemm<0, 0><<<dim3(H_ / 64, N_ / 64), 256, 0, stream>>>(
      T1, H_, W_hs, H_, h_info, H_, H_, b_hs, nullptr, nullptr);
  k_mgemm2<<<dim3(H_ / 64, N_ / 64), 256, 0, stream>>>(
      h_info, H_, W_hs_back, W_hs_fore, H_, hback, out_hs, H_, H_, b_hs_back, b_hs_fore);

  // stage 6: individual branch + final projection
  k_sub3<<<NH / 4 / 256, 256, 0, stream>>>((const float4*)x, (const float4*)pback,
                                           (const float4*)hback, (float4*)h_shared);
  k_mgemm<0, 1><<<dim3(H_ / 64, N_ / 64), 256, 0, stream>>>(
      h_shared, H_, W_indi, H_, outindi, H_, H_, b_indi, nullptr, nullptr);
  k_pred<<<N_, 128, 0, stream>>>(outps, out_hs, outindi, W_out, b_out, outp);
}